// Round 1
// baseline (8680.791 us; speedup 1.0000x reference)
//
#include <hip/hip_runtime.h>
#include <hip/hip_bf16.h>

typedef unsigned short u16;
typedef unsigned int u32;

constexpr int CD    = 180;
constexpr int BATCH = 4;
constexpr int RES   = 128;
constexpr int LSZ   = RES * RES;        // 16384
constexpr int NHEAD = 6;
constexpr int DH    = 30;
constexpr int NTOK  = 64;               // tokens per 8x8 window
constexpr int NWIN  = 1024;             // 4 * 16 * 16
constexpr int MROWS = NWIN * NTOK;      // 65536

__device__ __forceinline__ float b2f(u16 u) { return __uint_as_float(((u32)u) << 16); }
__device__ __forceinline__ u16 f2b(float f) {
    __hip_bfloat16 h = __float2bfloat16(f);
    return *reinterpret_cast<u16*>(&h);
}

// ---------------- LN1 + roll(-4,-4) + window partition -> bf16 [win][tok][C]
__global__ __launch_bounds__(256) void ln_win_kernel(
    const float* __restrict__ src, const float* __restrict__ gamma,
    const float* __restrict__ beta, u16* __restrict__ dst) {
    __shared__ float tile[NTOK][CD + 1];
    int widx = blockIdx.x;
    int b = widx >> 8, wrem = widx & 255;
    int wh = wrem >> 4, ww = wrem & 15;
    int t = threadIdx.x;
    for (int i = t; i < NTOK * CD; i += 256) {
        int c = i >> 6, pos = i & 63;
        int sh = ((wh << 3) + (pos >> 3) + 4) & 127;
        int sw = ((ww << 3) + (pos & 7) + 4) & 127;
        tile[pos][c] = src[(((size_t)b * CD + c) << 14) + (sh << 7) + sw];
    }
    __syncthreads();
    int pos = t >> 2, sub = t & 3;
    float s = 0.f, ss = 0.f;
    for (int k = 0; k < 45; ++k) {
        float v = tile[pos][sub * 45 + k];
        s += v; ss += v * v;
    }
    s += __shfl_xor(s, 1); ss += __shfl_xor(ss, 1);
    s += __shfl_xor(s, 2); ss += __shfl_xor(ss, 2);
    float mean = s * (1.f / CD);
    float rstd = rsqrtf(ss * (1.f / CD) - mean * mean + 1e-5f);
    size_t obase = ((size_t)widx * NTOK + pos) * CD;
    for (int k = 0; k < 45; ++k) {
        int c = sub * 45 + k;
        dst[obase + c] = f2b((tile[pos][c] - mean) * rstd * gamma[c] + beta[c]);
    }
}

// ---------------- sigmoid(ew @ W^T + bias) -> bf16
__global__ __launch_bounds__(256) void gate_kernel(
    const u16* __restrict__ ew, const float* __restrict__ W,
    const float* __restrict__ bias, u16* __restrict__ sig) {
    __shared__ float At[CD][65];   // A transposed: [k][pos]
    int rb = blockIdx.x;
    int t = threadIdx.x;
    size_t rbase = (size_t)rb * 64 * CD;
    for (int i = t; i < 64 * CD; i += 256) {
        int pos = i / CD, c = i - pos * CD;
        At[c][pos] = b2f(ew[rbase + i]);
    }
    __syncthreads();
    int pos = t & 63, cg = t >> 6;
    for (int j = 0; j < 45; ++j) {
        int c = cg * 45 + j;
        const float* wr = W + (size_t)c * CD;
        float acc = bias[c];
        #pragma unroll 4
        for (int k = 0; k < CD; ++k) acc += At[k][pos] * wr[k];
        acc = 1.f / (1.f + __expf(-acc));
        sig[rbase + (size_t)pos * CD + c] = f2b(acc);
    }
}

// ---------------- per (window, head): QKV + scores(+rpb+mask) + softmax + PV
__global__ __launch_bounds__(256) void attn_kernel(
    const u16* __restrict__ ew, const float* __restrict__ qkv_w,
    const float* __restrict__ qkv_b, const float* __restrict__ rpb,
    u16* __restrict__ outp) {
    __shared__ __align__(16) u16 ewt[NTOK][CD];   // 23040 B
    __shared__ float qkvs[3][NTOK][33];           // 25344 B
    __shared__ float sc[NTOK][65];                // 16640 B  (total 65024 <= 64KB)
    int blk = blockIdx.x;
    int widx = blk / NHEAD, h = blk - widx * NHEAD;
    int wrem = widx & 255;
    int wh = wrem >> 4, ww = wrem & 15;
    int t = threadIdx.x;
    size_t wbase = (size_t)widx * NTOK * CD;
    for (int i = t; i < NTOK * CD; i += 256) ewt[i / CD][i % CD] = ew[wbase + i];
    __syncthreads();
    // QKV
    for (int i = t; i < 3 * NTOK * DH; i += 256) {
        int which = i / (NTOK * DH);
        int rem = i - which * (NTOK * DH);
        int pos = rem / DH, dd = rem - pos * DH;
        int row = which * CD + h * DH + dd;
        const float4* wr4 = (const float4*)(qkv_w + (size_t)row * CD);
        const ushort4* ep = (const ushort4*)ewt[pos];
        float acc = qkv_b[row];
        #pragma unroll 5
        for (int k4 = 0; k4 < 45; ++k4) {
            ushort4 e4 = ep[k4];
            float4 w4 = wr4[k4];
            acc += b2f(e4.x) * w4.x + b2f(e4.y) * w4.y + b2f(e4.z) * w4.z + b2f(e4.w) * w4.w;
        }
        if (which == 0) acc *= 0.18257418583505536f;   // 30^-0.5
        qkvs[which][pos][dd] = acc;
    }
    __syncthreads();
    // scores + rel-pos bias + shift mask
    for (int i = t; i < NTOK * NTOK; i += 256) {
        int si = i >> 6, sj = i & 63;
        float acc = 0.f;
        #pragma unroll 6
        for (int dd = 0; dd < DH; ++dd) acc += qkvs[0][si][dd] * qkvs[1][sj][dd];
        int ih = si >> 3, iw = si & 7, jh = sj >> 3, jw = sj & 7;
        acc += rpb[((ih - jh + 7) * 15 + (iw - jw + 7)) * NHEAD + h];
        if (wh == 15 || ww == 15) {
            int hri = (wh << 3) + ih, wri = (ww << 3) + iw;
            int hrj = (wh << 3) + jh, wrj = (ww << 3) + jw;
            int ri = (hri < 120 ? 0 : (hri < 124 ? 1 : 2)) * 3 + (wri < 120 ? 0 : (wri < 124 ? 1 : 2));
            int rj = (hrj < 120 ? 0 : (hrj < 124 ? 1 : 2)) * 3 + (wrj < 120 ? 0 : (wrj < 124 ? 1 : 2));
            if (ri != rj) acc -= 100.f;
        }
        sc[si][sj] = acc;
    }
    __syncthreads();
    // softmax (4 lanes per row)
    {
        int row = t >> 2, sub = t & 3;
        float mx = -1e30f;
        for (int k = 0; k < 16; ++k) mx = fmaxf(mx, sc[row][sub * 16 + k]);
        mx = fmaxf(mx, __shfl_xor(mx, 1));
        mx = fmaxf(mx, __shfl_xor(mx, 2));
        float sm = 0.f;
        for (int k = 0; k < 16; ++k) {
            float e = __expf(sc[row][sub * 16 + k] - mx);
            sc[row][sub * 16 + k] = e; sm += e;
        }
        sm += __shfl_xor(sm, 1);
        sm += __shfl_xor(sm, 2);
        float inv = 1.f / sm;
        for (int k = 0; k < 16; ++k) sc[row][sub * 16 + k] *= inv;
    }
    __syncthreads();
    // PV
    for (int i = t; i < NTOK * DH; i += 256) {
        int pos = i / DH, dd = i - pos * DH;
        float acc = 0.f;
        #pragma unroll 8
        for (int j = 0; j < NTOK; ++j) acc += sc[pos][j] * qkvs[2][j][dd];
        outp[wbase + (size_t)pos * CD + h * DH + dd] = f2b(acc);
    }
}

// ---------------- o = concat(out_e*sig, out_b*sig) @ W^T + bias
__global__ __launch_bounds__(256) void proj_kernel(
    const u16* __restrict__ oute, const u16* __restrict__ outb,
    const u16* __restrict__ sig, const float* __restrict__ W,
    const float* __restrict__ bias, u16* __restrict__ o) {
    __shared__ float At[360][33];   // [k][pos], 32 rows per block
    int rb = blockIdx.x;
    int t = threadIdx.x;
    size_t rbase = (size_t)rb * 32 * CD;
    for (int i = t; i < 32 * 360; i += 256) {
        int pos = i / 360, k = i - pos * 360;
        int c = (k < 180) ? k : k - 180;
        float g = b2f(sig[rbase + pos * CD + c]);
        float v = (k < 180) ? b2f(oute[rbase + pos * CD + c]) : b2f(outb[rbase + pos * CD + c]);
        At[k][pos] = v * g;
    }
    __syncthreads();
    for (int i = t; i < 32 * CD; i += 256) {
        int pos = i & 31, c = i >> 5;
        float acc = bias[c];
        const float* wr = W + (size_t)c * 360;
        #pragma unroll 4
        for (int k = 0; k < 360; ++k) acc += At[k][pos] * wr[k];
        o[rbase + (size_t)pos * CD + c] = f2b(acc);
    }
}

// ---------------- x = shortcut + unshift(window_reverse(o)), in NCHW
__global__ __launch_bounds__(256) void addback_kernel(
    const float* __restrict__ src, const u16* __restrict__ o, float* __restrict__ xout) {
    size_t idx = ((size_t)blockIdx.x << 8) + threadIdx.x;   // over B*C*L
    int w = (int)(idx & 127);
    int hh = (int)((idx >> 7) & 127);
    int bc = (int)(idx >> 14);      // b*C + c
    int c = bc % CD;
    int b = bc / CD;
    int hr = (hh - 4) & 127, wr = (w - 4) & 127;
    int win = (b << 8) + ((hr >> 3) << 4) + (wr >> 3);
    int pos = ((hr & 7) << 3) + (wr & 7);
    xout[idx] = src[idx] + b2f(o[((size_t)win * NTOK + pos) * CD + c]);
}

// ---------------- LN2 (reads x in NCHW layout) -> bf16 [row][C]
__global__ __launch_bounds__(256) void ln2_kernel(
    const float* __restrict__ x, const float* __restrict__ gamma,
    const float* __restrict__ beta, u16* __restrict__ dst) {
    __shared__ float tile[NTOK][CD + 1];
    int blk = blockIdx.x;
    int b = blk >> 8;
    int l0 = (blk & 255) << 6;
    int t = threadIdx.x;
    for (int i = t; i < NTOK * CD; i += 256) {
        int c = i >> 6, pos = i & 63;
        tile[pos][c] = x[(((size_t)b * CD + c) << 14) + l0 + pos];
    }
    __syncthreads();
    int pos = t >> 2, sub = t & 3;
    float s = 0.f, ss = 0.f;
    for (int k = 0; k < 45; ++k) {
        float v = tile[pos][sub * 45 + k];
        s += v; ss += v * v;
    }
    s += __shfl_xor(s, 1); ss += __shfl_xor(ss, 1);
    s += __shfl_xor(s, 2); ss += __shfl_xor(ss, 2);
    float mean = s * (1.f / CD);
    float rstd = rsqrtf(ss * (1.f / CD) - mean * mean + 1e-5f);
    size_t obase = ((size_t)(b << 14) + l0 + pos) * CD;
    for (int k = 0; k < 45; ++k) {
        int c = sub * 45 + k;
        dst[obase + c] = f2b((tile[pos][c] - mean) * rstd * gamma[c] + beta[c]);
    }
}

// ---------------- fused MLP: xout += GELU(xln @ w1^T + b1) @ w2^T + b2
__global__ __launch_bounds__(256) void mlp_kernel(
    const u16* __restrict__ xln, const float* __restrict__ w1, const float* __restrict__ b1,
    const float* __restrict__ w2, const float* __restrict__ b2f_, float* __restrict__ xout) {
    __shared__ __align__(16) u16 xs[32][CD];     // 11520 B
    __shared__ __align__(16) u16 hid[32][724];   // 46336 B
    int rb = blockIdx.x;
    int t = threadIdx.x;
    size_t rbase = (size_t)rb * 32 * CD;
    for (int i = t; i < 32 * CD; i += 256) xs[i / CD][i % CD] = xln[rbase + i];
    __syncthreads();
    // hidden = GELU(x @ w1^T + b1), each lane owns hidden columns
    for (int hcol = t; hcol < 720; hcol += 256) {
        const float4* wr4 = (const float4*)(w1 + (size_t)hcol * CD);
        float bb = b1[hcol];
        float acc[32];
        #pragma unroll
        for (int r = 0; r < 32; ++r) acc[r] = bb;
        for (int k4 = 0; k4 < 45; ++k4) {
            float4 w4 = wr4[k4];
            #pragma unroll
            for (int r = 0; r < 32; ++r) {
                ushort4 x4 = ((const ushort4*)xs[r])[k4];
                acc[r] += b2f(x4.x) * w4.x + b2f(x4.y) * w4.y + b2f(x4.z) * w4.z + b2f(x4.w) * w4.w;
            }
        }
        #pragma unroll
        for (int r = 0; r < 32; ++r) {
            float v = acc[r];
            hid[r][hcol] = f2b(0.5f * v * (1.f + erff(v * 0.70710678118f)));
        }
    }
    __syncthreads();
    // out = hidden @ w2^T + b2, accumulate into xout (NCHW)
    for (int i = t; i < 32 * CD; i += 256) {
        int pos = i & 31, c = i >> 5;
        const float4* wr4 = (const float4*)(w2 + (size_t)c * 720);
        float acc = b2f_[c];
        for (int k4 = 0; k4 < 180; ++k4) {
            ushort4 h4 = ((const ushort4*)hid[pos])[k4];
            float4 w4 = wr4[k4];
            acc += b2f(h4.x) * w4.x + b2f(h4.y) * w4.y + b2f(h4.z) * w4.z + b2f(h4.w) * w4.w;
        }
        int m = (rb << 5) + pos;
        xout[(((size_t)(m >> 14) * CD + c) << 14) + (m & 16383)] += acc;
    }
}

extern "C" void kernel_launch(void* const* d_in, const int* in_sizes, int n_in,
                              void* d_out, int out_size, void* d_ws, size_t ws_size,
                              hipStream_t stream) {
    const float* e_f = (const float*)d_in[0];
    const float* b_f = (const float*)d_in[1];

    const size_t BUF = (size_t)MROWS * CD;   // elements per bf16 buffer
    u16* ew   = (u16*)d_ws;
    u16* bw   = ew + BUF;
    u16* sige = bw + BUF;
    u16* sigb = sige + BUF;
    u16* oute = sigb + BUF;
    u16* outb = oute + BUF;
    // reuse (consumers finished):
    u16* oe  = ew;    u16* ob  = bw;     // proj outputs overwrite ew/bw
    u16* lne = sige;  u16* lnb = sigb;   // ln2 outputs overwrite sig

    float* xe = (float*)d_out;
    float* xb = xe + (size_t)BATCH * CD * LSZ;

    ln_win_kernel<<<NWIN, 256, 0, stream>>>(e_f, (const float*)d_in[2], (const float*)d_in[3], ew);
    ln_win_kernel<<<NWIN, 256, 0, stream>>>(b_f, (const float*)d_in[4], (const float*)d_in[5], bw);

    gate_kernel<<<MROWS / 64, 256, 0, stream>>>(ew, (const float*)d_in[10], (const float*)d_in[11], sige);
    gate_kernel<<<MROWS / 64, 256, 0, stream>>>(bw, (const float*)d_in[12], (const float*)d_in[13], sigb);

    attn_kernel<<<NWIN * NHEAD, 256, 0, stream>>>(ew, (const float*)d_in[6], (const float*)d_in[7],
                                                  (const float*)d_in[14], oute);
    attn_kernel<<<NWIN * NHEAD, 256, 0, stream>>>(bw, (const float*)d_in[8], (const float*)d_in[9],
                                                  (const float*)d_in[14], outb);

    proj_kernel<<<MROWS / 32, 256, 0, stream>>>(oute, outb, sige, (const float*)d_in[15],
                                                (const float*)d_in[16], oe);
    proj_kernel<<<MROWS / 32, 256, 0, stream>>>(oute, outb, sigb, (const float*)d_in[17],
                                                (const float*)d_in[18], ob);

    addback_kernel<<<(BATCH * CD * LSZ) / 256, 256, 0, stream>>>(e_f, oe, xe);
    addback_kernel<<<(BATCH * CD * LSZ) / 256, 256, 0, stream>>>(b_f, ob, xb);

    ln2_kernel<<<NWIN, 256, 0, stream>>>(xe, (const float*)d_in[19], (const float*)d_in[20], lne);
    ln2_kernel<<<NWIN, 256, 0, stream>>>(xb, (const float*)d_in[21], (const float*)d_in[22], lnb);

    mlp_kernel<<<MROWS / 32, 256, 0, stream>>>(lne, (const float*)d_in[23], (const float*)d_in[24],
                                               (const float*)d_in[25], (const float*)d_in[26], xe);
    mlp_kernel<<<MROWS / 32, 256, 0, stream>>>(lnb, (const float*)d_in[27], (const float*)d_in[28],
                                               (const float*)d_in[29], (const float*)d_in[30], xb);
}

// Round 2
// 4025.459 us; speedup vs baseline: 2.1565x; 2.1565x over previous
//
#include <hip/hip_runtime.h>
#include <hip/hip_bf16.h>

typedef unsigned short u16;
typedef unsigned int u32;
typedef __attribute__((ext_vector_type(8))) short s16x8;
typedef __attribute__((ext_vector_type(4))) float f32x4;

constexpr int CD    = 180;
constexpr int CP    = 192;              // K-padded channel count
constexpr int BATCH = 4;
constexpr int RES   = 128;
constexpr int LSZ   = RES * RES;        // 16384
constexpr int NHEAD = 6;
constexpr int DH    = 30;
constexpr int NTOK  = 64;
constexpr int NWIN  = 1024;
constexpr int MROWS = NWIN * NTOK;      // 65536

__device__ __forceinline__ float b2f(u16 u) { return __uint_as_float(((u32)u) << 16); }
__device__ __forceinline__ u16 f2b(float f) {
    __hip_bfloat16 h = __float2bfloat16(f);
    return *reinterpret_cast<u16*>(&h);
}

// ---------------- weight prep: fp32 [N][K] -> bf16 [Npad][Kpad] zero-padded
__global__ __launch_bounds__(256) void prep_w(const float* __restrict__ src,
        u16* __restrict__ dst, int N, int K, int Kpad, int total) {
    int i = blockIdx.x * 256 + threadIdx.x;
    if (i >= total) return;
    int n = i / Kpad, k = i - n * Kpad;
    float v = (n < N && k < K) ? src[n * K + k] : 0.f;
    dst[i] = f2b(v);
}

// ---------------- LN1 + roll(-4,-4) + window partition -> bf16 [win][tok][CP]
__global__ __launch_bounds__(256) void ln_win_kernel(
    const float* __restrict__ src, const float* __restrict__ gamma,
    const float* __restrict__ beta, u16* __restrict__ dst) {
    __shared__ float tile[NTOK][CD + 1];
    int widx = blockIdx.x;
    int b = widx >> 8, wrem = widx & 255;
    int wh = wrem >> 4, ww = wrem & 15;
    int t = threadIdx.x;
    for (int i = t; i < NTOK * CD; i += 256) {
        int c = i >> 6, pos = i & 63;
        int sh = ((wh << 3) + (pos >> 3) + 4) & 127;
        int sw = ((ww << 3) + (pos & 7) + 4) & 127;
        tile[pos][c] = src[(((size_t)b * CD + c) << 14) + (sh << 7) + sw];
    }
    __syncthreads();
    int pos = t >> 2, sub = t & 3;
    float s = 0.f, ss = 0.f;
    for (int k = 0; k < 45; ++k) {
        float v = tile[pos][sub * 45 + k];
        s += v; ss += v * v;
    }
    s += __shfl_xor(s, 1); ss += __shfl_xor(ss, 1);
    s += __shfl_xor(s, 2); ss += __shfl_xor(ss, 2);
    float mean = s * (1.f / CD);
    float rstd = rsqrtf(ss * (1.f / CD) - mean * mean + 1e-5f);
    size_t obase = ((size_t)widx * NTOK + pos) * CP;
    for (int k = 0; k < 45; ++k) {
        int c = sub * 45 + k;
        dst[obase + c] = f2b((tile[pos][c] - mean) * rstd * gamma[c] + beta[c]);
    }
    if (sub == 3) {
        for (int k = 0; k < 12; ++k) dst[obase + CD + k] = 0;
    }
}

// ---------------- MFMA gate: sig = sigmoid(A @ Wg^T + bias), A [M][CP] bf16
__global__ __launch_bounds__(256) void gemm_gate(
    const u16* __restrict__ A, const u16* __restrict__ Wb,
    const float* __restrict__ bias, u16* __restrict__ sig) {
    __shared__ __align__(16) u16 As[64 * 200];
    int rb = blockIdx.x, t = threadIdx.x;
    size_t abase = (size_t)rb * 64 * CP;
    for (int i = t; i < 64 * 24; i += 256) {
        int row = i / 24, seg = i % 24;
        *(s16x8*)&As[row * 200 + seg * 8] = *(const s16x8*)&A[abase + (size_t)row * CP + seg * 8];
    }
    __syncthreads();
    int wave = t >> 6, lane = t & 63, lr = lane & 15, lk = lane >> 4;
    s16x8 a[6];
    #pragma unroll
    for (int ks = 0; ks < 6; ++ks)
        a[ks] = *(const s16x8*)&As[(wave * 16 + lr) * 200 + ks * 32 + lk * 8];
    for (int ct = 0; ct < 12; ++ct) {
        f32x4 acc = {0.f, 0.f, 0.f, 0.f};
        #pragma unroll
        for (int ks = 0; ks < 6; ++ks) {
            s16x8 b = *(const s16x8*)&Wb[(size_t)(ct * 16 + lr) * CP + ks * 32 + lk * 8];
            acc = __builtin_amdgcn_mfma_f32_16x16x32_bf16(a[ks], b, acc, 0, 0, 0);
        }
        int c = ct * 16 + lr;
        if (c < CD) {
            float bb = bias[c];
            #pragma unroll
            for (int j = 0; j < 4; ++j) {
                int rowm = rb * 64 + wave * 16 + lk * 4 + j;
                float v = acc[j] + bb;
                v = 1.f / (1.f + __expf(-v));
                sig[(size_t)rowm * CP + c] = f2b(v);
            }
        }
    }
}

// ---------------- per (window, head): QKV + scores + softmax + PV (scalar)
__global__ __launch_bounds__(256) void attn_kernel(
    const u16* __restrict__ ew, const float* __restrict__ qkv_w,
    const float* __restrict__ qkv_b, const float* __restrict__ rpb,
    u16* __restrict__ outp) {
    __shared__ __align__(16) u16 ewt[NTOK][CD];
    __shared__ float qkvs[3][NTOK][33];
    __shared__ float sc[NTOK][65];
    int blk = blockIdx.x;
    int widx = blk / NHEAD, h = blk - widx * NHEAD;
    int wrem = widx & 255;
    int wh = wrem >> 4, ww = wrem & 15;
    int t = threadIdx.x;
    size_t wbase = (size_t)widx * NTOK * CD;       // output base (stride 180)
    size_t wb192 = (size_t)widx * NTOK * CP;       // input base (stride 192)
    for (int i = t; i < NTOK * CD; i += 256) {
        int pos = i / CD, c = i - pos * CD;
        ewt[pos][c] = ew[wb192 + (size_t)pos * CP + c];
    }
    __syncthreads();
    for (int i = t; i < 3 * NTOK * DH; i += 256) {
        int which = i / (NTOK * DH);
        int rem = i - which * (NTOK * DH);
        int pos = rem / DH, dd = rem - pos * DH;
        int row = which * CD + h * DH + dd;
        const float4* wr4 = (const float4*)(qkv_w + (size_t)row * CD);
        const ushort4* ep = (const ushort4*)ewt[pos];
        float acc = qkv_b[row];
        #pragma unroll 5
        for (int k4 = 0; k4 < 45; ++k4) {
            ushort4 e4 = ep[k4];
            float4 w4 = wr4[k4];
            acc += b2f(e4.x) * w4.x + b2f(e4.y) * w4.y + b2f(e4.z) * w4.z + b2f(e4.w) * w4.w;
        }
        if (which == 0) acc *= 0.18257418583505536f;
        qkvs[which][pos][dd] = acc;
    }
    __syncthreads();
    for (int i = t; i < NTOK * NTOK; i += 256) {
        int si = i >> 6, sj = i & 63;
        float acc = 0.f;
        #pragma unroll 6
        for (int dd = 0; dd < DH; ++dd) acc += qkvs[0][si][dd] * qkvs[1][sj][dd];
        int ih = si >> 3, iw = si & 7, jh = sj >> 3, jw = sj & 7;
        acc += rpb[((ih - jh + 7) * 15 + (iw - jw + 7)) * NHEAD + h];
        if (wh == 15 || ww == 15) {
            int hri = (wh << 3) + ih, wri = (ww << 3) + iw;
            int hrj = (wh << 3) + jh, wrj = (ww << 3) + jw;
            int ri = (hri < 120 ? 0 : (hri < 124 ? 1 : 2)) * 3 + (wri < 120 ? 0 : (wri < 124 ? 1 : 2));
            int rj = (hrj < 120 ? 0 : (hrj < 124 ? 1 : 2)) * 3 + (wrj < 120 ? 0 : (wrj < 124 ? 1 : 2));
            if (ri != rj) acc -= 100.f;
        }
        sc[si][sj] = acc;
    }
    __syncthreads();
    {
        int row = t >> 2, sub = t & 3;
        float mx = -1e30f;
        for (int k = 0; k < 16; ++k) mx = fmaxf(mx, sc[row][sub * 16 + k]);
        mx = fmaxf(mx, __shfl_xor(mx, 1));
        mx = fmaxf(mx, __shfl_xor(mx, 2));
        float sm = 0.f;
        for (int k = 0; k < 16; ++k) {
            float e = __expf(sc[row][sub * 16 + k] - mx);
            sc[row][sub * 16 + k] = e; sm += e;
        }
        sm += __shfl_xor(sm, 1);
        sm += __shfl_xor(sm, 2);
        float inv = 1.f / sm;
        for (int k = 0; k < 16; ++k) sc[row][sub * 16 + k] *= inv;
    }
    __syncthreads();
    for (int i = t; i < NTOK * DH; i += 256) {
        int pos = i / DH, dd = i - pos * DH;
        float acc = 0.f;
        #pragma unroll 8
        for (int j = 0; j < NTOK; ++j) acc += sc[pos][j] * qkvs[2][j][dd];
        outp[wbase + (size_t)pos * CD + h * DH + dd] = f2b(acc);
    }
}

// ---------------- MFMA proj: o = concat(oute*sig, outb*sig) @ Wp^T + bias
__global__ __launch_bounds__(256) void gemm_proj(
    const u16* __restrict__ oute, const u16* __restrict__ outb,
    const u16* __restrict__ sig, const u16* __restrict__ Wb,
    const float* __restrict__ bias, u16* __restrict__ o) {
    __shared__ __align__(16) u16 As[64 * 392];
    int rb = blockIdx.x, t = threadIdx.x;
    size_t rb64 = (size_t)rb * 64;
    for (int i = t; i < 64 * 45; i += 256) {
        int row = i / 45, q = i % 45;
        size_t r180 = (rb64 + row) * (size_t)CD + q * 4;
        size_t r192 = (rb64 + row) * (size_t)CP + q * 4;
        ushort4 sg = *(const ushort4*)&sig[r192];
        ushort4 oe = *(const ushort4*)&oute[r180];
        ushort4 ob = *(const ushort4*)&outb[r180];
        ushort4 re, rbv;
        re.x = f2b(b2f(oe.x) * b2f(sg.x)); re.y = f2b(b2f(oe.y) * b2f(sg.y));
        re.z = f2b(b2f(oe.z) * b2f(sg.z)); re.w = f2b(b2f(oe.w) * b2f(sg.w));
        rbv.x = f2b(b2f(ob.x) * b2f(sg.x)); rbv.y = f2b(b2f(ob.y) * b2f(sg.y));
        rbv.z = f2b(b2f(ob.z) * b2f(sg.z)); rbv.w = f2b(b2f(ob.w) * b2f(sg.w));
        *(ushort4*)&As[row * 392 + q * 4] = re;
        *(ushort4*)&As[row * 392 + 180 + q * 4] = rbv;
    }
    for (int i = t; i < 64 * 6; i += 256) {
        int row = i / 6, q = i % 6;
        ushort4 z; z.x = 0; z.y = 0; z.z = 0; z.w = 0;
        *(ushort4*)&As[row * 392 + 360 + q * 4] = z;
    }
    __syncthreads();
    int wave = t >> 6, lane = t & 63, lr = lane & 15, lk = lane >> 4;
    s16x8 a[12];
    #pragma unroll
    for (int ks = 0; ks < 12; ++ks)
        a[ks] = *(const s16x8*)&As[(wave * 16 + lr) * 392 + ks * 32 + lk * 8];
    for (int ct = 0; ct < 12; ++ct) {
        f32x4 acc = {0.f, 0.f, 0.f, 0.f};
        #pragma unroll
        for (int ks = 0; ks < 12; ++ks) {
            s16x8 b = *(const s16x8*)&Wb[(size_t)(ct * 16 + lr) * 384 + ks * 32 + lk * 8];
            acc = __builtin_amdgcn_mfma_f32_16x16x32_bf16(a[ks], b, acc, 0, 0, 0);
        }
        int c = ct * 16 + lr;
        if (c < CD) {
            float bb = bias[c];
            #pragma unroll
            for (int j = 0; j < 4; ++j) {
                size_t rowm = rb64 + wave * 16 + lk * 4 + j;
                o[rowm * CD + c] = f2b(acc[j] + bb);
            }
        }
    }
}

// ---------------- x = shortcut + unshift(window_reverse(o)), NCHW
__global__ __launch_bounds__(256) void addback_kernel(
    const float* __restrict__ src, const u16* __restrict__ o, float* __restrict__ xout) {
    size_t idx = ((size_t)blockIdx.x << 8) + threadIdx.x;
    int w = (int)(idx & 127);
    int hh = (int)((idx >> 7) & 127);
    int bc = (int)(idx >> 14);
    int c = bc % CD;
    int b = bc / CD;
    int hr = (hh - 4) & 127, wr = (w - 4) & 127;
    int win = (b << 8) + ((hr >> 3) << 4) + (wr >> 3);
    int pos = ((hr & 7) << 3) + (wr & 7);
    xout[idx] = src[idx] + b2f(o[((size_t)win * NTOK + pos) * CD + c]);
}

// ---------------- LN2 (x in NCHW) -> bf16 [row][CP]
__global__ __launch_bounds__(256) void ln2_kernel(
    const float* __restrict__ x, const float* __restrict__ gamma,
    const float* __restrict__ beta, u16* __restrict__ dst) {
    __shared__ float tile[NTOK][CD + 1];
    int blk = blockIdx.x;
    int b = blk >> 8;
    int l0 = (blk & 255) << 6;
    int t = threadIdx.x;
    for (int i = t; i < NTOK * CD; i += 256) {
        int c = i >> 6, pos = i & 63;
        tile[pos][c] = x[(((size_t)b * CD + c) << 14) + l0 + pos];
    }
    __syncthreads();
    int pos = t >> 2, sub = t & 3;
    float s = 0.f, ss = 0.f;
    for (int k = 0; k < 45; ++k) {
        float v = tile[pos][sub * 45 + k];
        s += v; ss += v * v;
    }
    s += __shfl_xor(s, 1); ss += __shfl_xor(ss, 1);
    s += __shfl_xor(s, 2); ss += __shfl_xor(ss, 2);
    float mean = s * (1.f / CD);
    float rstd = rsqrtf(ss * (1.f / CD) - mean * mean + 1e-5f);
    size_t obase = ((size_t)(b << 14) + l0 + pos) * CP;
    for (int k = 0; k < 45; ++k) {
        int c = sub * 45 + k;
        dst[obase + c] = f2b((tile[pos][c] - mean) * rstd * gamma[c] + beta[c]);
    }
    if (sub == 3) {
        for (int k = 0; k < 12; ++k) dst[obase + CD + k] = 0;
    }
}

// ---------------- MFMA fused MLP: xout += GELU(xln @ W1^T + b1) @ W2^T + b2
__global__ __launch_bounds__(256) void mlp_kernel(
    const u16* __restrict__ xln, const u16* __restrict__ W1b,
    const float* __restrict__ b1, const u16* __restrict__ W2b,
    const float* __restrict__ b2v, float* __restrict__ xout) {
    __shared__ __align__(16) u16 Xs[32 * 200];
    __shared__ __align__(16) u16 Hid[32 * 744];
    int rb = blockIdx.x, t = threadIdx.x;
    size_t xbase = (size_t)rb * 32 * CP;
    for (int i = t; i < 32 * 24; i += 256) {
        int row = i / 24, seg = i % 24;
        *(s16x8*)&Xs[row * 200 + seg * 8] = *(const s16x8*)&xln[xbase + (size_t)row * CP + seg * 8];
    }
    if (t < 64) {   // zero Hid pad cols 720..735
        int row = t >> 1, q = t & 1;
        s16x8 z = {0, 0, 0, 0, 0, 0, 0, 0};
        *(s16x8*)&Hid[row * 744 + 720 + q * 8] = z;
    }
    __syncthreads();
    int wave = t >> 6, lane = t & 63, lr = lane & 15, lk = lane >> 4;
    int rt = wave & 1, base = wave >> 1;
    // GEMM1 -> Hid (GELU)
    s16x8 a[6];
    #pragma unroll
    for (int ks = 0; ks < 6; ++ks)
        a[ks] = *(const s16x8*)&Xs[(rt * 16 + lr) * 200 + ks * 32 + lk * 8];
    for (int ct = base; ct < 45; ct += 4) {
        int ct2 = ct + 2;
        bool two = ct2 < 45;
        f32x4 acc0 = {0.f, 0.f, 0.f, 0.f};
        f32x4 acc1 = {0.f, 0.f, 0.f, 0.f};
        #pragma unroll
        for (int ks = 0; ks < 6; ++ks) {
            s16x8 b0 = *(const s16x8*)&W1b[(size_t)(ct * 16 + lr) * CP + ks * 32 + lk * 8];
            acc0 = __builtin_amdgcn_mfma_f32_16x16x32_bf16(a[ks], b0, acc0, 0, 0, 0);
            if (two) {
                s16x8 b1v = *(const s16x8*)&W1b[(size_t)(ct2 * 16 + lr) * CP + ks * 32 + lk * 8];
                acc1 = __builtin_amdgcn_mfma_f32_16x16x32_bf16(a[ks], b1v, acc1, 0, 0, 0);
            }
        }
        {
            int hcol = ct * 16 + lr;
            float bb = b1[hcol];
            #pragma unroll
            for (int j = 0; j < 4; ++j) {
                float v = acc0[j] + bb;
                v = 0.5f * v * (1.f + erff(v * 0.70710678118f));
                Hid[(rt * 16 + lk * 4 + j) * 744 + hcol] = f2b(v);
            }
        }
        if (two) {
            int hcol = ct2 * 16 + lr;
            float bb = b1[hcol];
            #pragma unroll
            for (int j = 0; j < 4; ++j) {
                float v = acc1[j] + bb;
                v = 0.5f * v * (1.f + erff(v * 0.70710678118f));
                Hid[(rt * 16 + lk * 4 + j) * 744 + hcol] = f2b(v);
            }
        }
    }
    __syncthreads();
    // GEMM2 -> xout (+bias), K=736 (pad zeros)
    for (int ct = base; ct < 12; ct += 4) {
        int ct2 = ct + 2;
        f32x4 acc0 = {0.f, 0.f, 0.f, 0.f};
        f32x4 acc1 = {0.f, 0.f, 0.f, 0.f};
        for (int ks = 0; ks < 23; ++ks) {
            s16x8 av = *(const s16x8*)&Hid[(rt * 16 + lr) * 744 + ks * 32 + lk * 8];
            s16x8 b0 = *(const s16x8*)&W2b[(size_t)(ct * 16 + lr) * 736 + ks * 32 + lk * 8];
            s16x8 b1v = *(const s16x8*)&W2b[(size_t)(ct2 * 16 + lr) * 736 + ks * 32 + lk * 8];
            acc0 = __builtin_amdgcn_mfma_f32_16x16x32_bf16(av, b0, acc0, 0, 0, 0);
            acc1 = __builtin_amdgcn_mfma_f32_16x16x32_bf16(av, b1v, acc1, 0, 0, 0);
        }
        #pragma unroll 2
        for (int which = 0; which < 2; ++which) {
            int cc = (which == 0 ? ct : ct2) * 16 + lr;
            f32x4 acc = (which == 0) ? acc0 : acc1;
            if (cc < CD) {
                float bb = b2v[cc];
                #pragma unroll
                for (int j = 0; j < 4; ++j) {
                    int m = rb * 32 + rt * 16 + lk * 4 + j;
                    xout[(((size_t)(m >> 14) * CD + cc) << 14) + (m & 16383)] += acc[j] + bb;
                }
            }
        }
    }
}

extern "C" void kernel_launch(void* const* d_in, const int* in_sizes, int n_in,
                              void* d_out, int out_size, void* d_ws, size_t ws_size,
                              hipStream_t stream) {
    const float* e_f = (const float*)d_in[0];
    const float* b_f = (const float*)d_in[1];

    const size_t S192 = (size_t)MROWS * CP;
    const size_t S180 = (size_t)MROWS * CD;
    u16* ew   = (u16*)d_ws;
    u16* bw   = ew + S192;
    u16* sige = bw + S192;
    u16* sigb = sige + S192;
    u16* oute = sigb + S192;
    u16* outb = oute + S180;
    u16* wg_e = outb + S180;
    u16* wg_b = wg_e + 192 * 192;
    u16* wp_e = wg_b + 192 * 192;
    u16* wp_b = wp_e + 192 * 384;
    u16* w1_e = wp_b + 192 * 384;
    u16* w1_b = w1_e + 720 * 192;
    u16* w2_e = w1_b + 720 * 192;
    u16* w2_b = w2_e + 192 * 736;
    // reuse after consumers finish:
    u16* oe  = ew;    u16* ob  = bw;     // proj outputs (stride 180)
    u16* lne = sige;  u16* lnb = sigb;   // ln2 outputs (stride 192)

    float* xe = (float*)d_out;
    float* xb = xe + (size_t)BATCH * CD * LSZ;

    auto prep = [&](const void* s, u16* d, int N, int K, int Kp, int Np) {
        int tot = Np * Kp;
        prep_w<<<(tot + 255) / 256, 256, 0, stream>>>((const float*)s, d, N, K, Kp, tot);
    };
    prep(d_in[10], wg_e, 180, 180, 192, 192);
    prep(d_in[12], wg_b, 180, 180, 192, 192);
    prep(d_in[15], wp_e, 180, 360, 384, 192);
    prep(d_in[17], wp_b, 180, 360, 384, 192);
    prep(d_in[23], w1_e, 720, 180, 192, 720);
    prep(d_in[27], w1_b, 720, 180, 192, 720);
    prep(d_in[25], w2_e, 180, 720, 736, 192);
    prep(d_in[29], w2_b, 180, 720, 736, 192);

    ln_win_kernel<<<NWIN, 256, 0, stream>>>(e_f, (const float*)d_in[2], (const float*)d_in[3], ew);
    ln_win_kernel<<<NWIN, 256, 0, stream>>>(b_f, (const float*)d_in[4], (const float*)d_in[5], bw);

    gemm_gate<<<MROWS / 64, 256, 0, stream>>>(ew, wg_e, (const float*)d_in[11], sige);
    gemm_gate<<<MROWS / 64, 256, 0, stream>>>(bw, wg_b, (const float*)d_in[13], sigb);

    attn_kernel<<<NWIN * NHEAD, 256, 0, stream>>>(ew, (const float*)d_in[6], (const float*)d_in[7],
                                                  (const float*)d_in[14], oute);
    attn_kernel<<<NWIN * NHEAD, 256, 0, stream>>>(bw, (const float*)d_in[8], (const float*)d_in[9],
                                                  (const float*)d_in[14], outb);

    gemm_proj<<<MROWS / 64, 256, 0, stream>>>(oute, outb, sige, wp_e, (const float*)d_in[16], oe);
    gemm_proj<<<MROWS / 64, 256, 0, stream>>>(oute, outb, sigb, wp_b, (const float*)d_in[18], ob);

    addback_kernel<<<(BATCH * CD * LSZ) / 256, 256, 0, stream>>>(e_f, oe, xe);
    addback_kernel<<<(BATCH * CD * LSZ) / 256, 256, 0, stream>>>(b_f, ob, xb);

    ln2_kernel<<<NWIN, 256, 0, stream>>>(xe, (const float*)d_in[19], (const float*)d_in[20], lne);
    ln2_kernel<<<NWIN, 256, 0, stream>>>(xb, (const float*)d_in[21], (const float*)d_in[22], lnb);

    mlp_kernel<<<MROWS / 32, 256, 0, stream>>>(lne, w1_e, (const float*)d_in[24],
                                               w2_e, (const float*)d_in[26], xe);
    mlp_kernel<<<MROWS / 32, 256, 0, stream>>>(lnb, w1_b, (const float*)d_in[28],
                                               w2_b, (const float*)d_in[30], xb);
}

// Round 3
// 1365.589 us; speedup vs baseline: 6.3568x; 2.9478x over previous
//
#include <hip/hip_runtime.h>
#include <hip/hip_bf16.h>

typedef unsigned short u16;
typedef unsigned int u32;
typedef __attribute__((ext_vector_type(8))) short s16x8;
typedef __attribute__((ext_vector_type(4))) float f32x4;

constexpr int CD    = 180;
constexpr int CP    = 192;              // K-padded channel count
constexpr int BATCH = 4;
constexpr int RES   = 128;
constexpr int LSZ   = RES * RES;        // 16384
constexpr int NHEAD = 6;
constexpr int DH    = 30;
constexpr int NTOK  = 64;
constexpr int NWIN  = 1024;
constexpr int MROWS = NWIN * NTOK;      // 65536

__device__ __forceinline__ float b2f(u16 u) { return __uint_as_float(((u32)u) << 16); }
__device__ __forceinline__ u16 f2b(float f) {
    __hip_bfloat16 h = __float2bfloat16(f);
    return *reinterpret_cast<u16*>(&h);
}

// ---------------- weight prep: fp32 [N][K] -> bf16 [Npad][Kpad] zero-padded
__global__ __launch_bounds__(256) void prep_w(const float* __restrict__ src,
        u16* __restrict__ dst, int N, int K, int Kpad, int total) {
    int i = blockIdx.x * 256 + threadIdx.x;
    if (i >= total) return;
    int n = i / Kpad, k = i - n * Kpad;
    float v = (n < N && k < K) ? src[n * K + k] : 0.f;
    dst[i] = f2b(v);
}

// ---------------- qkv weight prep: [540][180] -> packed [6 heads][96][192]
// sections q(0-31),k(32-63),v(64-95); d padded 30->32; q scale folded.
__global__ __launch_bounds__(256) void prep_wqkv(const float* __restrict__ w,
        const float* __restrict__ bsrc, u16* __restrict__ wp, float* __restrict__ bp) {
    int i = blockIdx.x * 256 + threadIdx.x;
    if (i >= 576 * 192) return;
    int r = i / 192, k = i - r * 192;
    int head = r / 96, rr = r - head * 96;
    int sec = rr >> 5, dd = rr & 31;
    int srow = sec * 180 + head * 30 + dd;
    float scale = (sec == 0) ? 0.18257418583505536f : 1.f;
    float v = (dd < 30 && k < 180) ? w[srow * 180 + k] * scale : 0.f;
    wp[i] = f2b(v);
    if (k == 0) bp[r] = (dd < 30) ? bsrc[srow] * scale : 0.f;
}

// ---------------- LN1 + roll(-4,-4) + window partition -> bf16 [win][tok][CP]
__global__ __launch_bounds__(256) void ln_win_kernel(
    const float* __restrict__ src, const float* __restrict__ gamma,
    const float* __restrict__ beta, u16* __restrict__ dst) {
    __shared__ float tile[NTOK][CD + 1];
    int widx = blockIdx.x;
    int b = widx >> 8, wrem = widx & 255;
    int wh = wrem >> 4, ww = wrem & 15;
    int t = threadIdx.x;
    for (int i = t; i < NTOK * CD; i += 256) {
        int c = i >> 6, pos = i & 63;
        int sh = ((wh << 3) + (pos >> 3) + 4) & 127;
        int sw = ((ww << 3) + (pos & 7) + 4) & 127;
        tile[pos][c] = src[(((size_t)b * CD + c) << 14) + (sh << 7) + sw];
    }
    __syncthreads();
    int pos = t >> 2, sub = t & 3;
    float s = 0.f, ss = 0.f;
    for (int k = 0; k < 45; ++k) {
        float v = tile[pos][sub * 45 + k];
        s += v; ss += v * v;
    }
    s += __shfl_xor(s, 1); ss += __shfl_xor(ss, 1);
    s += __shfl_xor(s, 2); ss += __shfl_xor(ss, 2);
    float mean = s * (1.f / CD);
    float rstd = rsqrtf(ss * (1.f / CD) - mean * mean + 1e-5f);
    size_t obase = ((size_t)widx * NTOK + pos) * CP;
    for (int k = 0; k < 45; ++k) {
        int c = sub * 45 + k;
        dst[obase + c] = f2b((tile[pos][c] - mean) * rstd * gamma[c] + beta[c]);
    }
    if (sub == 3) {
        for (int k = 0; k < 12; ++k) dst[obase + CD + k] = 0;
    }
}

// ---------------- MFMA gate: sig = sigmoid(A @ Wg^T + bias), A [M][CP] bf16
__global__ __launch_bounds__(256) void gemm_gate(
    const u16* __restrict__ A, const u16* __restrict__ Wb,
    const float* __restrict__ bias, u16* __restrict__ sig) {
    __shared__ __align__(16) u16 As[64 * 200];
    int rb = blockIdx.x, t = threadIdx.x;
    size_t abase = (size_t)rb * 64 * CP;
    for (int i = t; i < 64 * 24; i += 256) {
        int row = i / 24, seg = i % 24;
        *(s16x8*)&As[row * 200 + seg * 8] = *(const s16x8*)&A[abase + (size_t)row * CP + seg * 8];
    }
    __syncthreads();
    int wave = t >> 6, lane = t & 63, lr = lane & 15, lk = lane >> 4;
    s16x8 a[6];
    #pragma unroll
    for (int ks = 0; ks < 6; ++ks)
        a[ks] = *(const s16x8*)&As[(wave * 16 + lr) * 200 + ks * 32 + lk * 8];
    for (int ct = 0; ct < 12; ++ct) {
        f32x4 acc = {0.f, 0.f, 0.f, 0.f};
        #pragma unroll
        for (int ks = 0; ks < 6; ++ks) {
            s16x8 b = *(const s16x8*)&Wb[(size_t)(ct * 16 + lr) * CP + ks * 32 + lk * 8];
            acc = __builtin_amdgcn_mfma_f32_16x16x32_bf16(a[ks], b, acc, 0, 0, 0);
        }
        int c = ct * 16 + lr;
        if (c < CD) {
            float bb = bias[c];
            #pragma unroll
            for (int j = 0; j < 4; ++j) {
                int rowm = rb * 64 + wave * 16 + lk * 4 + j;
                float v = acc[j] + bb;
                v = 1.f / (1.f + __expf(-v));
                sig[(size_t)rowm * CP + c] = f2b(v);
            }
        }
    }
}

// ---------------- MFMA attention: one block per window, loop 6 heads
__global__ __launch_bounds__(256) void attn_mfma(
    const u16* __restrict__ ew, const u16* __restrict__ Wq,
    const float* __restrict__ Bq, const float* __restrict__ rpb,
    u16* __restrict__ outp) {
    __shared__ __align__(16) char smem[61728];
    u16*   ews  = (u16*)smem;                 // 64*200       = 25600 B
    u16*   Qs   = (u16*)(smem + 25600);       // 64*36*2      =  4608 B
    u16*   Ks   = (u16*)(smem + 30208);       // 64*36*2      =  4608 B
    u16*   Pb   = (u16*)(smem + 25600);       // 64*72*2      =  9216 B (aliases Qs+Ks)
    u16*   Vt   = (u16*)(smem + 34816);       // 32*72*2      =  4608 B
    float* Sf   = (float*)(smem + 39424);     // 64*66*4      = 16896 B
    float* rpbs = (float*)(smem + 56320);     // 1350*4       =  5400 B

    int widx = blockIdx.x;
    int wrem = widx & 255;
    int wh = wrem >> 4, ww = wrem & 15;
    bool edge = (wh == 15) || (ww == 15);
    int t = threadIdx.x;
    size_t wbase = (size_t)widx * NTOK * CD;
    size_t wb192 = (size_t)widx * NTOK * CP;

    for (int i = t; i < 64 * 24; i += 256) {
        int row = i / 24, seg = i % 24;
        *(s16x8*)&ews[row * 200 + seg * 8] = *(const s16x8*)&ew[wb192 + (size_t)row * CP + seg * 8];
    }
    for (int i = t; i < 1350; i += 256) rpbs[i] = rpb[i];
    __syncthreads();

    int wave = t >> 6, lane = t & 63, lr = lane & 15, lk = lane >> 4;
    s16x8 a[6];
    #pragma unroll
    for (int ks = 0; ks < 6; ++ks)
        a[ks] = *(const s16x8*)&ews[(wave * 16 + lr) * 200 + ks * 32 + lk * 8];

    for (int h = 0; h < NHEAD; ++h) {
        // ---- QKV for head h
        const u16* wh_base = Wq + (size_t)h * 96 * 192;
        #pragma unroll
        for (int ct = 0; ct < 6; ++ct) {
            f32x4 acc = {0.f, 0.f, 0.f, 0.f};
            #pragma unroll
            for (int ks = 0; ks < 6; ++ks) {
                s16x8 b = *(const s16x8*)&wh_base[(size_t)(ct * 16 + lr) * 192 + ks * 32 + lk * 8];
                acc = __builtin_amdgcn_mfma_f32_16x16x32_bf16(a[ks], b, acc, 0, 0, 0);
            }
            int sec = ct >> 1;
            int dd = ((ct & 1) << 4) + lr;
            float bb = Bq[h * 96 + ct * 16 + lr];
            #pragma unroll
            for (int j = 0; j < 4; ++j) {
                int tok = wave * 16 + lk * 4 + j;
                float v = acc[j] + bb;
                if (sec == 0)      Qs[tok * 36 + dd] = f2b(v);
                else if (sec == 1) Ks[tok * 36 + dd] = f2b(v);
                else               Vt[dd * 72 + tok] = f2b(v);
            }
        }
        __syncthreads();
        // ---- S = Q K^T (+rpb, +mask)
        {
            s16x8 qa = *(const s16x8*)&Qs[(wave * 16 + lr) * 36 + lk * 8];
            #pragma unroll
            for (int ct = 0; ct < 4; ++ct) {
                s16x8 kb = *(const s16x8*)&Ks[(ct * 16 + lr) * 36 + lk * 8];
                f32x4 acc = {0.f, 0.f, 0.f, 0.f};
                acc = __builtin_amdgcn_mfma_f32_16x16x32_bf16(qa, kb, acc, 0, 0, 0);
                int sj = ct * 16 + lr;
                int jh = sj >> 3, jw = sj & 7;
                #pragma unroll
                for (int j = 0; j < 4; ++j) {
                    int si = wave * 16 + lk * 4 + j;
                    int ih = si >> 3, iw = si & 7;
                    float v = acc[j] + rpbs[((ih - jh + 7) * 15 + (iw - jw + 7)) * 6 + h];
                    if (edge) {
                        int hri = (wh << 3) + ih, wri = (ww << 3) + iw;
                        int hrj = (wh << 3) + jh, wrj = (ww << 3) + jw;
                        int ri = (hri < 120 ? 0 : (hri < 124 ? 1 : 2)) * 3 + (wri < 120 ? 0 : (wri < 124 ? 1 : 2));
                        int rj = (hrj < 120 ? 0 : (hrj < 124 ? 1 : 2)) * 3 + (wrj < 120 ? 0 : (wrj < 124 ? 1 : 2));
                        if (ri != rj) v -= 100.f;
                    }
                    Sf[si * 66 + sj] = v;
                }
            }
        }
        __syncthreads();
        // ---- softmax rows + P(bf16) into Pb
        {
            int row = t >> 2, sub = t & 3;
            float mx = -1e30f;
            for (int k = 0; k < 16; ++k) mx = fmaxf(mx, Sf[row * 66 + sub * 16 + k]);
            mx = fmaxf(mx, __shfl_xor(mx, 1));
            mx = fmaxf(mx, __shfl_xor(mx, 2));
            float sm = 0.f;
            float ev[16];
            for (int k = 0; k < 16; ++k) {
                float e = __expf(Sf[row * 66 + sub * 16 + k] - mx);
                ev[k] = e; sm += e;
            }
            sm += __shfl_xor(sm, 1);
            sm += __shfl_xor(sm, 2);
            float inv = 1.f / sm;
            for (int k = 0; k < 16; ++k)
                Pb[row * 72 + sub * 16 + k] = f2b(ev[k] * inv);
        }
        __syncthreads();
        // ---- O = P V
        {
            s16x8 pa0 = *(const s16x8*)&Pb[(wave * 16 + lr) * 72 + lk * 8];
            s16x8 pa1 = *(const s16x8*)&Pb[(wave * 16 + lr) * 72 + 32 + lk * 8];
            #pragma unroll
            for (int ct = 0; ct < 2; ++ct) {
                f32x4 acc = {0.f, 0.f, 0.f, 0.f};
                s16x8 vb0 = *(const s16x8*)&Vt[(ct * 16 + lr) * 72 + lk * 8];
                s16x8 vb1 = *(const s16x8*)&Vt[(ct * 16 + lr) * 72 + 32 + lk * 8];
                acc = __builtin_amdgcn_mfma_f32_16x16x32_bf16(pa0, vb0, acc, 0, 0, 0);
                acc = __builtin_amdgcn_mfma_f32_16x16x32_bf16(pa1, vb1, acc, 0, 0, 0);
                int dd = ct * 16 + lr;
                if (dd < DH) {
                    #pragma unroll
                    for (int j = 0; j < 4; ++j) {
                        int tok = wave * 16 + lk * 4 + j;
                        outp[wbase + (size_t)tok * CD + h * DH + dd] = f2b(acc[j]);
                    }
                }
            }
        }
        __syncthreads();
    }
}

// ---------------- MFMA proj: o = concat(oute*sig, outb*sig) @ Wp^T + bias
__global__ __launch_bounds__(256) void gemm_proj(
    const u16* __restrict__ oute, const u16* __restrict__ outb,
    const u16* __restrict__ sig, const u16* __restrict__ Wb,
    const float* __restrict__ bias, u16* __restrict__ o) {
    __shared__ __align__(16) u16 As[64 * 392];
    int rb = blockIdx.x, t = threadIdx.x;
    size_t rb64 = (size_t)rb * 64;
    for (int i = t; i < 64 * 45; i += 256) {
        int row = i / 45, q = i % 45;
        size_t r180 = (rb64 + row) * (size_t)CD + q * 4;
        size_t r192 = (rb64 + row) * (size_t)CP + q * 4;
        ushort4 sg = *(const ushort4*)&sig[r192];
        ushort4 oe = *(const ushort4*)&oute[r180];
        ushort4 ob = *(const ushort4*)&outb[r180];
        ushort4 re, rbv;
        re.x = f2b(b2f(oe.x) * b2f(sg.x)); re.y = f2b(b2f(oe.y) * b2f(sg.y));
        re.z = f2b(b2f(oe.z) * b2f(sg.z)); re.w = f2b(b2f(oe.w) * b2f(sg.w));
        rbv.x = f2b(b2f(ob.x) * b2f(sg.x)); rbv.y = f2b(b2f(ob.y) * b2f(sg.y));
        rbv.z = f2b(b2f(ob.z) * b2f(sg.z)); rbv.w = f2b(b2f(ob.w) * b2f(sg.w));
        *(ushort4*)&As[row * 392 + q * 4] = re;
        *(ushort4*)&As[row * 392 + 180 + q * 4] = rbv;
    }
    for (int i = t; i < 64 * 6; i += 256) {
        int row = i / 6, q = i % 6;
        ushort4 z; z.x = 0; z.y = 0; z.z = 0; z.w = 0;
        *(ushort4*)&As[row * 392 + 360 + q * 4] = z;
    }
    __syncthreads();
    int wave = t >> 6, lane = t & 63, lr = lane & 15, lk = lane >> 4;
    s16x8 a[12];
    #pragma unroll
    for (int ks = 0; ks < 12; ++ks)
        a[ks] = *(const s16x8*)&As[(wave * 16 + lr) * 392 + ks * 32 + lk * 8];
    for (int ct = 0; ct < 12; ++ct) {
        f32x4 acc = {0.f, 0.f, 0.f, 0.f};
        #pragma unroll
        for (int ks = 0; ks < 12; ++ks) {
            s16x8 b = *(const s16x8*)&Wb[(size_t)(ct * 16 + lr) * 384 + ks * 32 + lk * 8];
            acc = __builtin_amdgcn_mfma_f32_16x16x32_bf16(a[ks], b, acc, 0, 0, 0);
        }
        int c = ct * 16 + lr;
        if (c < CD) {
            float bb = bias[c];
            #pragma unroll
            for (int j = 0; j < 4; ++j) {
                size_t rowm = rb64 + wave * 16 + lk * 4 + j;
                o[rowm * CD + c] = f2b(acc[j] + bb);
            }
        }
    }
}

// ---------------- x = shortcut + unshift(window_reverse(o)), NCHW
__global__ __launch_bounds__(256) void addback_kernel(
    const float* __restrict__ src, const u16* __restrict__ o, float* __restrict__ xout) {
    size_t idx = ((size_t)blockIdx.x << 8) + threadIdx.x;
    int w = (int)(idx & 127);
    int hh = (int)((idx >> 7) & 127);
    int bc = (int)(idx >> 14);
    int c = bc % CD;
    int b = bc / CD;
    int hr = (hh - 4) & 127, wr = (w - 4) & 127;
    int win = (b << 8) + ((hr >> 3) << 4) + (wr >> 3);
    int pos = ((hr & 7) << 3) + (wr & 7);
    xout[idx] = src[idx] + b2f(o[((size_t)win * NTOK + pos) * CD + c]);
}

// ---------------- LN2 (x in NCHW) -> bf16 [row][CP]
__global__ __launch_bounds__(256) void ln2_kernel(
    const float* __restrict__ x, const float* __restrict__ gamma,
    const float* __restrict__ beta, u16* __restrict__ dst) {
    __shared__ float tile[NTOK][CD + 1];
    int blk = blockIdx.x;
    int b = blk >> 8;
    int l0 = (blk & 255) << 6;
    int t = threadIdx.x;
    for (int i = t; i < NTOK * CD; i += 256) {
        int c = i >> 6, pos = i & 63;
        tile[pos][c] = x[(((size_t)b * CD + c) << 14) + l0 + pos];
    }
    __syncthreads();
    int pos = t >> 2, sub = t & 3;
    float s = 0.f, ss = 0.f;
    for (int k = 0; k < 45; ++k) {
        float v = tile[pos][sub * 45 + k];
        s += v; ss += v * v;
    }
    s += __shfl_xor(s, 1); ss += __shfl_xor(ss, 1);
    s += __shfl_xor(s, 2); ss += __shfl_xor(ss, 2);
    float mean = s * (1.f / CD);
    float rstd = rsqrtf(ss * (1.f / CD) - mean * mean + 1e-5f);
    size_t obase = ((size_t)(b << 14) + l0 + pos) * CP;
    for (int k = 0; k < 45; ++k) {
        int c = sub * 45 + k;
        dst[obase + c] = f2b((tile[pos][c] - mean) * rstd * gamma[c] + beta[c]);
    }
    if (sub == 3) {
        for (int k = 0; k < 12; ++k) dst[obase + CD + k] = 0;
    }
}

// ---------------- MFMA fused MLP: xout += GELU(xln @ W1^T + b1) @ W2^T + b2
__global__ __launch_bounds__(256) void mlp_kernel(
    const u16* __restrict__ xln, const u16* __restrict__ W1b,
    const float* __restrict__ b1, const u16* __restrict__ W2b,
    const float* __restrict__ b2v, float* __restrict__ xout) {
    __shared__ __align__(16) u16 Xs[32 * 200];
    __shared__ __align__(16) u16 Hid[32 * 744];
    int rb = blockIdx.x, t = threadIdx.x;
    size_t xbase = (size_t)rb * 32 * CP;
    for (int i = t; i < 32 * 24; i += 256) {
        int row = i / 24, seg = i % 24;
        *(s16x8*)&Xs[row * 200 + seg * 8] = *(const s16x8*)&xln[xbase + (size_t)row * CP + seg * 8];
    }
    if (t < 64) {
        int row = t >> 1, q = t & 1;
        s16x8 z = {0, 0, 0, 0, 0, 0, 0, 0};
        *(s16x8*)&Hid[row * 744 + 720 + q * 8] = z;
    }
    __syncthreads();
    int wave = t >> 6, lane = t & 63, lr = lane & 15, lk = lane >> 4;
    int rt = wave & 1, base = wave >> 1;
    s16x8 a[6];
    #pragma unroll
    for (int ks = 0; ks < 6; ++ks)
        a[ks] = *(const s16x8*)&Xs[(rt * 16 + lr) * 200 + ks * 32 + lk * 8];
    for (int ct = base; ct < 45; ct += 4) {
        int ct2 = ct + 2;
        bool two = ct2 < 45;
        f32x4 acc0 = {0.f, 0.f, 0.f, 0.f};
        f32x4 acc1 = {0.f, 0.f, 0.f, 0.f};
        #pragma unroll
        for (int ks = 0; ks < 6; ++ks) {
            s16x8 b0 = *(const s16x8*)&W1b[(size_t)(ct * 16 + lr) * CP + ks * 32 + lk * 8];
            acc0 = __builtin_amdgcn_mfma_f32_16x16x32_bf16(a[ks], b0, acc0, 0, 0, 0);
            if (two) {
                s16x8 b1v = *(const s16x8*)&W1b[(size_t)(ct2 * 16 + lr) * CP + ks * 32 + lk * 8];
                acc1 = __builtin_amdgcn_mfma_f32_16x16x32_bf16(a[ks], b1v, acc1, 0, 0, 0);
            }
        }
        {
            int hcol = ct * 16 + lr;
            float bb = b1[hcol];
            #pragma unroll
            for (int j = 0; j < 4; ++j) {
                float v = acc0[j] + bb;
                v = 0.5f * v * (1.f + erff(v * 0.70710678118f));
                Hid[(rt * 16 + lk * 4 + j) * 744 + hcol] = f2b(v);
            }
        }
        if (two) {
            int hcol = ct2 * 16 + lr;
            float bb = b1[hcol];
            #pragma unroll
            for (int j = 0; j < 4; ++j) {
                float v = acc1[j] + bb;
                v = 0.5f * v * (1.f + erff(v * 0.70710678118f));
                Hid[(rt * 16 + lk * 4 + j) * 744 + hcol] = f2b(v);
            }
        }
    }
    __syncthreads();
    for (int ct = base; ct < 12; ct += 4) {
        int ct2 = ct + 2;
        f32x4 acc0 = {0.f, 0.f, 0.f, 0.f};
        f32x4 acc1 = {0.f, 0.f, 0.f, 0.f};
        for (int ks = 0; ks < 23; ++ks) {
            s16x8 av = *(const s16x8*)&Hid[(rt * 16 + lr) * 744 + ks * 32 + lk * 8];
            s16x8 b0 = *(const s16x8*)&W2b[(size_t)(ct * 16 + lr) * 736 + ks * 32 + lk * 8];
            s16x8 b1v = *(const s16x8*)&W2b[(size_t)(ct2 * 16 + lr) * 736 + ks * 32 + lk * 8];
            acc0 = __builtin_amdgcn_mfma_f32_16x16x32_bf16(av, b0, acc0, 0, 0, 0);
            acc1 = __builtin_amdgcn_mfma_f32_16x16x32_bf16(av, b1v, acc1, 0, 0, 0);
        }
        #pragma unroll 2
        for (int which = 0; which < 2; ++which) {
            int cc = (which == 0 ? ct : ct2) * 16 + lr;
            f32x4 acc = (which == 0) ? acc0 : acc1;
            if (cc < CD) {
                float bb = b2v[cc];
                #pragma unroll
                for (int j = 0; j < 4; ++j) {
                    int m = rb * 32 + rt * 16 + lk * 4 + j;
                    xout[(((size_t)(m >> 14) * CD + cc) << 14) + (m & 16383)] += acc[j] + bb;
                }
            }
        }
    }
}

extern "C" void kernel_launch(void* const* d_in, const int* in_sizes, int n_in,
                              void* d_out, int out_size, void* d_ws, size_t ws_size,
                              hipStream_t stream) {
    const float* e_f = (const float*)d_in[0];
    const float* b_f = (const float*)d_in[1];

    const size_t S192 = (size_t)MROWS * CP;
    const size_t S180 = (size_t)MROWS * CD;
    u16* ew   = (u16*)d_ws;
    u16* bw   = ew + S192;
    u16* sige = bw + S192;
    u16* sigb = sige + S192;
    u16* oute = sigb + S192;
    u16* outb = oute + S180;
    u16* wg_e = outb + S180;
    u16* wg_b = wg_e + 192 * 192;
    u16* wp_e = wg_b + 192 * 192;
    u16* wp_b = wp_e + 192 * 384;
    u16* w1_e = wp_b + 192 * 384;
    u16* w1_b = w1_e + 720 * 192;
    u16* w2_e = w1_b + 720 * 192;
    u16* w2_b = w2_e + 192 * 736;
    u16* wq_e = w2_b + 192 * 736;        // 576*192
    u16* wq_b = wq_e + 576 * 192;
    float* bq_e = (float*)(wq_b + 576 * 192);   // 576
    float* bq_b = bq_e + 576;
    // reuse after consumers finish:
    u16* oe  = ew;    u16* ob  = bw;     // proj outputs (stride 180)
    u16* lne = sige;  u16* lnb = sigb;   // ln2 outputs (stride 192)

    float* xe = (float*)d_out;
    float* xb = xe + (size_t)BATCH * CD * LSZ;

    auto prep = [&](const void* s, u16* d, int N, int K, int Kp, int Np) {
        int tot = Np * Kp;
        prep_w<<<(tot + 255) / 256, 256, 0, stream>>>((const float*)s, d, N, K, Kp, tot);
    };
    prep(d_in[10], wg_e, 180, 180, 192, 192);
    prep(d_in[12], wg_b, 180, 180, 192, 192);
    prep(d_in[15], wp_e, 180, 360, 384, 192);
    prep(d_in[17], wp_b, 180, 360, 384, 192);
    prep(d_in[23], w1_e, 720, 180, 192, 720);
    prep(d_in[27], w1_b, 720, 180, 192, 720);
    prep(d_in[25], w2_e, 180, 720, 736, 192);
    prep(d_in[29], w2_b, 180, 720, 736, 192);
    prep_wqkv<<<(576 * 192 + 255) / 256, 256, 0, stream>>>(
        (const float*)d_in[6], (const float*)d_in[7], wq_e, bq_e);
    prep_wqkv<<<(576 * 192 + 255) / 256, 256, 0, stream>>>(
        (const float*)d_in[8], (const float*)d_in[9], wq_b, bq_b);

    ln_win_kernel<<<NWIN, 256, 0, stream>>>(e_f, (const float*)d_in[2], (const float*)d_in[3], ew);
    ln_win_kernel<<<NWIN, 256, 0, stream>>>(b_f, (const float*)d_in[4], (const float*)d_in[5], bw);

    gemm_gate<<<MROWS / 64, 256, 0, stream>>>(ew, wg_e, (const float*)d_in[11], sige);
    gemm_gate<<<MROWS / 64, 256, 0, stream>>>(bw, wg_b, (const float*)d_in[13], sigb);

    attn_mfma<<<NWIN, 256, 0, stream>>>(ew, wq_e, bq_e, (const float*)d_in[14], oute);
    attn_mfma<<<NWIN, 256, 0, stream>>>(bw, wq_b, bq_b, (const float*)d_in[14], outb);

    gemm_proj<<<MROWS / 64, 256, 0, stream>>>(oute, outb, sige, wp_e, (const float*)d_in[16], oe);
    gemm_proj<<<MROWS / 64, 256, 0, stream>>>(oute, outb, sigb, wp_b, (const float*)d_in[18], ob);

    addback_kernel<<<(BATCH * CD * LSZ) / 256, 256, 0, stream>>>(e_f, oe, xe);
    addback_kernel<<<(BATCH * CD * LSZ) / 256, 256, 0, stream>>>(b_f, ob, xb);

    ln2_kernel<<<NWIN, 256, 0, stream>>>(xe, (const float*)d_in[19], (const float*)d_in[20], lne);
    ln2_kernel<<<NWIN, 256, 0, stream>>>(xb, (const float*)d_in[21], (const float*)d_in[22], lnb);

    mlp_kernel<<<MROWS / 32, 256, 0, stream>>>(lne, w1_e, (const float*)d_in[24],
                                               w2_e, (const float*)d_in[26], xe);
    mlp_kernel<<<MROWS / 32, 256, 0, stream>>>(lnb, w1_b, (const float*)d_in[28],
                                               w2_b, (const float*)d_in[30], xb);
}

// Round 4
// 1003.996 us; speedup vs baseline: 8.6462x; 1.3602x over previous
//
#include <hip/hip_runtime.h>
#include <hip/hip_bf16.h>

typedef unsigned short u16;
typedef unsigned int u32;
typedef __attribute__((ext_vector_type(8))) short s16x8;
typedef __attribute__((ext_vector_type(4))) float f32x4;

constexpr int CD    = 180;
constexpr int CP    = 192;              // K-padded channel count
constexpr int BATCH = 4;
constexpr int RES   = 128;
constexpr int LSZ   = RES * RES;        // 16384
constexpr int NHEAD = 6;
constexpr int DH    = 30;
constexpr int NTOK  = 64;
constexpr int NWIN  = 1024;
constexpr int MROWS = NWIN * NTOK;      // 65536

__device__ __forceinline__ float b2f(u16 u) { return __uint_as_float(((u32)u) << 16); }
__device__ __forceinline__ u16 f2b(float f) {
    __hip_bfloat16 h = __float2bfloat16(f);
    return *reinterpret_cast<u16*>(&h);
}

// ---------------- weight prep: fp32 [N][K] -> bf16 fragment-major
// dst[((ct*nks + ks)*64 + lk*16 + lr)*8 + e] = src[ct*16+lr][ks*32+lk*8+e]
__global__ __launch_bounds__(256) void prep_wfrag(const float* __restrict__ src,
        u16* __restrict__ dst, int N, int K, int nks, int total) {
    int i = blockIdx.x * 256 + threadIdx.x;
    if (i >= total) return;
    int e = i & 7, lr = (i >> 3) & 15, lk = (i >> 7) & 3, rest = i >> 9;
    int ks = rest % nks, ct = rest / nks;
    int n = ct * 16 + lr, k = ks * 32 + lk * 8 + e;
    float v = (n < N && k < K) ? src[n * K + k] : 0.f;
    dst[i] = f2b(v);
}

// ---------------- qkv weight prep -> per-head fragment-major [6][6ct][6ks][64][8]
// sections q(rr 0-31),k(32-63),v(64-95); d padded 30->32; q scale folded.
__global__ __launch_bounds__(256) void prep_wqkv(const float* __restrict__ w,
        const float* __restrict__ bsrc, u16* __restrict__ wp, float* __restrict__ bp) {
    int i = blockIdx.x * 256 + threadIdx.x;
    if (i >= 576 * 192) return;
    int e = i & 7, lr = (i >> 3) & 15, lk = (i >> 7) & 3, rest = i >> 9;
    int ks = rest % 6, rest2 = rest / 6;
    int ct = rest2 % 6, head = rest2 / 6;
    int rr = ct * 16 + lr;
    int sec = rr >> 5, dd = rr & 31;
    int srow = sec * 180 + head * 30 + dd;
    int k = ks * 32 + lk * 8 + e;
    float scale = (sec == 0) ? 0.18257418583505536f : 1.f;
    float v = (dd < 30 && k < 180) ? w[srow * 180 + k] * scale : 0.f;
    wp[i] = f2b(v);
    if (ks == 0 && lk == 0 && e == 0)
        bp[head * 96 + rr] = (dd < 30) ? bsrc[srow] * scale : 0.f;
}

// ---------------- LN1 + roll(-4,-4) + window partition -> bf16 [win][tok][CP]
__global__ __launch_bounds__(256) void ln_win_kernel(
    const float* __restrict__ src, const float* __restrict__ gamma,
    const float* __restrict__ beta, u16* __restrict__ dst) {
    __shared__ float tile[NTOK][CD + 1];
    int widx = blockIdx.x;
    int b = widx >> 8, wrem = widx & 255;
    int wh = wrem >> 4, ww = wrem & 15;
    int t = threadIdx.x;
    for (int i = t; i < NTOK * CD; i += 256) {
        int c = i >> 6, pos = i & 63;
        int sh = ((wh << 3) + (pos >> 3) + 4) & 127;
        int sw = ((ww << 3) + (pos & 7) + 4) & 127;
        tile[pos][c] = src[(((size_t)b * CD + c) << 14) + (sh << 7) + sw];
    }
    __syncthreads();
    int pos = t >> 2, sub = t & 3;
    float s = 0.f, ss = 0.f;
    for (int k = 0; k < 45; ++k) {
        float v = tile[pos][sub * 45 + k];
        s += v; ss += v * v;
    }
    s += __shfl_xor(s, 1); ss += __shfl_xor(ss, 1);
    s += __shfl_xor(s, 2); ss += __shfl_xor(ss, 2);
    float mean = s * (1.f / CD);
    float rstd = rsqrtf(ss * (1.f / CD) - mean * mean + 1e-5f);
    size_t obase = ((size_t)widx * NTOK + pos) * CP;
    for (int k = 0; k < 45; ++k) {
        int c = sub * 45 + k;
        dst[obase + c] = f2b((tile[pos][c] - mean) * rstd * gamma[c] + beta[c]);
    }
    if (sub == 3) {
        for (int k = 0; k < 12; ++k) dst[obase + CD + k] = 0;
    }
}

// ---------------- MFMA gate: sig = sigmoid(A @ Wg^T + bias)
__global__ __launch_bounds__(256) void gemm_gate(
    const u16* __restrict__ A, const u16* __restrict__ Wb,
    const float* __restrict__ bias, u16* __restrict__ sig) {
    __shared__ __align__(16) u16 As[64 * 200];
    int rb = blockIdx.x, t = threadIdx.x;
    size_t abase = (size_t)rb * 64 * CP;
    for (int i = t; i < 64 * 24; i += 256) {
        int row = i / 24, seg = i % 24;
        *(s16x8*)&As[row * 200 + seg * 8] = *(const s16x8*)&A[abase + (size_t)row * CP + seg * 8];
    }
    __syncthreads();
    int wave = t >> 6, lane = t & 63, lr = lane & 15, lk = lane >> 4;
    s16x8 a[6];
    #pragma unroll
    for (int ks = 0; ks < 6; ++ks)
        a[ks] = *(const s16x8*)&As[(wave * 16 + lr) * 200 + ks * 32 + lk * 8];
    for (int ct = 0; ct < 12; ++ct) {
        f32x4 acc = {0.f, 0.f, 0.f, 0.f};
        #pragma unroll
        for (int ks = 0; ks < 6; ++ks) {
            s16x8 b = *(const s16x8*)&Wb[((size_t)(ct * 6 + ks) * 64 + lane) * 8];
            acc = __builtin_amdgcn_mfma_f32_16x16x32_bf16(a[ks], b, acc, 0, 0, 0);
        }
        int c = ct * 16 + lr;
        if (c < CD) {
            float bb = bias[c];
            #pragma unroll
            for (int j = 0; j < 4; ++j) {
                int rowm = rb * 64 + wave * 16 + lk * 4 + j;
                float v = acc[j] + bb;
                v = 1.f / (1.f + __expf(-v));
                sig[(size_t)rowm * CP + c] = f2b(v);
            }
        }
    }
}

// ---------------- MFMA attention: one block per window, loop 6 heads
__global__ __launch_bounds__(256) void attn_mfma(
    const u16* __restrict__ ew, const u16* __restrict__ Wq,
    const float* __restrict__ Bq, const float* __restrict__ rpb,
    u16* __restrict__ outp) {
    __shared__ __align__(16) char smem[61728];
    u16*   ews  = (u16*)smem;                 // 64*200       = 25600 B
    u16*   Qs   = (u16*)(smem + 25600);       // 64*36*2      =  4608 B
    u16*   Ks   = (u16*)(smem + 30208);       // 64*36*2      =  4608 B
    u16*   Pb   = (u16*)(smem + 25600);       // 64*72*2      =  9216 B (aliases Qs+Ks)
    u16*   Vt   = (u16*)(smem + 34816);       // 32*72*2      =  4608 B
    float* Sf   = (float*)(smem + 39424);     // 64*66*4      = 16896 B
    float* rpbs = (float*)(smem + 56320);     // 1350*4       =  5400 B

    int widx = blockIdx.x;
    int wrem = widx & 255;
    int wh = wrem >> 4, ww = wrem & 15;
    bool edge = (wh == 15) || (ww == 15);
    int t = threadIdx.x;
    size_t wbase = (size_t)widx * NTOK * CD;
    size_t wb192 = (size_t)widx * NTOK * CP;

    for (int i = t; i < 64 * 24; i += 256) {
        int row = i / 24, seg = i % 24;
        *(s16x8*)&ews[row * 200 + seg * 8] = *(const s16x8*)&ew[wb192 + (size_t)row * CP + seg * 8];
    }
    for (int i = t; i < 1350; i += 256) rpbs[i] = rpb[i];
    __syncthreads();

    int wave = t >> 6, lane = t & 63, lr = lane & 15, lk = lane >> 4;
    s16x8 a[6];
    #pragma unroll
    for (int ks = 0; ks < 6; ++ks)
        a[ks] = *(const s16x8*)&ews[(wave * 16 + lr) * 200 + ks * 32 + lk * 8];

    for (int h = 0; h < NHEAD; ++h) {
        // ---- QKV for head h
        #pragma unroll
        for (int ct = 0; ct < 6; ++ct) {
            f32x4 acc = {0.f, 0.f, 0.f, 0.f};
            #pragma unroll
            for (int ks = 0; ks < 6; ++ks) {
                s16x8 b = *(const s16x8*)&Wq[(((size_t)(h * 6 + ct) * 6 + ks) * 64 + lane) * 8];
                acc = __builtin_amdgcn_mfma_f32_16x16x32_bf16(a[ks], b, acc, 0, 0, 0);
            }
            int sec = ct >> 1;
            int dd = ((ct & 1) << 4) + lr;
            float bb = Bq[h * 96 + ct * 16 + lr];
            #pragma unroll
            for (int j = 0; j < 4; ++j) {
                int tok = wave * 16 + lk * 4 + j;
                float v = acc[j] + bb;
                if (sec == 0)      Qs[tok * 36 + dd] = f2b(v);
                else if (sec == 1) Ks[tok * 36 + dd] = f2b(v);
                else               Vt[dd * 72 + tok] = f2b(v);
            }
        }
        __syncthreads();
        // ---- S = Q K^T (+rpb, +mask)
        {
            s16x8 qa = *(const s16x8*)&Qs[(wave * 16 + lr) * 36 + lk * 8];
            #pragma unroll
            for (int ct = 0; ct < 4; ++ct) {
                s16x8 kb = *(const s16x8*)&Ks[(ct * 16 + lr) * 36 + lk * 8];
                f32x4 acc = {0.f, 0.f, 0.f, 0.f};
                acc = __builtin_amdgcn_mfma_f32_16x16x32_bf16(qa, kb, acc, 0, 0, 0);
                int sj = ct * 16 + lr;
                int jh = sj >> 3, jw = sj & 7;
                #pragma unroll
                for (int j = 0; j < 4; ++j) {
                    int si = wave * 16 + lk * 4 + j;
                    int ih = si >> 3, iw = si & 7;
                    float v = acc[j] + rpbs[((ih - jh + 7) * 15 + (iw - jw + 7)) * 6 + h];
                    if (edge) {
                        int hri = (wh << 3) + ih, wri = (ww << 3) + iw;
                        int hrj = (wh << 3) + jh, wrj = (ww << 3) + jw;
                        int ri = (hri < 120 ? 0 : (hri < 124 ? 1 : 2)) * 3 + (wri < 120 ? 0 : (wri < 124 ? 1 : 2));
                        int rj = (hrj < 120 ? 0 : (hrj < 124 ? 1 : 2)) * 3 + (wrj < 120 ? 0 : (wrj < 124 ? 1 : 2));
                        if (ri != rj) v -= 100.f;
                    }
                    Sf[si * 66 + sj] = v;
                }
            }
        }
        __syncthreads();
        // ---- softmax rows + P(bf16) into Pb
        {
            int row = t >> 2, sub = t & 3;
            float mx = -1e30f;
            for (int k = 0; k < 16; ++k) mx = fmaxf(mx, Sf[row * 66 + sub * 16 + k]);
            mx = fmaxf(mx, __shfl_xor(mx, 1));
            mx = fmaxf(mx, __shfl_xor(mx, 2));
            float sm = 0.f;
            float ev[16];
            for (int k = 0; k < 16; ++k) {
                float e = __expf(Sf[row * 66 + sub * 16 + k] - mx);
                ev[k] = e; sm += e;
            }
            sm += __shfl_xor(sm, 1);
            sm += __shfl_xor(sm, 2);
            float inv = 1.f / sm;
            for (int k = 0; k < 16; ++k)
                Pb[row * 72 + sub * 16 + k] = f2b(ev[k] * inv);
        }
        __syncthreads();
        // ---- O = P V
        {
            s16x8 pa0 = *(const s16x8*)&Pb[(wave * 16 + lr) * 72 + lk * 8];
            s16x8 pa1 = *(const s16x8*)&Pb[(wave * 16 + lr) * 72 + 32 + lk * 8];
            #pragma unroll
            for (int ct = 0; ct < 2; ++ct) {
                f32x4 acc = {0.f, 0.f, 0.f, 0.f};
                s16x8 vb0 = *(const s16x8*)&Vt[(ct * 16 + lr) * 72 + lk * 8];
                s16x8 vb1 = *(const s16x8*)&Vt[(ct * 16 + lr) * 72 + 32 + lk * 8];
                acc = __builtin_amdgcn_mfma_f32_16x16x32_bf16(pa0, vb0, acc, 0, 0, 0);
                acc = __builtin_amdgcn_mfma_f32_16x16x32_bf16(pa1, vb1, acc, 0, 0, 0);
                int dd = ct * 16 + lr;
                if (dd < DH) {
                    #pragma unroll
                    for (int j = 0; j < 4; ++j) {
                        int tok = wave * 16 + lk * 4 + j;
                        outp[wbase + (size_t)tok * CD + h * DH + dd] = f2b(acc[j]);
                    }
                }
            }
        }
        __syncthreads();
    }
}

// ---------------- MFMA proj: o = concat(oute*sig, outb*sig) @ Wp^T + bias
__global__ __launch_bounds__(256) void gemm_proj(
    const u16* __restrict__ oute, const u16* __restrict__ outb,
    const u16* __restrict__ sig, const u16* __restrict__ Wb,
    const float* __restrict__ bias, u16* __restrict__ o) {
    __shared__ __align__(16) u16 As[64 * 392];
    int rb = blockIdx.x, t = threadIdx.x;
    size_t rb64 = (size_t)rb * 64;
    for (int i = t; i < 64 * 45; i += 256) {
        int row = i / 45, q = i % 45;
        size_t r180 = (rb64 + row) * (size_t)CD + q * 4;
        size_t r192 = (rb64 + row) * (size_t)CP + q * 4;
        ushort4 sg = *(const ushort4*)&sig[r192];
        ushort4 oe = *(const ushort4*)&oute[r180];
        ushort4 ob = *(const ushort4*)&outb[r180];
        ushort4 re, rbv;
        re.x = f2b(b2f(oe.x) * b2f(sg.x)); re.y = f2b(b2f(oe.y) * b2f(sg.y));
        re.z = f2b(b2f(oe.z) * b2f(sg.z)); re.w = f2b(b2f(oe.w) * b2f(sg.w));
        rbv.x = f2b(b2f(ob.x) * b2f(sg.x)); rbv.y = f2b(b2f(ob.y) * b2f(sg.y));
        rbv.z = f2b(b2f(ob.z) * b2f(sg.z)); rbv.w = f2b(b2f(ob.w) * b2f(sg.w));
        *(ushort4*)&As[row * 392 + q * 4] = re;
        *(ushort4*)&As[row * 392 + 180 + q * 4] = rbv;
    }
    for (int i = t; i < 64 * 6; i += 256) {
        int row = i / 6, q = i % 6;
        ushort4 z; z.x = 0; z.y = 0; z.z = 0; z.w = 0;
        *(ushort4*)&As[row * 392 + 360 + q * 4] = z;
    }
    __syncthreads();
    int wave = t >> 6, lane = t & 63, lr = lane & 15, lk = lane >> 4;
    s16x8 a[12];
    #pragma unroll
    for (int ks = 0; ks < 12; ++ks)
        a[ks] = *(const s16x8*)&As[(wave * 16 + lr) * 392 + ks * 32 + lk * 8];
    for (int ct = 0; ct < 12; ++ct) {
        f32x4 acc = {0.f, 0.f, 0.f, 0.f};
        #pragma unroll
        for (int ks = 0; ks < 12; ++ks) {
            s16x8 b = *(const s16x8*)&Wb[((size_t)(ct * 12 + ks) * 64 + lane) * 8];
            acc = __builtin_amdgcn_mfma_f32_16x16x32_bf16(a[ks], b, acc, 0, 0, 0);
        }
        int c = ct * 16 + lr;
        if (c < CD) {
            float bb = bias[c];
            #pragma unroll
            for (int j = 0; j < 4; ++j) {
                size_t rowm = rb64 + wave * 16 + lk * 4 + j;
                o[rowm * CD + c] = f2b(acc[j] + bb);
            }
        }
    }
}

// ---------------- x = shortcut + unshift(window_reverse(o)), NCHW
__global__ __launch_bounds__(256) void addback_kernel(
    const float* __restrict__ src, const u16* __restrict__ o, float* __restrict__ xout) {
    size_t idx = ((size_t)blockIdx.x << 8) + threadIdx.x;
    int w = (int)(idx & 127);
    int hh = (int)((idx >> 7) & 127);
    int bc = (int)(idx >> 14);
    int c = bc % CD;
    int b = bc / CD;
    int hr = (hh - 4) & 127, wr = (w - 4) & 127;
    int win = (b << 8) + ((hr >> 3) << 4) + (wr >> 3);
    int pos = ((hr & 7) << 3) + (wr & 7);
    xout[idx] = src[idx] + b2f(o[((size_t)win * NTOK + pos) * CD + c]);
}

// ---------------- LN2 (x in NCHW) -> bf16 [row][CP]
__global__ __launch_bounds__(256) void ln2_kernel(
    const float* __restrict__ x, const float* __restrict__ gamma,
    const float* __restrict__ beta, u16* __restrict__ dst) {
    __shared__ float tile[NTOK][CD + 1];
    int blk = blockIdx.x;
    int b = blk >> 8;
    int l0 = (blk & 255) << 6;
    int t = threadIdx.x;
    for (int i = t; i < NTOK * CD; i += 256) {
        int c = i >> 6, pos = i & 63;
        tile[pos][c] = x[(((size_t)b * CD + c) << 14) + l0 + pos];
    }
    __syncthreads();
    int pos = t >> 2, sub = t & 3;
    float s = 0.f, ss = 0.f;
    for (int k = 0; k < 45; ++k) {
        float v = tile[pos][sub * 45 + k];
        s += v; ss += v * v;
    }
    s += __shfl_xor(s, 1); ss += __shfl_xor(ss, 1);
    s += __shfl_xor(s, 2); ss += __shfl_xor(ss, 2);
    float mean = s * (1.f / CD);
    float rstd = rsqrtf(ss * (1.f / CD) - mean * mean + 1e-5f);
    size_t obase = ((size_t)(b << 14) + l0 + pos) * CP;
    for (int k = 0; k < 45; ++k) {
        int c = sub * 45 + k;
        dst[obase + c] = f2b((tile[pos][c] - mean) * rstd * gamma[c] + beta[c]);
    }
    if (sub == 3) {
        for (int k = 0; k < 12; ++k) dst[obase + CD + k] = 0;
    }
}

// ---------------- MFMA fused MLP v2: 64 rows/block, Hid tiled 3x256, no barriers
// xout += GELU(xln @ W1^T + b1) @ W2^T + b2
__global__ __launch_bounds__(256, 4) void mlp_kernel(
    const u16* __restrict__ xln, const u16* __restrict__ W1p,
    const float* __restrict__ b1, const u16* __restrict__ W2p,
    const float* __restrict__ b2v, float* __restrict__ xout) {
    __shared__ __align__(16) u16 Hid[64 * 264];   // 33792 B; wave-private 16-row slabs
    int rb = blockIdx.x, t = threadIdx.x;
    int wave = t >> 6, lane = t & 63, lr = lane & 15, lk = lane >> 4;

    // A-fragments for GEMM1 straight from global (wave owns rows wave*16..+15)
    const u16* arow = xln + ((size_t)rb * 64 + wave * 16 + lr) * CP;
    s16x8 a[6];
    #pragma unroll
    for (int ks = 0; ks < 6; ++ks)
        a[ks] = *(const s16x8*)&arow[ks * 32 + lk * 8];

    f32x4 acc2[12];
    #pragma unroll
    for (int c = 0; c < 12; ++c) acc2[c] = (f32x4){0.f, 0.f, 0.f, 0.f};

    for (int ch = 0; ch < 3; ++ch) {
        // ---- GEMM1 chunk: hid cols [ch*256, ch*256+256), 2 ct-tiles at a time
        #pragma unroll
        for (int ct = 0; ct < 16; ct += 2) {
            int ctg0 = ch * 16 + ct, ctg1 = ctg0 + 1;
            f32x4 h0 = {0.f, 0.f, 0.f, 0.f};
            f32x4 h1 = {0.f, 0.f, 0.f, 0.f};
            #pragma unroll
            for (int ks = 0; ks < 6; ++ks) {
                s16x8 b0 = *(const s16x8*)&W1p[((size_t)(ctg0 * 6 + ks) * 64 + lane) * 8];
                s16x8 b1f = *(const s16x8*)&W1p[((size_t)(ctg1 * 6 + ks) * 64 + lane) * 8];
                h0 = __builtin_amdgcn_mfma_f32_16x16x32_bf16(a[ks], b0, h0, 0, 0, 0);
                h1 = __builtin_amdgcn_mfma_f32_16x16x32_bf16(a[ks], b1f, h1, 0, 0, 0);
            }
            #pragma unroll 2
            for (int which = 0; which < 2; ++which) {
                int ctg = which ? ctg1 : ctg0;
                f32x4 hv = which ? h1 : h0;
                int hcol = ctg * 16 + lr;
                float bb = (hcol < 720) ? b1[hcol] : 0.f;
                int lcol = (ct + which) * 16 + lr;
                #pragma unroll
                for (int j = 0; j < 4; ++j) {
                    float v = hv[j] + bb;
                    v = 0.5f * v * (1.f + erff(v * 0.70710678118f));
                    Hid[(wave * 16 + lk * 4 + j) * 264 + lcol] = f2b(v);
                }
            }
        }
        // ---- GEMM2 partial over this chunk's 256 K (wave-private rows; no barrier)
        #pragma unroll
        for (int ks = 0; ks < 8; ++ks) {
            s16x8 av = *(const s16x8*)&Hid[(wave * 16 + lr) * 264 + ks * 32 + lk * 8];
            int gks = ch * 8 + ks;
            #pragma unroll
            for (int ct = 0; ct < 12; ++ct) {
                s16x8 b = *(const s16x8*)&W2p[((size_t)(ct * 24 + gks) * 64 + lane) * 8];
                acc2[ct] = __builtin_amdgcn_mfma_f32_16x16x32_bf16(av, b, acc2[ct], 0, 0, 0);
            }
        }
    }
    // ---- epilogue: bias + accumulate into xout (NCHW)
    #pragma unroll
    for (int ct = 0; ct < 12; ++ct) {
        int cc = ct * 16 + lr;
        if (cc < CD) {
            float bb = b2v[cc];
            #pragma unroll
            for (int j = 0; j < 4; ++j) {
                int m = rb * 64 + wave * 16 + lk * 4 + j;
                xout[(((size_t)(m >> 14) * CD + cc) << 14) + (m & 16383)] += acc2[ct][j] + bb;
            }
        }
    }
}

extern "C" void kernel_launch(void* const* d_in, const int* in_sizes, int n_in,
                              void* d_out, int out_size, void* d_ws, size_t ws_size,
                              hipStream_t stream) {
    const float* e_f = (const float*)d_in[0];
    const float* b_f = (const float*)d_in[1];

    const size_t S192 = (size_t)MROWS * CP;
    const size_t S180 = (size_t)MROWS * CD;
    u16* ew   = (u16*)d_ws;
    u16* bw   = ew + S192;
    u16* sige = bw + S192;
    u16* sigb = sige + S192;
    u16* oute = sigb + S192;
    u16* outb = oute + S180;
    u16* wg_e = outb + S180;                 // 192*192
    u16* wg_b = wg_e + 192 * 192;
    u16* wp_e = wg_b + 192 * 192;            // 192*384
    u16* wp_b = wp_e + 192 * 384;
    u16* w1_e = wp_b + 192 * 384;            // 768*192
    u16* w1_b = w1_e + 768 * 192;
    u16* w2_e = w1_b + 768 * 192;            // 192*768
    u16* w2_b = w2_e + 192 * 768;
    u16* wq_e = w2_b + 192 * 768;            // 576*192
    u16* wq_b = wq_e + 576 * 192;
    float* bq_e = (float*)(wq_b + 576 * 192);   // 576
    float* bq_b = bq_e + 576;
    // reuse after consumers finish:
    u16* oe  = ew;    u16* ob  = bw;     // proj outputs (stride 180)
    u16* lne = sige;  u16* lnb = sigb;   // ln2 outputs (stride 192)

    float* xe = (float*)d_out;
    float* xb = xe + (size_t)BATCH * CD * LSZ;

    auto prep = [&](const void* s, u16* d, int N, int K, int Npad, int Kpad) {
        int tot = Npad * Kpad;
        prep_wfrag<<<(tot + 255) / 256, 256, 0, stream>>>((const float*)s, d, N, K, Kpad / 32, tot);
    };
    prep(d_in[10], wg_e, 180, 180, 192, 192);
    prep(d_in[12], wg_b, 180, 180, 192, 192);
    prep(d_in[15], wp_e, 180, 360, 192, 384);
    prep(d_in[17], wp_b, 180, 360, 192, 384);
    prep(d_in[23], w1_e, 720, 180, 768, 192);
    prep(d_in[27], w1_b, 720, 180, 768, 192);
    prep(d_in[25], w2_e, 180, 720, 192, 768);
    prep(d_in[29], w2_b, 180, 720, 192, 768);
    prep_wqkv<<<(576 * 192 + 255) / 256, 256, 0, stream>>>(
        (const float*)d_in[6], (const float*)d_in[7], wq_e, bq_e);
    prep_wqkv<<<(576 * 192 + 255) / 256, 256, 0, stream>>>(
        (const float*)d_in[8], (const float*)d_in[9], wq_b, bq_b);

    ln_win_kernel<<<NWIN, 256, 0, stream>>>(e_f, (const float*)d_in[2], (const float*)d_in[3], ew);
    ln_win_kernel<<<NWIN, 256, 0, stream>>>(b_f, (const float*)d_in[4], (const float*)d_in[5], bw);

    gemm_gate<<<MROWS / 64, 256, 0, stream>>>(ew, wg_e, (const float*)d_in[11], sige);
    gemm_gate<<<MROWS / 64, 256, 0, stream>>>(bw, wg_b, (const float*)d_in[13], sigb);

    attn_mfma<<<NWIN, 256, 0, stream>>>(ew, wq_e, bq_e, (const float*)d_in[14], oute);
    attn_mfma<<<NWIN, 256, 0, stream>>>(bw, wq_b, bq_b, (const float*)d_in[14], outb);

    gemm_proj<<<MROWS / 64, 256, 0, stream>>>(oute, outb, sige, wp_e, (const float*)d_in[16], oe);
    gemm_proj<<<MROWS / 64, 256, 0, stream>>>(oute, outb, sigb, wp_b, (const float*)d_in[18], ob);

    addback_kernel<<<(BATCH * CD * LSZ) / 256, 256, 0, stream>>>(e_f, oe, xe);
    addback_kernel<<<(BATCH * CD * LSZ) / 256, 256, 0, stream>>>(b_f, ob, xb);

    ln2_kernel<<<NWIN, 256, 0, stream>>>(xe, (const float*)d_in[19], (const float*)d_in[20], lne);
    ln2_kernel<<<NWIN, 256, 0, stream>>>(xb, (const float*)d_in[21], (const float*)d_in[22], lnb);

    mlp_kernel<<<MROWS / 64, 256, 0, stream>>>(lne, w1_e, (const float*)d_in[24],
                                               w2_e, (const float*)d_in[26], xe);
    mlp_kernel<<<MROWS / 64, 256, 0, stream>>>(lnb, w1_b, (const float*)d_in[28],
                                               w2_b, (const float*)d_in[30], xb);
}

// Round 5
// 992.050 us; speedup vs baseline: 8.7504x; 1.0120x over previous
//
#include <hip/hip_runtime.h>
#include <hip/hip_bf16.h>

typedef unsigned short u16;
typedef unsigned int u32;
typedef __attribute__((ext_vector_type(8))) short s16x8;
typedef __attribute__((ext_vector_type(4))) float f32x4;

constexpr int CD    = 180;
constexpr int CP    = 192;              // K-padded channel count
constexpr int BATCH = 4;
constexpr int RES   = 128;
constexpr int LSZ   = RES * RES;        // 16384
constexpr int NHEAD = 6;
constexpr int DH    = 30;
constexpr int NTOK  = 64;
constexpr int NWIN  = 1024;
constexpr int MROWS = NWIN * NTOK;      // 65536

__device__ __forceinline__ float b2f(u16 u) { return __uint_as_float(((u32)u) << 16); }
__device__ __forceinline__ u16 f2b(float f) {
    __hip_bfloat16 h = __float2bfloat16(f);
    return *reinterpret_cast<u16*>(&h);
}
// fast GELU (tanh form); |err vs exact erf-GELU| <~1e-3, far under threshold
__device__ __forceinline__ float gelu_f(float x) {
    float y = 0.7978845608028654f * (x + 0.044715f * x * x * x);
    float t = __expf(-2.f * fabsf(y));
    float th = (1.f - t) / (1.f + t);
    th = copysignf(th, y);
    return 0.5f * x * (1.f + th);
}

// ---------------- weight prep: fp32 [N][K] -> bf16 fragment-major
__global__ __launch_bounds__(256) void prep_wfrag(const float* __restrict__ src,
        u16* __restrict__ dst, int N, int K, int nks, int total) {
    int i = blockIdx.x * 256 + threadIdx.x;
    if (i >= total) return;
    int e = i & 7, lr = (i >> 3) & 15, lk = (i >> 7) & 3, rest = i >> 9;
    int ks = rest % nks, ct = rest / nks;
    int n = ct * 16 + lr, k = ks * 32 + lk * 8 + e;
    float v = (n < N && k < K) ? src[n * K + k] : 0.f;
    dst[i] = f2b(v);
}

// ---------------- qkv weight prep -> per-head fragment-major [6][6ct][6ks][64][8]
__global__ __launch_bounds__(256) void prep_wqkv(const float* __restrict__ w,
        const float* __restrict__ bsrc, u16* __restrict__ wp, float* __restrict__ bp) {
    int i = blockIdx.x * 256 + threadIdx.x;
    if (i >= 576 * 192) return;
    int e = i & 7, lr = (i >> 3) & 15, lk = (i >> 7) & 3, rest = i >> 9;
    int ks = rest % 6, rest2 = rest / 6;
    int ct = rest2 % 6, head = rest2 / 6;
    int rr = ct * 16 + lr;
    int sec = rr >> 5, dd = rr & 31;
    int srow = sec * 180 + head * 30 + dd;
    int k = ks * 32 + lk * 8 + e;
    float scale = (sec == 0) ? 0.18257418583505536f : 1.f;
    float v = (dd < 30 && k < 180) ? w[srow * 180 + k] * scale : 0.f;
    wp[i] = f2b(v);
    if (ks == 0 && lk == 0 && e == 0)
        bp[head * 96 + rr] = (dd < 30) ? bsrc[srow] * scale : 0.f;
}

// ---------------- LN1 + roll(-4,-4) + window partition -> bf16 [win][tok][CP]
__global__ __launch_bounds__(256) void ln_win_kernel(
    const float* __restrict__ src, const float* __restrict__ gamma,
    const float* __restrict__ beta, u16* __restrict__ dst) {
    __shared__ float tile[NTOK][CD + 1];
    int widx = blockIdx.x;
    int b = widx >> 8, wrem = widx & 255;
    int wh = wrem >> 4, ww = wrem & 15;
    int t = threadIdx.x;
    for (int i = t; i < NTOK * CD; i += 256) {
        int c = i >> 6, pos = i & 63;
        int sh = ((wh << 3) + (pos >> 3) + 4) & 127;
        int sw = ((ww << 3) + (pos & 7) + 4) & 127;
        tile[pos][c] = src[(((size_t)b * CD + c) << 14) + (sh << 7) + sw];
    }
    __syncthreads();
    int pos = t >> 2, sub = t & 3;
    float s = 0.f, ss = 0.f;
    for (int k = 0; k < 45; ++k) {
        float v = tile[pos][sub * 45 + k];
        s += v; ss += v * v;
    }
    s += __shfl_xor(s, 1); ss += __shfl_xor(ss, 1);
    s += __shfl_xor(s, 2); ss += __shfl_xor(ss, 2);
    float mean = s * (1.f / CD);
    float rstd = rsqrtf(ss * (1.f / CD) - mean * mean + 1e-5f);
    size_t obase = ((size_t)widx * NTOK + pos) * CP;
    for (int k = 0; k < 45; ++k) {
        int c = sub * 45 + k;
        dst[obase + c] = f2b((tile[pos][c] - mean) * rstd * gamma[c] + beta[c]);
    }
    if (sub == 3) {
        for (int k = 0; k < 12; ++k) dst[obase + CD + k] = 0;
    }
}

// ---------------- MFMA gate: sig = sigmoid(A @ Wg^T + bias)
__global__ __launch_bounds__(256) void gemm_gate(
    const u16* __restrict__ A, const u16* __restrict__ Wb,
    const float* __restrict__ bias, u16* __restrict__ sig) {
    __shared__ __align__(16) u16 As[64 * 200];
    int rb = blockIdx.x, t = threadIdx.x;
    size_t abase = (size_t)rb * 64 * CP;
    for (int i = t; i < 64 * 24; i += 256) {
        int row = i / 24, seg = i % 24;
        *(s16x8*)&As[row * 200 + seg * 8] = *(const s16x8*)&A[abase + (size_t)row * CP + seg * 8];
    }
    __syncthreads();
    int wave = t >> 6, lane = t & 63, lr = lane & 15, lk = lane >> 4;
    s16x8 a[6];
    #pragma unroll
    for (int ks = 0; ks < 6; ++ks)
        a[ks] = *(const s16x8*)&As[(wave * 16 + lr) * 200 + ks * 32 + lk * 8];
    for (int ct = 0; ct < 12; ++ct) {
        f32x4 acc = {0.f, 0.f, 0.f, 0.f};
        #pragma unroll
        for (int ks = 0; ks < 6; ++ks) {
            s16x8 b = *(const s16x8*)&Wb[((size_t)(ct * 6 + ks) * 64 + lane) * 8];
            acc = __builtin_amdgcn_mfma_f32_16x16x32_bf16(a[ks], b, acc, 0, 0, 0);
        }
        int c = ct * 16 + lr;
        if (c < CD) {
            float bb = bias[c];
            #pragma unroll
            for (int j = 0; j < 4; ++j) {
                int rowm = rb * 64 + wave * 16 + lk * 4 + j;
                float v = acc[j] + bb;
                v = 1.f / (1.f + __expf(-v));
                sig[(size_t)rowm * CP + c] = f2b(v);
            }
        }
    }
}

// ---------------- MFMA attention v2: in-register softmax, aliased LDS (28.4 KB)
__global__ __launch_bounds__(256) void attn_mfma(
    const u16* __restrict__ ew, const u16* __restrict__ Wq,
    const float* __restrict__ Bq, const float* __restrict__ rpb,
    u16* __restrict__ outp) {
    __shared__ __align__(16) char smem[28448];
    u16*   ews  = (u16*)smem;                 // 64*200*2 = 25600 B (staging, dies)
    u16*   Qs   = (u16*)smem;                 // 64*36*2  =  4608
    u16*   Ks   = (u16*)(smem + 4608);        // 64*36*2  =  4608
    u16*   Vt   = (u16*)(smem + 9216);        // 32*72*2  =  4608
    u16*   Pb   = (u16*)(smem + 13824);       // 64*72*2  =  9216
    float* rpbs = (float*)(smem + 23040);     // 1350*4   =  5400  (total 28440)

    int widx = blockIdx.x;
    int wrem = widx & 255;
    int wh = wrem >> 4, ww = wrem & 15;
    bool edge = (wh == 15) || (ww == 15);
    int t = threadIdx.x;
    size_t wbase = (size_t)widx * NTOK * CD;
    size_t wb192 = (size_t)widx * NTOK * CP;

    for (int i = t; i < 64 * 24; i += 256) {
        int row = i / 24, seg = i % 24;
        *(s16x8*)&ews[row * 200 + seg * 8] = *(const s16x8*)&ew[wb192 + (size_t)row * CP + seg * 8];
    }
    __syncthreads();

    int wave = t >> 6, lane = t & 63, lr = lane & 15, lk = lane >> 4;
    s16x8 a[6];
    #pragma unroll
    for (int ks = 0; ks < 6; ++ks)
        a[ks] = *(const s16x8*)&ews[(wave * 16 + lr) * 200 + ks * 32 + lk * 8];
    __syncthreads();   // all waves done reading ews; region reusable

    for (int i = t; i < 1350; i += 256) rpbs[i] = rpb[i];  // visible after next barrier

    for (int h = 0; h < NHEAD; ++h) {
        // ---- QKV for head h
        #pragma unroll
        for (int ct = 0; ct < 6; ++ct) {
            f32x4 acc = {0.f, 0.f, 0.f, 0.f};
            #pragma unroll
            for (int ks = 0; ks < 6; ++ks) {
                s16x8 b = *(const s16x8*)&Wq[(((size_t)(h * 6 + ct) * 6 + ks) * 64 + lane) * 8];
                acc = __builtin_amdgcn_mfma_f32_16x16x32_bf16(a[ks], b, acc, 0, 0, 0);
            }
            int sec = ct >> 1;
            int dd = ((ct & 1) << 4) + lr;
            float bb = Bq[h * 96 + ct * 16 + lr];
            #pragma unroll
            for (int j = 0; j < 4; ++j) {
                int tok = wave * 16 + lk * 4 + j;
                float v = acc[j] + bb;
                if (sec == 0)      Qs[tok * 36 + dd] = f2b(v);
                else if (sec == 1) Ks[tok * 36 + dd] = f2b(v);
                else               Vt[dd * 72 + tok] = f2b(v);
            }
        }
        __syncthreads();
        // ---- S = Q K^T (+rpb, +mask) in registers
        f32x4 sv[4];
        {
            s16x8 qa = *(const s16x8*)&Qs[(wave * 16 + lr) * 36 + lk * 8];
            #pragma unroll
            for (int ct = 0; ct < 4; ++ct) {
                s16x8 kb = *(const s16x8*)&Ks[(ct * 16 + lr) * 36 + lk * 8];
                f32x4 z = {0.f, 0.f, 0.f, 0.f};
                sv[ct] = __builtin_amdgcn_mfma_f32_16x16x32_bf16(qa, kb, z, 0, 0, 0);
            }
            #pragma unroll
            for (int ct = 0; ct < 4; ++ct) {
                int sj = ct * 16 + lr;
                int jh = sj >> 3, jw = sj & 7;
                #pragma unroll
                for (int j = 0; j < 4; ++j) {
                    int si = wave * 16 + lk * 4 + j;
                    int ih = si >> 3, iw = si & 7;
                    float v = sv[ct][j] + rpbs[((ih - jh + 7) * 15 + (iw - jw + 7)) * 6 + h];
                    if (edge) {
                        int hri = (wh << 3) + ih, wri = (ww << 3) + iw;
                        int hrj = (wh << 3) + jh, wrj = (ww << 3) + jw;
                        int ri = (hri < 120 ? 0 : (hri < 124 ? 1 : 2)) * 3 + (wri < 120 ? 0 : (wri < 124 ? 1 : 2));
                        int rj = (hrj < 120 ? 0 : (hrj < 124 ? 1 : 2)) * 3 + (wrj < 120 ? 0 : (wrj < 124 ? 1 : 2));
                        if (ri != rj) v -= 100.f;
                    }
                    sv[ct][j] = v;
                }
            }
        }
        __syncthreads();   // Qs/Ks reads complete before Pb (distinct) / next use
        // ---- in-register softmax per row (16-lane lr group holds one row)
        #pragma unroll
        for (int j = 0; j < 4; ++j) {
            float mx = fmaxf(fmaxf(sv[0][j], sv[1][j]), fmaxf(sv[2][j], sv[3][j]));
            mx = fmaxf(mx, __shfl_xor(mx, 1));
            mx = fmaxf(mx, __shfl_xor(mx, 2));
            mx = fmaxf(mx, __shfl_xor(mx, 4));
            mx = fmaxf(mx, __shfl_xor(mx, 8));
            float e0 = __expf(sv[0][j] - mx);
            float e1 = __expf(sv[1][j] - mx);
            float e2 = __expf(sv[2][j] - mx);
            float e3 = __expf(sv[3][j] - mx);
            float sm = e0 + e1 + e2 + e3;
            sm += __shfl_xor(sm, 1);
            sm += __shfl_xor(sm, 2);
            sm += __shfl_xor(sm, 4);
            sm += __shfl_xor(sm, 8);
            float inv = 1.f / sm;
            int row = wave * 16 + lk * 4 + j;
            Pb[row * 72 +      lr] = f2b(e0 * inv);
            Pb[row * 72 + 16 + lr] = f2b(e1 * inv);
            Pb[row * 72 + 32 + lr] = f2b(e2 * inv);
            Pb[row * 72 + 48 + lr] = f2b(e3 * inv);
        }
        __syncthreads();
        // ---- O = P V
        {
            s16x8 pa0 = *(const s16x8*)&Pb[(wave * 16 + lr) * 72 + lk * 8];
            s16x8 pa1 = *(const s16x8*)&Pb[(wave * 16 + lr) * 72 + 32 + lk * 8];
            #pragma unroll
            for (int ct = 0; ct < 2; ++ct) {
                f32x4 acc = {0.f, 0.f, 0.f, 0.f};
                s16x8 vb0 = *(const s16x8*)&Vt[(ct * 16 + lr) * 72 + lk * 8];
                s16x8 vb1 = *(const s16x8*)&Vt[(ct * 16 + lr) * 72 + 32 + lk * 8];
                acc = __builtin_amdgcn_mfma_f32_16x16x32_bf16(pa0, vb0, acc, 0, 0, 0);
                acc = __builtin_amdgcn_mfma_f32_16x16x32_bf16(pa1, vb1, acc, 0, 0, 0);
                int dd = ct * 16 + lr;
                if (dd < DH) {
                    #pragma unroll
                    for (int j = 0; j < 4; ++j) {
                        int tok = wave * 16 + lk * 4 + j;
                        outp[wbase + (size_t)tok * CD + h * DH + dd] = f2b(acc[j]);
                    }
                }
            }
        }
        __syncthreads();   // Pb/Vt reads done before next head's writes
    }
}

// ---------------- MFMA proj fused with addback: xout = src + unshift(win_rev(proj))
__global__ __launch_bounds__(256) void gemm_proj_add(
    const u16* __restrict__ oute, const u16* __restrict__ outb,
    const u16* __restrict__ sig, const u16* __restrict__ Wb,
    const float* __restrict__ bias, const float* __restrict__ src,
    float* __restrict__ xout) {
    __shared__ __align__(16) u16 As[64 * 392];
    int rb = blockIdx.x, t = threadIdx.x;
    size_t rb64 = (size_t)rb * 64;
    for (int i = t; i < 64 * 45; i += 256) {
        int row = i / 45, q = i % 45;
        size_t r180 = (rb64 + row) * (size_t)CD + q * 4;
        size_t r192 = (rb64 + row) * (size_t)CP + q * 4;
        ushort4 sg = *(const ushort4*)&sig[r192];
        ushort4 oe = *(const ushort4*)&oute[r180];
        ushort4 ob = *(const ushort4*)&outb[r180];
        ushort4 re, rbv;
        re.x = f2b(b2f(oe.x) * b2f(sg.x)); re.y = f2b(b2f(oe.y) * b2f(sg.y));
        re.z = f2b(b2f(oe.z) * b2f(sg.z)); re.w = f2b(b2f(oe.w) * b2f(sg.w));
        rbv.x = f2b(b2f(ob.x) * b2f(sg.x)); rbv.y = f2b(b2f(ob.y) * b2f(sg.y));
        rbv.z = f2b(b2f(ob.z) * b2f(sg.z)); rbv.w = f2b(b2f(ob.w) * b2f(sg.w));
        *(ushort4*)&As[row * 392 + q * 4] = re;
        *(ushort4*)&As[row * 392 + 180 + q * 4] = rbv;
    }
    for (int i = t; i < 64 * 6; i += 256) {
        int row = i / 6, q = i % 6;
        ushort4 z; z.x = 0; z.y = 0; z.z = 0; z.w = 0;
        *(ushort4*)&As[row * 392 + 360 + q * 4] = z;
    }
    __syncthreads();
    int wave = t >> 6, lane = t & 63, lr = lane & 15, lk = lane >> 4;
    s16x8 a[12];
    #pragma unroll
    for (int ks = 0; ks < 12; ++ks)
        a[ks] = *(const s16x8*)&As[(wave * 16 + lr) * 392 + ks * 32 + lk * 8];
    for (int ct = 0; ct < 12; ++ct) {
        f32x4 acc = {0.f, 0.f, 0.f, 0.f};
        #pragma unroll
        for (int ks = 0; ks < 12; ++ks) {
            s16x8 b = *(const s16x8*)&Wb[((size_t)(ct * 12 + ks) * 64 + lane) * 8];
            acc = __builtin_amdgcn_mfma_f32_16x16x32_bf16(a[ks], b, acc, 0, 0, 0);
        }
        int c = ct * 16 + lr;
        if (c < CD) {
            float bb = bias[c];
            #pragma unroll
            for (int j = 0; j < 4; ++j) {
                int rowm = (int)rb64 + wave * 16 + lk * 4 + j;
                int win = rowm >> 6, pos = rowm & 63;
                int b = win >> 8, whh = (win >> 4) & 15, www = win & 15;
                int hh = (((whh << 3) + (pos >> 3)) + 4) & 127;
                int w2 = (((www << 3) + (pos & 7)) + 4) & 127;
                size_t idx = (((size_t)(b * CD + c)) << 14) + (hh << 7) + w2;
                xout[idx] = src[idx] + acc[j] + bb;
            }
        }
    }
}

// ---------------- LN2 (x in NCHW) -> bf16 [row][CP]
__global__ __launch_bounds__(256) void ln2_kernel(
    const float* __restrict__ x, const float* __restrict__ gamma,
    const float* __restrict__ beta, u16* __restrict__ dst) {
    __shared__ float tile[NTOK][CD + 1];
    int blk = blockIdx.x;
    int b = blk >> 8;
    int l0 = (blk & 255) << 6;
    int t = threadIdx.x;
    for (int i = t; i < NTOK * CD; i += 256) {
        int c = i >> 6, pos = i & 63;
        tile[pos][c] = x[(((size_t)b * CD + c) << 14) + l0 + pos];
    }
    __syncthreads();
    int pos = t >> 2, sub = t & 3;
    float s = 0.f, ss = 0.f;
    for (int k = 0; k < 45; ++k) {
        float v = tile[pos][sub * 45 + k];
        s += v; ss += v * v;
    }
    s += __shfl_xor(s, 1); ss += __shfl_xor(ss, 1);
    s += __shfl_xor(s, 2); ss += __shfl_xor(ss, 2);
    float mean = s * (1.f / CD);
    float rstd = rsqrtf(ss * (1.f / CD) - mean * mean + 1e-5f);
    size_t obase = ((size_t)(b << 14) + l0 + pos) * CP;
    for (int k = 0; k < 45; ++k) {
        int c = sub * 45 + k;
        dst[obase + c] = f2b((tile[pos][c] - mean) * rstd * gamma[c] + beta[c]);
    }
    if (sub == 3) {
        for (int k = 0; k < 12; ++k) dst[obase + CD + k] = 0;
    }
}

// ---------------- MFMA fused MLP v3: 128-col Hid chunks (17.4 KB LDS), fast GELU
__global__ __launch_bounds__(256, 4) void mlp_kernel(
    const u16* __restrict__ xln, const u16* __restrict__ W1p,
    const float* __restrict__ b1, const u16* __restrict__ W2p,
    const float* __restrict__ b2v, float* __restrict__ xout) {
    __shared__ __align__(16) u16 Hid[64 * 136];   // 17408 B; wave-private 16-row slabs
    int rb = blockIdx.x, t = threadIdx.x;
    int wave = t >> 6, lane = t & 63, lr = lane & 15, lk = lane >> 4;

    const u16* arow = xln + ((size_t)rb * 64 + wave * 16 + lr) * CP;
    s16x8 a[6];
    #pragma unroll
    for (int ks = 0; ks < 6; ++ks)
        a[ks] = *(const s16x8*)&arow[ks * 32 + lk * 8];

    f32x4 acc2[12];
    #pragma unroll
    for (int c = 0; c < 12; ++c) acc2[c] = (f32x4){0.f, 0.f, 0.f, 0.f};

    for (int ch = 0; ch < 6; ++ch) {
        // ---- GEMM1 chunk: hid cols [ch*128, ch*128+128)
        #pragma unroll
        for (int ct = 0; ct < 8; ct += 2) {
            int ctg0 = ch * 8 + ct, ctg1 = ctg0 + 1;
            f32x4 h0 = {0.f, 0.f, 0.f, 0.f};
            f32x4 h1 = {0.f, 0.f, 0.f, 0.f};
            #pragma unroll
            for (int ks = 0; ks < 6; ++ks) {
                s16x8 b0 = *(const s16x8*)&W1p[((size_t)(ctg0 * 6 + ks) * 64 + lane) * 8];
                s16x8 b1f = *(const s16x8*)&W1p[((size_t)(ctg1 * 6 + ks) * 64 + lane) * 8];
                h0 = __builtin_amdgcn_mfma_f32_16x16x32_bf16(a[ks], b0, h0, 0, 0, 0);
                h1 = __builtin_amdgcn_mfma_f32_16x16x32_bf16(a[ks], b1f, h1, 0, 0, 0);
            }
            #pragma unroll 2
            for (int which = 0; which < 2; ++which) {
                int ctg = which ? ctg1 : ctg0;
                f32x4 hv = which ? h1 : h0;
                int hcol = ctg * 16 + lr;
                float bb = (hcol < 720) ? b1[hcol] : 0.f;
                int lcol = (ct + which) * 16 + lr;
                #pragma unroll
                for (int j = 0; j < 4; ++j) {
                    float v = gelu_f(hv[j] + bb);
                    Hid[(wave * 16 + lk * 4 + j) * 136 + lcol] = f2b(v);
                }
            }
        }
        // ---- GEMM2 partial over this chunk's 128 K (wave-private rows; no barrier)
        #pragma unroll
        for (int ks = 0; ks < 4; ++ks) {
            s16x8 av = *(const s16x8*)&Hid[(wave * 16 + lr) * 136 + ks * 32 + lk * 8];
            int gks = ch * 4 + ks;
            #pragma unroll
            for (int ct = 0; ct < 12; ++ct) {
                s16x8 b = *(const s16x8*)&W2p[((size_t)(ct * 24 + gks) * 64 + lane) * 8];
                acc2[ct] = __builtin_amdgcn_mfma_f32_16x16x32_bf16(av, b, acc2[ct], 0, 0, 0);
            }
        }
    }
    // ---- epilogue: bias + accumulate into xout (NCHW)
    #pragma unroll
    for (int ct = 0; ct < 12; ++ct) {
        int cc = ct * 16 + lr;
        if (cc < CD) {
            float bb = b2v[cc];
            #pragma unroll
            for (int j = 0; j < 4; ++j) {
                int m = rb * 64 + wave * 16 + lk * 4 + j;
                xout[(((size_t)(m >> 14) * CD + cc) << 14) + (m & 16383)] += acc2[ct][j] + bb;
            }
        }
    }
}

extern "C" void kernel_launch(void* const* d_in, const int* in_sizes, int n_in,
                              void* d_out, int out_size, void* d_ws, size_t ws_size,
                              hipStream_t stream) {
    const float* e_f = (const float*)d_in[0];
    const float* b_f = (const float*)d_in[1];

    const size_t S192 = (size_t)MROWS * CP;
    const size_t S180 = (size_t)MROWS * CD;
    u16* ew   = (u16*)d_ws;
    u16* bw   = ew + S192;
    u16* sige = bw + S192;
    u16* sigb = sige + S192;
    u16* oute = sigb + S192;
    u16* outb = oute + S180;
    u16* wg_e = outb + S180;                 // 192*192
    u16* wg_b = wg_e + 192 * 192;
    u16* wp_e = wg_b + 192 * 192;            // 192*384
    u16* wp_b = wp_e + 192 * 384;
    u16* w1_e = wp_b + 192 * 384;            // 768*192
    u16* w1_b = w1_e + 768 * 192;
    u16* w2_e = w1_b + 768 * 192;            // 192*768
    u16* w2_b = w2_e + 192 * 768;
    u16* wq_e = w2_b + 192 * 768;            // 576*192
    u16* wq_b = wq_e + 576 * 192;
    float* bq_e = (float*)(wq_b + 576 * 192);   // 576
    float* bq_b = bq_e + 576;
    u16* lne = sige;  u16* lnb = sigb;   // ln2 outputs overwrite sig after proj

    float* xe = (float*)d_out;
    float* xb = xe + (size_t)BATCH * CD * LSZ;

    auto prep = [&](const void* s, u16* d, int N, int K, int Npad, int Kpad) {
        int tot = Npad * Kpad;
        prep_wfrag<<<(tot + 255) / 256, 256, 0, stream>>>((const float*)s, d, N, K, Kpad / 32, tot);
    };
    prep(d_in[10], wg_e, 180, 180, 192, 192);
    prep(d_in[12], wg_b, 180, 180, 192, 192);
    prep(d_in[15], wp_e, 180, 360, 192, 384);
    prep(d_in[17], wp_b, 180, 360, 192, 384);
    prep(d_in[23], w1_e, 720, 180, 768, 192);
    prep(d_in[27], w1_b, 720, 180, 768, 192);
    prep(d_in[25], w2_e, 180, 720, 192, 768);
    prep(d_in[29], w2_b, 180, 720, 192, 768);
    prep_wqkv<<<(576 * 192 + 255) / 256, 256, 0, stream>>>(
        (const float*)d_in[6], (const float*)d_in[7], wq_e, bq_e);
    prep_wqkv<<<(576 * 192 + 255) / 256, 256, 0, stream>>>(
        (const float*)d_in[8], (const float*)d_in[9], wq_b, bq_b);

    ln_win_kernel<<<NWIN, 256, 0, stream>>>(e_f, (const float*)d_in[2], (const float*)d_in[3], ew);
    ln_win_kernel<<<NWIN, 256, 0, stream>>>(b_f, (const float*)d_in[4], (const float*)d_in[5], bw);

    gemm_gate<<<MROWS / 64, 256, 0, stream>>>(ew, wg_e, (const float*)d_in[11], sige);
    gemm_gate<<<MROWS / 64, 256, 0, stream>>>(bw, wg_b, (const float*)d_in[13], sigb);

    attn_mfma<<<NWIN, 256, 0, stream>>>(ew, wq_e, bq_e, (const float*)d_in[14], oute);
    attn_mfma<<<NWIN, 256, 0, stream>>>(bw, wq_b, bq_b, (const float*)d_in[14], outb);

    gemm_proj_add<<<MROWS / 64, 256, 0, stream>>>(oute, outb, sige, wp_e,
                                                  (const float*)d_in[16], e_f, xe);
    gemm_proj_add<<<MROWS / 64, 256, 0, stream>>>(oute, outb, sigb, wp_b,
                                                  (const float*)d_in[18], b_f, xb);

    ln2_kernel<<<NWIN, 256, 0, stream>>>(xe, (const float*)d_in[19], (const float*)d_in[20], lne);
    ln2_kernel<<<NWIN, 256, 0, stream>>>(xb, (const float*)d_in[21], (const float*)d_in[22], lnb);

    mlp_kernel<<<MROWS / 64, 256, 0, stream>>>(lne, w1_e, (const float*)d_in[24],
                                               w2_e, (const float*)d_in[26], xe);
    mlp_kernel<<<MROWS / 64, 256, 0, stream>>>(lnb, w1_b, (const float*)d_in[28],
                                               w2_b, (const float*)d_in[30], xb);
}

// Round 6
// 970.152 us; speedup vs baseline: 8.9479x; 1.0226x over previous
//
#include <hip/hip_runtime.h>
#include <hip/hip_bf16.h>

typedef unsigned short u16;
typedef unsigned int u32;
typedef __attribute__((ext_vector_type(8))) short s16x8;
typedef __attribute__((ext_vector_type(4))) float f32x4;

constexpr int CD    = 180;
constexpr int CP    = 192;              // K-padded channel count
constexpr int BATCH = 4;
constexpr int RES   = 128;
constexpr int LSZ   = RES * RES;        // 16384
constexpr int NHEAD = 6;
constexpr int DH    = 30;
constexpr int NTOK  = 64;
constexpr int NWIN  = 1024;
constexpr int MROWS = NWIN * NTOK;      // 65536
constexpr size_t S192 = (size_t)MROWS * CP;
constexpr size_t S180 = (size_t)MROWS * CD;
constexpr size_t XSZ  = (size_t)BATCH * CD * LSZ;

__device__ __forceinline__ float b2f(u16 u) { return __uint_as_float(((u32)u) << 16); }
__device__ __forceinline__ u16 f2b(float f) {
    __hip_bfloat16 h = __float2bfloat16(f);
    return *reinterpret_cast<u16*>(&h);
}
// fast GELU (tanh form); |err vs exact erf-GELU| <~1e-3
__device__ __forceinline__ float gelu_f(float x) {
    float y = 0.7978845608028654f * (x + 0.044715f * x * x * x);
    float t = __expf(-2.f * fabsf(y));
    float th = (1.f - t) / (1.f + t);
    th = copysignf(th, y);
    return 0.5f * x * (1.f + th);
}

// ---------------- merged weight prep: 8 fragment-major jobs in one launch
struct PrepArgs {
    const float *s0, *s1, *s2, *s3, *s4, *s5, *s6, *s7;
    u16* dst;   // base of contiguous dst region (wg_e)
};
__device__ __forceinline__ void do_frag(const float* __restrict__ src,
        u16* __restrict__ dst, int N, int K, int nks, int li) {
    int e = li & 7, lr = (li >> 3) & 15, lk = (li >> 7) & 3, rest = li >> 9;
    int ks = rest % nks, ct = rest / nks;
    int n = ct * 16 + lr, k = ks * 32 + lk * 8 + e;
    float v = (n < N && k < K) ? src[n * K + k] : 0.f;
    dst[li] = f2b(v);
}
__global__ __launch_bounds__(256) void prep_all(PrepArgs pa) {
    int bid = blockIdx.x, t = threadIdx.x;
    // blocks: wg_e 144 | wg_b 144 | wp_e 288 | wp_b 288 | w1_e 576 | w1_b 576 | w2_e 576 | w2_b 576
    if (bid < 144)       do_frag(pa.s0, pa.dst,                         180, 180,  6, (bid      ) * 256 + t);
    else if (bid < 288)  do_frag(pa.s1, pa.dst + 36864,                 180, 180,  6, (bid - 144) * 256 + t);
    else if (bid < 576)  do_frag(pa.s2, pa.dst + 73728,                 180, 360, 12, (bid - 288) * 256 + t);
    else if (bid < 864)  do_frag(pa.s3, pa.dst + 147456,                180, 360, 12, (bid - 576) * 256 + t);
    else if (bid < 1440) do_frag(pa.s4, pa.dst + 221184,                720, 180,  6, (bid - 864) * 256 + t);
    else if (bid < 2016) do_frag(pa.s5, pa.dst + 368640,                720, 180,  6, (bid - 1440) * 256 + t);
    else if (bid < 2592) do_frag(pa.s6, pa.dst + 516096,                180, 720, 24, (bid - 2016) * 256 + t);
    else                 do_frag(pa.s7, pa.dst + 663552,                180, 720, 24, (bid - 2592) * 256 + t);
}

// ---------------- merged qkv weight prep (e and b)
__global__ __launch_bounds__(256) void prep_wqkv2(
        const float* __restrict__ we, const float* __restrict__ be,
        const float* __restrict__ wb, const float* __restrict__ bb,
        u16* __restrict__ wp_base, float* __restrict__ bp_base) {
    int gi = blockIdx.x * 256 + threadIdx.x;
    int flag = gi >= 576 * 192;
    int i = flag ? gi - 576 * 192 : gi;
    if (i >= 576 * 192) return;
    const float* w = flag ? wb : we;
    const float* bsrc = flag ? bb : be;
    u16* wp = wp_base + (size_t)flag * (576 * 192);
    float* bp = bp_base + flag * 576;
    int e = i & 7, lr = (i >> 3) & 15, lk = (i >> 7) & 3, rest = i >> 9;
    int ks = rest % 6, rest2 = rest / 6;
    int ct = rest2 % 6, head = rest2 / 6;
    int rr = ct * 16 + lr;
    int sec = rr >> 5, dd = rr & 31;
    int srow = sec * 180 + head * 30 + dd;
    int k = ks * 32 + lk * 8 + e;
    float scale = (sec == 0) ? 0.18257418583505536f : 1.f;
    float v = (dd < 30 && k < 180) ? w[srow * 180 + k] * scale : 0.f;
    wp[i] = f2b(v);
    if (ks == 0 && lk == 0 && e == 0)
        bp[head * 96 + rr] = (dd < 30) ? bsrc[srow] * scale : 0.f;
}

// ---------------- merged LN1 + roll + window partition (e and b)
__global__ __launch_bounds__(256) void ln_win2(
    const float* __restrict__ e_f, const float* __restrict__ b_f,
    const float* __restrict__ g_e, const float* __restrict__ be_e,
    const float* __restrict__ g_b, const float* __restrict__ be_b,
    u16* __restrict__ dst_base) {
    __shared__ float tile[NTOK][CD + 1];
    int bid = blockIdx.x;
    int flag = bid >> 10;
    int widx = bid & 1023;
    const float* src = flag ? b_f : e_f;
    const float* gamma = flag ? g_b : g_e;
    const float* beta = flag ? be_b : be_e;
    u16* dst = dst_base + (size_t)flag * S192;
    int b = widx >> 8, wrem = widx & 255;
    int wh = wrem >> 4, ww = wrem & 15;
    int t = threadIdx.x;
    for (int i = t; i < NTOK * CD; i += 256) {
        int c = i >> 6, pos = i & 63;
        int sh = ((wh << 3) + (pos >> 3) + 4) & 127;
        int sw = ((ww << 3) + (pos & 7) + 4) & 127;
        tile[pos][c] = src[(((size_t)b * CD + c) << 14) + (sh << 7) + sw];
    }
    __syncthreads();
    int pos = t >> 2, sub = t & 3;
    float s = 0.f, ss = 0.f;
    for (int k = 0; k < 45; ++k) {
        float v = tile[pos][sub * 45 + k];
        s += v; ss += v * v;
    }
    s += __shfl_xor(s, 1); ss += __shfl_xor(ss, 1);
    s += __shfl_xor(s, 2); ss += __shfl_xor(ss, 2);
    float mean = s * (1.f / CD);
    float rstd = rsqrtf(ss * (1.f / CD) - mean * mean + 1e-5f);
    size_t obase = ((size_t)widx * NTOK + pos) * CP;
    for (int k = 0; k < 45; ++k) {
        int c = sub * 45 + k;
        dst[obase + c] = f2b((tile[pos][c] - mean) * rstd * gamma[c] + beta[c]);
    }
    if (sub == 3) {
        for (int k = 0; k < 12; ++k) dst[obase + CD + k] = 0;
    }
}

// ---------------- merged MFMA gate (e and b)
__global__ __launch_bounds__(256) void gate2(
    const u16* __restrict__ A_base, const u16* __restrict__ W_base,
    const float* __restrict__ bias_e, const float* __restrict__ bias_b,
    u16* __restrict__ sig_base) {
    __shared__ __align__(16) u16 As[64 * 200];
    int bid = blockIdx.x, t = threadIdx.x;
    int flag = bid >> 10;
    int rb = bid & 1023;
    const u16* A = A_base + (size_t)flag * S192;
    const u16* Wb = W_base + flag * 36864;
    const float* bias = flag ? bias_b : bias_e;
    u16* sig = sig_base + (size_t)flag * S192;
    size_t abase = (size_t)rb * 64 * CP;
    for (int i = t; i < 64 * 24; i += 256) {
        int row = i / 24, seg = i % 24;
        *(s16x8*)&As[row * 200 + seg * 8] = *(const s16x8*)&A[abase + (size_t)row * CP + seg * 8];
    }
    __syncthreads();
    int wave = t >> 6, lane = t & 63, lr = lane & 15, lk = lane >> 4;
    s16x8 a[6];
    #pragma unroll
    for (int ks = 0; ks < 6; ++ks)
        a[ks] = *(const s16x8*)&As[(wave * 16 + lr) * 200 + ks * 32 + lk * 8];
    for (int ct = 0; ct < 12; ++ct) {
        f32x4 acc = {0.f, 0.f, 0.f, 0.f};
        #pragma unroll
        for (int ks = 0; ks < 6; ++ks) {
            s16x8 b = *(const s16x8*)&Wb[((size_t)(ct * 6 + ks) * 64 + lane) * 8];
            acc = __builtin_amdgcn_mfma_f32_16x16x32_bf16(a[ks], b, acc, 0, 0, 0);
        }
        int c = ct * 16 + lr;
        if (c < CD) {
            float bb = bias[c];
            #pragma unroll
            for (int j = 0; j < 4; ++j) {
                int rowm = rb * 64 + wave * 16 + lk * 4 + j;
                float v = acc[j] + bb;
                v = 1.f / (1.f + __expf(-v));
                sig[(size_t)rowm * CP + c] = f2b(v);
            }
        }
    }
}

// ---------------- merged MFMA attention (e and b)
__global__ __launch_bounds__(256) void attn2(
    const u16* __restrict__ ew_base, const u16* __restrict__ wq_base,
    const float* __restrict__ bq_base, const float* __restrict__ rpb,
    u16* __restrict__ out_base) {
    __shared__ __align__(16) char smem[28448];
    u16*   ews  = (u16*)smem;                 // 64*200*2 = 25600 B (staging, dies)
    u16*   Qs   = (u16*)smem;                 // 64*36*2  =  4608
    u16*   Ks   = (u16*)(smem + 4608);
    u16*   Vt   = (u16*)(smem + 9216);        // 32*72*2  =  4608
    u16*   Pb   = (u16*)(smem + 13824);       // 64*72*2  =  9216
    float* rpbs = (float*)(smem + 23040);     // 1350*4   =  5400

    int bid = blockIdx.x;
    int flag = bid >> 10;
    int widx = bid & 1023;
    const u16* ew = ew_base + (size_t)flag * S192;
    const u16* Wq = wq_base + (size_t)flag * (576 * 192);
    const float* Bq = bq_base + flag * 576;
    u16* outp = out_base + (size_t)flag * S180;

    int wrem = widx & 255;
    int wh = wrem >> 4, ww = wrem & 15;
    bool edge = (wh == 15) || (ww == 15);
    int t = threadIdx.x;
    size_t wbase = (size_t)widx * NTOK * CD;
    size_t wb192 = (size_t)widx * NTOK * CP;

    for (int i = t; i < 64 * 24; i += 256) {
        int row = i / 24, seg = i % 24;
        *(s16x8*)&ews[row * 200 + seg * 8] = *(const s16x8*)&ew[wb192 + (size_t)row * CP + seg * 8];
    }
    __syncthreads();

    int wave = t >> 6, lane = t & 63, lr = lane & 15, lk = lane >> 4;
    s16x8 a[6];
    #pragma unroll
    for (int ks = 0; ks < 6; ++ks)
        a[ks] = *(const s16x8*)&ews[(wave * 16 + lr) * 200 + ks * 32 + lk * 8];
    __syncthreads();   // all waves done reading ews; region reusable

    for (int i = t; i < 1350; i += 256) rpbs[i] = rpb[i];  // visible after next barrier

    for (int h = 0; h < NHEAD; ++h) {
        // ---- QKV for head h
        #pragma unroll
        for (int ct = 0; ct < 6; ++ct) {
            f32x4 acc = {0.f, 0.f, 0.f, 0.f};
            #pragma unroll
            for (int ks = 0; ks < 6; ++ks) {
                s16x8 b = *(const s16x8*)&Wq[(((size_t)(h * 6 + ct) * 6 + ks) * 64 + lane) * 8];
                acc = __builtin_amdgcn_mfma_f32_16x16x32_bf16(a[ks], b, acc, 0, 0, 0);
            }
            int sec = ct >> 1;
            int dd = ((ct & 1) << 4) + lr;
            float bb = Bq[h * 96 + ct * 16 + lr];
            #pragma unroll
            for (int j = 0; j < 4; ++j) {
                int tok = wave * 16 + lk * 4 + j;
                float v = acc[j] + bb;
                if (sec == 0)      Qs[tok * 36 + dd] = f2b(v);
                else if (sec == 1) Ks[tok * 36 + dd] = f2b(v);
                else               Vt[dd * 72 + tok] = f2b(v);
            }
        }
        __syncthreads();
        // ---- S = Q K^T (+rpb, +mask) in registers
        f32x4 sv[4];
        {
            s16x8 qa = *(const s16x8*)&Qs[(wave * 16 + lr) * 36 + lk * 8];
            #pragma unroll
            for (int ct = 0; ct < 4; ++ct) {
                s16x8 kb = *(const s16x8*)&Ks[(ct * 16 + lr) * 36 + lk * 8];
                f32x4 z = {0.f, 0.f, 0.f, 0.f};
                sv[ct] = __builtin_amdgcn_mfma_f32_16x16x32_bf16(qa, kb, z, 0, 0, 0);
            }
            #pragma unroll
            for (int ct = 0; ct < 4; ++ct) {
                int sj = ct * 16 + lr;
                int jh = sj >> 3, jw = sj & 7;
                #pragma unroll
                for (int j = 0; j < 4; ++j) {
                    int si = wave * 16 + lk * 4 + j;
                    int ih = si >> 3, iw = si & 7;
                    float v = sv[ct][j] + rpbs[((ih - jh + 7) * 15 + (iw - jw + 7)) * 6 + h];
                    if (edge) {
                        int hri = (wh << 3) + ih, wri = (ww << 3) + iw;
                        int hrj = (wh << 3) + jh, wrj = (ww << 3) + jw;
                        int ri = (hri < 120 ? 0 : (hri < 124 ? 1 : 2)) * 3 + (wri < 120 ? 0 : (wri < 124 ? 1 : 2));
                        int rj = (hrj < 120 ? 0 : (hrj < 124 ? 1 : 2)) * 3 + (wrj < 120 ? 0 : (wrj < 124 ? 1 : 2));
                        if (ri != rj) v -= 100.f;
                    }
                    sv[ct][j] = v;
                }
            }
        }
        __syncthreads();
        // ---- in-register softmax per row (16-lane lr group holds one row)
        #pragma unroll
        for (int j = 0; j < 4; ++j) {
            float mx = fmaxf(fmaxf(sv[0][j], sv[1][j]), fmaxf(sv[2][j], sv[3][j]));
            mx = fmaxf(mx, __shfl_xor(mx, 1));
            mx = fmaxf(mx, __shfl_xor(mx, 2));
            mx = fmaxf(mx, __shfl_xor(mx, 4));
            mx = fmaxf(mx, __shfl_xor(mx, 8));
            float e0 = __expf(sv[0][j] - mx);
            float e1 = __expf(sv[1][j] - mx);
            float e2 = __expf(sv[2][j] - mx);
            float e3 = __expf(sv[3][j] - mx);
            float sm = e0 + e1 + e2 + e3;
            sm += __shfl_xor(sm, 1);
            sm += __shfl_xor(sm, 2);
            sm += __shfl_xor(sm, 4);
            sm += __shfl_xor(sm, 8);
            float inv = 1.f / sm;
            int row = wave * 16 + lk * 4 + j;
            Pb[row * 72 +      lr] = f2b(e0 * inv);
            Pb[row * 72 + 16 + lr] = f2b(e1 * inv);
            Pb[row * 72 + 32 + lr] = f2b(e2 * inv);
            Pb[row * 72 + 48 + lr] = f2b(e3 * inv);
        }
        __syncthreads();
        // ---- O = P V
        {
            s16x8 pa0 = *(const s16x8*)&Pb[(wave * 16 + lr) * 72 + lk * 8];
            s16x8 pa1 = *(const s16x8*)&Pb[(wave * 16 + lr) * 72 + 32 + lk * 8];
            #pragma unroll
            for (int ct = 0; ct < 2; ++ct) {
                f32x4 acc = {0.f, 0.f, 0.f, 0.f};
                s16x8 vb0 = *(const s16x8*)&Vt[(ct * 16 + lr) * 72 + lk * 8];
                s16x8 vb1 = *(const s16x8*)&Vt[(ct * 16 + lr) * 72 + 32 + lk * 8];
                acc = __builtin_amdgcn_mfma_f32_16x16x32_bf16(pa0, vb0, acc, 0, 0, 0);
                acc = __builtin_amdgcn_mfma_f32_16x16x32_bf16(pa1, vb1, acc, 0, 0, 0);
                int dd = ct * 16 + lr;
                if (dd < DH) {
                    #pragma unroll
                    for (int j = 0; j < 4; ++j) {
                        int tok = wave * 16 + lk * 4 + j;
                        outp[wbase + (size_t)tok * CD + h * DH + dd] = f2b(acc[j]);
                    }
                }
            }
        }
        __syncthreads();
    }
}

// ---------------- merged MFMA proj + addback (e and b)
__global__ __launch_bounds__(256) void proj_add2(
    const u16* __restrict__ oute, const u16* __restrict__ outb,
    const u16* __restrict__ sig_base, const u16* __restrict__ wp_base,
    const float* __restrict__ bias_e, const float* __restrict__ bias_b,
    const float* __restrict__ e_f, const float* __restrict__ b_f,
    float* __restrict__ xout_base) {
    __shared__ __align__(16) u16 As[64 * 392];
    int bid = blockIdx.x, t = threadIdx.x;
    int flag = bid >> 10;
    int rb = bid & 1023;
    const u16* sig = sig_base + (size_t)flag * S192;
    const u16* Wb = wp_base + flag * (192 * 384);
    const float* bias = flag ? bias_b : bias_e;
    const float* src = flag ? b_f : e_f;
    float* xout = xout_base + (size_t)flag * XSZ;
    size_t rb64 = (size_t)rb * 64;
    for (int i = t; i < 64 * 45; i += 256) {
        int row = i / 45, q = i % 45;
        size_t r180 = (rb64 + row) * (size_t)CD + q * 4;
        size_t r192 = (rb64 + row) * (size_t)CP + q * 4;
        ushort4 sg = *(const ushort4*)&sig[r192];
        ushort4 oe = *(const ushort4*)&oute[r180];
        ushort4 ob = *(const ushort4*)&outb[r180];
        ushort4 re, rbv;
        re.x = f2b(b2f(oe.x) * b2f(sg.x)); re.y = f2b(b2f(oe.y) * b2f(sg.y));
        re.z = f2b(b2f(oe.z) * b2f(sg.z)); re.w = f2b(b2f(oe.w) * b2f(sg.w));
        rbv.x = f2b(b2f(ob.x) * b2f(sg.x)); rbv.y = f2b(b2f(ob.y) * b2f(sg.y));
        rbv.z = f2b(b2f(ob.z) * b2f(sg.z)); rbv.w = f2b(b2f(ob.w) * b2f(sg.w));
        *(ushort4*)&As[row * 392 + q * 4] = re;
        *(ushort4*)&As[row * 392 + 180 + q * 4] = rbv;
    }
    for (int i = t; i < 64 * 6; i += 256) {
        int row = i / 6, q = i % 6;
        ushort4 z; z.x = 0; z.y = 0; z.z = 0; z.w = 0;
        *(ushort4*)&As[row * 392 + 360 + q * 4] = z;
    }
    __syncthreads();
    int wave = t >> 6, lane = t & 63, lr = lane & 15, lk = lane >> 4;
    s16x8 a[12];
    #pragma unroll
    for (int ks = 0; ks < 12; ++ks)
        a[ks] = *(const s16x8*)&As[(wave * 16 + lr) * 392 + ks * 32 + lk * 8];
    for (int ct = 0; ct < 12; ++ct) {
        f32x4 acc = {0.f, 0.f, 0.f, 0.f};
        #pragma unroll
        for (int ks = 0; ks < 12; ++ks) {
            s16x8 b = *(const s16x8*)&Wb[((size_t)(ct * 12 + ks) * 64 + lane) * 8];
            acc = __builtin_amdgcn_mfma_f32_16x16x32_bf16(a[ks], b, acc, 0, 0, 0);
        }
        int c = ct * 16 + lr;
        if (c < CD) {
            float bb = bias[c];
            #pragma unroll
            for (int j = 0; j < 4; ++j) {
                int rowm = (int)rb64 + wave * 16 + lk * 4 + j;
                int win = rowm >> 6, pos = rowm & 63;
                int b = win >> 8, whh = (win >> 4) & 15, www = win & 15;
                int hh = (((whh << 3) + (pos >> 3)) + 4) & 127;
                int w2 = (((www << 3) + (pos & 7)) + 4) & 127;
                size_t idx = (((size_t)(b * CD + c)) << 14) + (hh << 7) + w2;
                xout[idx] = src[idx] + acc[j] + bb;
            }
        }
    }
}

// ---------------- merged LN2 (e and b)
__global__ __launch_bounds__(256) void ln2_2(
    const float* __restrict__ x_base, const float* __restrict__ g_e,
    const float* __restrict__ be_e, const float* __restrict__ g_b,
    const float* __restrict__ be_b, u16* __restrict__ dst_base) {
    __shared__ float tile[NTOK][CD + 1];
    int bid = blockIdx.x;
    int flag = bid >> 10;
    int blk = bid & 1023;
    const float* x = x_base + (size_t)flag * XSZ;
    const float* gamma = flag ? g_b : g_e;
    const float* beta = flag ? be_b : be_e;
    u16* dst = dst_base + (size_t)flag * S192;
    int b = blk >> 8;
    int l0 = (blk & 255) << 6;
    int t = threadIdx.x;
    for (int i = t; i < NTOK * CD; i += 256) {
        int c = i >> 6, pos = i & 63;
        tile[pos][c] = x[(((size_t)b * CD + c) << 14) + l0 + pos];
    }
    __syncthreads();
    int pos = t >> 2, sub = t & 3;
    float s = 0.f, ss = 0.f;
    for (int k = 0; k < 45; ++k) {
        float v = tile[pos][sub * 45 + k];
        s += v; ss += v * v;
    }
    s += __shfl_xor(s, 1); ss += __shfl_xor(ss, 1);
    s += __shfl_xor(s, 2); ss += __shfl_xor(ss, 2);
    float mean = s * (1.f / CD);
    float rstd = rsqrtf(ss * (1.f / CD) - mean * mean + 1e-5f);
    size_t obase = ((size_t)(b << 14) + l0 + pos) * CP;
    for (int k = 0; k < 45; ++k) {
        int c = sub * 45 + k;
        dst[obase + c] = f2b((tile[pos][c] - mean) * rstd * gamma[c] + beta[c]);
    }
    if (sub == 3) {
        for (int k = 0; k < 12; ++k) dst[obase + CD + k] = 0;
    }
}

// ---------------- merged MFMA fused MLP (e and b)
__global__ __launch_bounds__(256, 4) void mlp2(
    const u16* __restrict__ xln_base, const u16* __restrict__ w1_base,
    const float* __restrict__ b1_e, const float* __restrict__ b1_b,
    const u16* __restrict__ w2_base, const float* __restrict__ b2_e,
    const float* __restrict__ b2_b, float* __restrict__ xout_base) {
    __shared__ __align__(16) u16 Hid[64 * 136];   // 17408 B; wave-private 16-row slabs
    int bid = blockIdx.x, t = threadIdx.x;
    int flag = bid >> 10;
    int rb = bid & 1023;
    const u16* xln = xln_base + (size_t)flag * S192;
    const u16* W1p = w1_base + (size_t)flag * (768 * 192);
    const u16* W2p = w2_base + (size_t)flag * (192 * 768);
    const float* b1 = flag ? b1_b : b1_e;
    const float* b2v = flag ? b2_b : b2_e;
    float* xout = xout_base + (size_t)flag * XSZ;
    int wave = t >> 6, lane = t & 63, lr = lane & 15, lk = lane >> 4;

    const u16* arow = xln + ((size_t)rb * 64 + wave * 16 + lr) * CP;
    s16x8 a[6];
    #pragma unroll
    for (int ks = 0; ks < 6; ++ks)
        a[ks] = *(const s16x8*)&arow[ks * 32 + lk * 8];

    f32x4 acc2[12];
    #pragma unroll
    for (int c = 0; c < 12; ++c) acc2[c] = (f32x4){0.f, 0.f, 0.f, 0.f};

    for (int ch = 0; ch < 6; ++ch) {
        // ---- GEMM1 chunk: hid cols [ch*128, ch*128+128)
        #pragma unroll
        for (int ct = 0; ct < 8; ct += 2) {
            int ctg0 = ch * 8 + ct, ctg1 = ctg0 + 1;
            f32x4 h0 = {0.f, 0.f, 0.f, 0.f};
            f32x4 h1 = {0.f, 0.f, 0.f, 0.f};
            #pragma unroll
            for (int ks = 0; ks < 6; ++ks) {
                s16x8 b0 = *(const s16x8*)&W1p[((size_t)(ctg0 * 6 + ks) * 64 + lane) * 8];
                s16x8 b1f = *(const s16x8*)&W1p[((size_t)(ctg1 * 6 + ks) * 64 + lane) * 8];
                h0 = __builtin_amdgcn_mfma_f32_16x16x32_bf16(a[ks], b0, h0, 0, 0, 0);
                h1 = __builtin_amdgcn_mfma_f32_16x16x32_bf16(a[ks], b1f, h1, 0, 0, 0);
            }
            #pragma unroll 2
            for (int which = 0; which < 2; ++which) {
                int ctg = which ? ctg1 : ctg0;
                f32x4 hv = which ? h1 : h0;
                int hcol = ctg * 16 + lr;
                float bb = (hcol < 720) ? b1[hcol] : 0.f;
                int lcol = (ct + which) * 16 + lr;
                #pragma unroll
                for (int j = 0; j < 4; ++j) {
                    float v = gelu_f(hv[j] + bb);
                    Hid[(wave * 16 + lk * 4 + j) * 136 + lcol] = f2b(v);
                }
            }
        }
        // ---- GEMM2 partial over this chunk's 128 K (wave-private rows; no barrier)
        #pragma unroll
        for (int ks = 0; ks < 4; ++ks) {
            s16x8 av = *(const s16x8*)&Hid[(wave * 16 + lr) * 136 + ks * 32 + lk * 8];
            int gks = ch * 4 + ks;
            #pragma unroll
            for (int ct = 0; ct < 12; ++ct) {
                s16x8 b = *(const s16x8*)&W2p[((size_t)(ct * 24 + gks) * 64 + lane) * 8];
                acc2[ct] = __builtin_amdgcn_mfma_f32_16x16x32_bf16(av, b, acc2[ct], 0, 0, 0);
            }
        }
    }
    // ---- epilogue: bias + accumulate into xout (NCHW)
    #pragma unroll
    for (int ct = 0; ct < 12; ++ct) {
        int cc = ct * 16 + lr;
        if (cc < CD) {
            float bb = b2v[cc];
            #pragma unroll
            for (int j = 0; j < 4; ++j) {
                int m = rb * 64 + wave * 16 + lk * 4 + j;
                xout[(((size_t)(m >> 14) * CD + cc) << 14) + (m & 16383)] += acc2[ct][j] + bb;
            }
        }
    }
}

extern "C" void kernel_launch(void* const* d_in, const int* in_sizes, int n_in,
                              void* d_out, int out_size, void* d_ws, size_t ws_size,
                              hipStream_t stream) {
    const float* e_f = (const float*)d_in[0];
    const float* b_f = (const float*)d_in[1];

    u16* ew   = (u16*)d_ws;
    u16* bw   = ew + S192;
    u16* sige = bw + S192;
    u16* sigb = sige + S192;
    u16* oute = sigb + S192;
    u16* outb = oute + S180;
    u16* wg_e = outb + S180;                 // contiguous prep region:
    // wg_e(36864) wg_b(36864) wp_e(73728) wp_b(73728) w1_e(147456) w1_b(147456) w2_e(147456) w2_b(147456)
    u16* wp_e = wg_e + 2 * 36864;
    u16* w1_e = wp_e + 2 * 73728;
    u16* w2_e = w1_e + 2 * 147456;
    u16* wq_e = w2_e + 2 * 147456;           // 2 * 576*192
    float* bq_e = (float*)(wq_e + 2 * 576 * 192);   // 2 * 576
    u16* lne = sige;   // ln2 outputs overwrite sig after proj

    float* xe = (float*)d_out;

    PrepArgs pa;
    pa.s0 = (const float*)d_in[10];  // pse_w   -> wg_e
    pa.s1 = (const float*)d_in[12];  // psb_w   -> wg_b
    pa.s2 = (const float*)d_in[15];  // proj_e  -> wp_e
    pa.s3 = (const float*)d_in[17];  // proj_b  -> wp_b
    pa.s4 = (const float*)d_in[23];  // mlp_e_w1-> w1_e
    pa.s5 = (const float*)d_in[27];  // mlp_b_w1-> w1_b
    pa.s6 = (const float*)d_in[25];  // mlp_e_w2-> w2_e
    pa.s7 = (const float*)d_in[29];  // mlp_b_w2-> w2_b
    pa.dst = wg_e;
    prep_all<<<3168, 256, 0, stream>>>(pa);
    prep_wqkv2<<<(2 * 576 * 192 + 255) / 256, 256, 0, stream>>>(
        (const float*)d_in[6], (const float*)d_in[7],
        (const float*)d_in[8], (const float*)d_in[9], wq_e, bq_e);

    ln_win2<<<2 * NWIN, 256, 0, stream>>>(e_f, b_f,
        (const float*)d_in[2], (const float*)d_in[3],
        (const float*)d_in[4], (const float*)d_in[5], ew);

    gate2<<<2 * MROWS / 64, 256, 0, stream>>>(ew, wg_e,
        (const float*)d_in[11], (const float*)d_in[13], sige);

    attn2<<<2 * NWIN, 256, 0, stream>>>(ew, wq_e, bq_e,
        (const float*)d_in[14], oute);

    proj_add2<<<2 * MROWS / 64, 256, 0, stream>>>(oute, outb, sige, wp_e,
        (const float*)d_in[16], (const float*)d_in[18], e_f, b_f, xe);

    ln2_2<<<2 * NWIN, 256, 0, stream>>>(xe,
        (const float*)d_in[19], (const float*)d_in[20],
        (const float*)d_in[21], (const float*)d_in[22], lne);

    mlp2<<<2 * MROWS / 64, 256, 0, stream>>>(lne, w1_e,
        (const float*)d_in[24], (const float*)d_in[28], w2_e,
        (const float*)d_in[26], (const float*)d_in[30], xe);
}

// Round 8
// 831.904 us; speedup vs baseline: 10.4348x; 1.1662x over previous
//
#include <hip/hip_runtime.h>
#include <hip/hip_bf16.h>

typedef unsigned short u16;
typedef unsigned int u32;
typedef __attribute__((ext_vector_type(8))) short s16x8;
typedef __attribute__((ext_vector_type(4))) float f32x4;

constexpr int CD    = 180;
constexpr int CP    = 192;              // K-padded channel count
constexpr int BATCH = 4;
constexpr int RES   = 128;
constexpr int LSZ   = RES * RES;        // 16384
constexpr int NHEAD = 6;
constexpr int DH    = 30;
constexpr int NTOK  = 64;
constexpr int NWIN  = 1024;
constexpr int MROWS = NWIN * NTOK;      // 65536
constexpr size_t S192 = (size_t)MROWS * CP;
constexpr size_t S180 = (size_t)MROWS * CD;
constexpr size_t XSZ  = (size_t)BATCH * CD * LSZ;

__device__ __forceinline__ float b2f(u16 u) { return __uint_as_float(((u32)u) << 16); }
__device__ __forceinline__ u16 f2b(float f) {
    __hip_bfloat16 h = __float2bfloat16(f);
    return *reinterpret_cast<u16*>(&h);
}
// fast GELU (tanh form); |err vs exact erf-GELU| <~1e-3
__device__ __forceinline__ float gelu_f(float x) {
    float y = 0.7978845608028654f * (x + 0.044715f * x * x * x);
    float t = __expf(-2.f * fabsf(y));
    float th = (1.f - t) / (1.f + t);
    th = copysignf(th, y);
    return 0.5f * x * (1.f + th);
}

// ---------------- merged weight prep: 8 fragment-major jobs in one launch
struct PrepArgs {
    const float *s0, *s1, *s2, *s3, *s4, *s5, *s6, *s7;
    u16* dst;   // base of contiguous dst region (wg_e)
};
__device__ __forceinline__ void do_frag(const float* __restrict__ src,
        u16* __restrict__ dst, int N, int K, int nks, int li) {
    int e = li & 7, lr = (li >> 3) & 15, lk = (li >> 7) & 3, rest = li >> 9;
    int ks = rest % nks, ct = rest / nks;
    int n = ct * 16 + lr, k = ks * 32 + lk * 8 + e;
    float v = (n < N && k < K) ? src[n * K + k] : 0.f;
    dst[li] = f2b(v);
}
__global__ __launch_bounds__(256) void prep_all(PrepArgs pa) {
    int bid = blockIdx.x, t = threadIdx.x;
    if (bid < 144)       do_frag(pa.s0, pa.dst,          180, 180,  6, (bid       ) * 256 + t);
    else if (bid < 288)  do_frag(pa.s1, pa.dst + 36864,  180, 180,  6, (bid - 144 ) * 256 + t);
    else if (bid < 576)  do_frag(pa.s2, pa.dst + 73728,  180, 360, 12, (bid - 288 ) * 256 + t);
    else if (bid < 864)  do_frag(pa.s3, pa.dst + 147456, 180, 360, 12, (bid - 576 ) * 256 + t);
    else if (bid < 1440) do_frag(pa.s4, pa.dst + 221184, 720, 180,  6, (bid - 864 ) * 256 + t);
    else if (bid < 2016) do_frag(pa.s5, pa.dst + 368640, 720, 180,  6, (bid - 1440) * 256 + t);
    else if (bid < 2592) do_frag(pa.s6, pa.dst + 516096, 180, 720, 24, (bid - 2016) * 256 + t);
    else                 do_frag(pa.s7, pa.dst + 663552, 180, 720, 24, (bid - 2592) * 256 + t);
}

// ---------------- merged qkv weight prep (e and b)
__global__ __launch_bounds__(256) void prep_wqkv2(
        const float* __restrict__ we, const float* __restrict__ be,
        const float* __restrict__ wb, const float* __restrict__ bb,
        u16* __restrict__ wp_base, float* __restrict__ bp_base) {
    int gi = blockIdx.x * 256 + threadIdx.x;
    int flag = gi >= 576 * 192;
    int i = flag ? gi - 576 * 192 : gi;
    if (i >= 576 * 192) return;
    const float* w = flag ? wb : we;
    const float* bsrc = flag ? bb : be;
    u16* wp = wp_base + (size_t)flag * (576 * 192);
    float* bp = bp_base + flag * 576;
    int e = i & 7, lr = (i >> 3) & 15, lk = (i >> 7) & 3, rest = i >> 9;
    int ks = rest % 6, rest2 = rest / 6;
    int ct = rest2 % 6, head = rest2 / 6;
    int rr = ct * 16 + lr;
    int sec = rr >> 5, dd = rr & 31;
    int srow = sec * 180 + head * 30 + dd;
    int k = ks * 32 + lk * 8 + e;
    float scale = (sec == 0) ? 0.18257418583505536f : 1.f;
    float v = (dd < 30 && k < 180) ? w[srow * 180 + k] * scale : 0.f;
    wp[i] = f2b(v);
    if (ks == 0 && lk == 0 && e == 0)
        bp[head * 96 + rr] = (dd < 30) ? bsrc[srow] * scale : 0.f;
}

// ---------------- merged LN1 + roll + window partition (e and b)
__global__ __launch_bounds__(256) void ln_win2(
    const float* __restrict__ e_f, const float* __restrict__ b_f,
    const float* __restrict__ g_e, const float* __restrict__ be_e,
    const float* __restrict__ g_b, const float* __restrict__ be_b,
    u16* __restrict__ dst_base) {
    __shared__ float tile[NTOK][CD + 1];
    int bid = blockIdx.x;
    int flag = bid >> 10;
    int widx = bid & 1023;
    const float* src = flag ? b_f : e_f;
    const float* gamma = flag ? g_b : g_e;
    const float* beta = flag ? be_b : be_e;
    u16* dst = dst_base + (size_t)flag * S192;
    int b = widx >> 8, wrem = widx & 255;
    int wh = wrem >> 4, ww = wrem & 15;
    int t = threadIdx.x;
    for (int i = t; i < NTOK * CD; i += 256) {
        int c = i >> 6, pos = i & 63;
        int sh = ((wh << 3) + (pos >> 3) + 4) & 127;
        int sw = ((ww << 3) + (pos & 7) + 4) & 127;
        tile[pos][c] = src[(((size_t)b * CD + c) << 14) + (sh << 7) + sw];
    }
    __syncthreads();
    int pos = t >> 2, sub = t & 3;
    float s = 0.f, ss = 0.f;
    for (int k = 0; k < 45; ++k) {
        float v = tile[pos][sub * 45 + k];
        s += v; ss += v * v;
    }
    s += __shfl_xor(s, 1); ss += __shfl_xor(ss, 1);
    s += __shfl_xor(s, 2); ss += __shfl_xor(ss, 2);
    float mean = s * (1.f / CD);
    float rstd = rsqrtf(ss * (1.f / CD) - mean * mean + 1e-5f);
    size_t obase = ((size_t)widx * NTOK + pos) * CP;
    for (int k = 0; k < 45; ++k) {
        int c = sub * 45 + k;
        dst[obase + c] = f2b((tile[pos][c] - mean) * rstd * gamma[c] + beta[c]);
    }
    if (sub == 3) {
        for (int k = 0; k < 12; ++k) dst[obase + CD + k] = 0;
    }
}

// ---------------- merged MFMA gate (e and b)
__global__ __launch_bounds__(256) void gate2(
    const u16* __restrict__ A_base, const u16* __restrict__ W_base,
    const float* __restrict__ bias_e, const float* __restrict__ bias_b,
    u16* __restrict__ sig_base) {
    __shared__ __align__(16) u16 As[64 * 200];
    int bid = blockIdx.x, t = threadIdx.x;
    int flag = bid >> 10;
    int rb = bid & 1023;
    const u16* A = A_base + (size_t)flag * S192;
    const u16* Wb = W_base + flag * 36864;
    const float* bias = flag ? bias_b : bias_e;
    u16* sig = sig_base + (size_t)flag * S192;
    size_t abase = (size_t)rb * 64 * CP;
    for (int i = t; i < 64 * 24; i += 256) {
        int row = i / 24, seg = i % 24;
        *(s16x8*)&As[row * 200 + seg * 8] = *(const s16x8*)&A[abase + (size_t)row * CP + seg * 8];
    }
    __syncthreads();
    int wave = t >> 6, lane = t & 63, lr = lane & 15, lk = lane >> 4;
    s16x8 a[6];
    #pragma unroll
    for (int ks = 0; ks < 6; ++ks)
        a[ks] = *(const s16x8*)&As[(wave * 16 + lr) * 200 + ks * 32 + lk * 8];
    for (int ct = 0; ct < 12; ++ct) {
        f32x4 acc = {0.f, 0.f, 0.f, 0.f};
        #pragma unroll
        for (int ks = 0; ks < 6; ++ks) {
            s16x8 b = *(const s16x8*)&Wb[((size_t)(ct * 6 + ks) * 64 + lane) * 8];
            acc = __builtin_amdgcn_mfma_f32_16x16x32_bf16(a[ks], b, acc, 0, 0, 0);
        }
        int c = ct * 16 + lr;
        if (c < CD) {
            float bb = bias[c];
            #pragma unroll
            for (int j = 0; j < 4; ++j) {
                int rowm = rb * 64 + wave * 16 + lk * 4 + j;
                float v = acc[j] + bb;
                v = 1.f / (1.f + __expf(-v));
                sig[(size_t)rowm * CP + c] = f2b(v);
            }
        }
    }
}

// ---------------- merged MFMA attention (e and b)
__global__ __launch_bounds__(256) void attn2(
    const u16* __restrict__ ew_base, const u16* __restrict__ wq_base,
    const float* __restrict__ bq_base, const float* __restrict__ rpb,
    u16* __restrict__ out_base) {
    __shared__ __align__(16) char smem[28448];
    u16*   ews  = (u16*)smem;                 // 64*200*2 = 25600 B (staging, dies)
    u16*   Qs   = (u16*)smem;                 // 64*36*2  =  4608
    u16*   Ks   = (u16*)(smem + 4608);
    u16*   Vt   = (u16*)(smem + 9216);        // 32*72*2  =  4608
    u16*   Pb   = (u16*)(smem + 13824);       // 64*72*2  =  9216
    float* rpbs = (float*)(smem + 23040);     // 1350*4   =  5400

    int bid = blockIdx.x;
    int flag = bid >> 10;
    int widx = bid & 1023;
    const u16* ew = ew_base + (size_t)flag * S192;
    const u16* Wq = wq_base + (size_t)flag * (576 * 192);
    const float* Bq = bq_base + flag * 576;
    u16* outp = out_base + (size_t)flag * S180;

    int wrem = widx & 255;
    int wh = wrem >> 4, ww = wrem & 15;
    bool edge = (wh == 15) || (ww == 15);
    int t = threadIdx.x;
    size_t wbase = (size_t)widx * NTOK * CD;
    size_t wb192 = (size_t)widx * NTOK * CP;

    for (int i = t; i < 64 * 24; i += 256) {
        int row = i / 24, seg = i % 24;
        *(s16x8*)&ews[row * 200 + seg * 8] = *(const s16x8*)&ew[wb192 + (size_t)row * CP + seg * 8];
    }
    __syncthreads();

    int wave = t >> 6, lane = t & 63, lr = lane & 15, lk = lane >> 4;
    s16x8 a[6];
    #pragma unroll
    for (int ks = 0; ks < 6; ++ks)
        a[ks] = *(const s16x8*)&ews[(wave * 16 + lr) * 200 + ks * 32 + lk * 8];
    __syncthreads();   // all waves done reading ews; region reusable

    for (int i = t; i < 1350; i += 256) rpbs[i] = rpb[i];  // visible after next barrier

    for (int h = 0; h < NHEAD; ++h) {
        #pragma unroll
        for (int ct = 0; ct < 6; ++ct) {
            f32x4 acc = {0.f, 0.f, 0.f, 0.f};
            #pragma unroll
            for (int ks = 0; ks < 6; ++ks) {
                s16x8 b = *(const s16x8*)&Wq[(((size_t)(h * 6 + ct) * 6 + ks) * 64 + lane) * 8];
                acc = __builtin_amdgcn_mfma_f32_16x16x32_bf16(a[ks], b, acc, 0, 0, 0);
            }
            int sec = ct >> 1;
            int dd = ((ct & 1) << 4) + lr;
            float bb = Bq[h * 96 + ct * 16 + lr];
            #pragma unroll
            for (int j = 0; j < 4; ++j) {
                int tok = wave * 16 + lk * 4 + j;
                float v = acc[j] + bb;
                if (sec == 0)      Qs[tok * 36 + dd] = f2b(v);
                else if (sec == 1) Ks[tok * 36 + dd] = f2b(v);
                else               Vt[dd * 72 + tok] = f2b(v);
            }
        }
        __syncthreads();
        f32x4 sv[4];
        {
            s16x8 qa = *(const s16x8*)&Qs[(wave * 16 + lr) * 36 + lk * 8];
            #pragma unroll
            for (int ct = 0; ct < 4; ++ct) {
                s16x8 kb = *(const s16x8*)&Ks[(ct * 16 + lr) * 36 + lk * 8];
                f32x4 z = {0.f, 0.f, 0.f, 0.f};
                sv[ct] = __builtin_amdgcn_mfma_f32_16x16x32_bf16(qa, kb, z, 0, 0, 0);
            }
            #pragma unroll
            for (int ct = 0; ct < 4; ++ct) {
                int sj = ct * 16 + lr;
                int jh = sj >> 3, jw = sj & 7;
                #pragma unroll
                for (int j = 0; j < 4; ++j) {
                    int si = wave * 16 + lk * 4 + j;
                    int ih = si >> 3, iw = si & 7;
                    float v = sv[ct][j] + rpbs[((ih - jh + 7) * 15 + (iw - jw + 7)) * 6 + h];
                    if (edge) {
                        int hri = (wh << 3) + ih, wri = (ww << 3) + iw;
                        int hrj = (wh << 3) + jh, wrj = (ww << 3) + jw;
                        int ri = (hri < 120 ? 0 : (hri < 124 ? 1 : 2)) * 3 + (wri < 120 ? 0 : (wri < 124 ? 1 : 2));
                        int rj = (hrj < 120 ? 0 : (hrj < 124 ? 1 : 2)) * 3 + (wrj < 120 ? 0 : (wrj < 124 ? 1 : 2));
                        if (ri != rj) v -= 100.f;
                    }
                    sv[ct][j] = v;
                }
            }
        }
        __syncthreads();
        #pragma unroll
        for (int j = 0; j < 4; ++j) {
            float mx = fmaxf(fmaxf(sv[0][j], sv[1][j]), fmaxf(sv[2][j], sv[3][j]));
            mx = fmaxf(mx, __shfl_xor(mx, 1));
            mx = fmaxf(mx, __shfl_xor(mx, 2));
            mx = fmaxf(mx, __shfl_xor(mx, 4));
            mx = fmaxf(mx, __shfl_xor(mx, 8));
            float e0 = __expf(sv[0][j] - mx);
            float e1 = __expf(sv[1][j] - mx);
            float e2 = __expf(sv[2][j] - mx);
            float e3 = __expf(sv[3][j] - mx);
            float sm = e0 + e1 + e2 + e3;
            sm += __shfl_xor(sm, 1);
            sm += __shfl_xor(sm, 2);
            sm += __shfl_xor(sm, 4);
            sm += __shfl_xor(sm, 8);
            float inv = 1.f / sm;
            int row = wave * 16 + lk * 4 + j;
            Pb[row * 72 +      lr] = f2b(e0 * inv);
            Pb[row * 72 + 16 + lr] = f2b(e1 * inv);
            Pb[row * 72 + 32 + lr] = f2b(e2 * inv);
            Pb[row * 72 + 48 + lr] = f2b(e3 * inv);
        }
        __syncthreads();
        {
            s16x8 pa0 = *(const s16x8*)&Pb[(wave * 16 + lr) * 72 + lk * 8];
            s16x8 pa1 = *(const s16x8*)&Pb[(wave * 16 + lr) * 72 + 32 + lk * 8];
            #pragma unroll
            for (int ct = 0; ct < 2; ++ct) {
                f32x4 acc = {0.f, 0.f, 0.f, 0.f};
                s16x8 vb0 = *(const s16x8*)&Vt[(ct * 16 + lr) * 72 + lk * 8];
                s16x8 vb1 = *(const s16x8*)&Vt[(ct * 16 + lr) * 72 + 32 + lk * 8];
                acc = __builtin_amdgcn_mfma_f32_16x16x32_bf16(pa0, vb0, acc, 0, 0, 0);
                acc = __builtin_amdgcn_mfma_f32_16x16x32_bf16(pa1, vb1, acc, 0, 0, 0);
                int dd = ct * 16 + lr;
                if (dd < DH) {
                    #pragma unroll
                    for (int j = 0; j < 4; ++j) {
                        int tok = wave * 16 + lk * 4 + j;
                        outp[wbase + (size_t)tok * CD + h * DH + dd] = f2b(acc[j]);
                    }
                }
            }
        }
        __syncthreads();
    }
}

// ---------------- proj + addback + fused LN2: writes xout (NCHW fp32) AND xln (bf16, windowed rows)
__global__ __launch_bounds__(256) void proj_ln2(
    const u16* __restrict__ oute, const u16* __restrict__ outb,
    const u16* __restrict__ sig_base, const u16* __restrict__ wp_base,
    const float* __restrict__ bias_e, const float* __restrict__ bias_b,
    const float* __restrict__ e_f, const float* __restrict__ b_f,
    const float* __restrict__ g2e, const float* __restrict__ be2e,
    const float* __restrict__ g2b, const float* __restrict__ be2b,
    float* __restrict__ xout_base, u16* __restrict__ xln_base) {
    __shared__ __align__(16) u16 As[64 * 392];
    int bid = blockIdx.x, t = threadIdx.x;
    int flag = bid >> 10;
    int rb = bid & 1023;
    const u16* sig = sig_base + (size_t)flag * S192;
    const u16* Wb = wp_base + flag * (192 * 384);
    const float* bias = flag ? bias_b : bias_e;
    const float* src = flag ? b_f : e_f;
    const float* gamma = flag ? g2b : g2e;
    const float* beta2 = flag ? be2b : be2e;
    float* xout = xout_base + (size_t)flag * XSZ;
    u16* xln = xln_base + (size_t)flag * S192;
    size_t rb64 = (size_t)rb * 64;
    for (int i = t; i < 64 * 45; i += 256) {
        int row = i / 45, q = i % 45;
        size_t r180 = (rb64 + row) * (size_t)CD + q * 4;
        size_t r192 = (rb64 + row) * (size_t)CP + q * 4;
        ushort4 sg = *(const ushort4*)&sig[r192];
        ushort4 oe = *(const ushort4*)&oute[r180];
        ushort4 ob = *(const ushort4*)&outb[r180];
        ushort4 re, rbv;
        re.x = f2b(b2f(oe.x) * b2f(sg.x)); re.y = f2b(b2f(oe.y) * b2f(sg.y));
        re.z = f2b(b2f(oe.z) * b2f(sg.z)); re.w = f2b(b2f(oe.w) * b2f(sg.w));
        rbv.x = f2b(b2f(ob.x) * b2f(sg.x)); rbv.y = f2b(b2f(ob.y) * b2f(sg.y));
        rbv.z = f2b(b2f(ob.z) * b2f(sg.z)); rbv.w = f2b(b2f(ob.w) * b2f(sg.w));
        *(ushort4*)&As[row * 392 + q * 4] = re;
        *(ushort4*)&As[row * 392 + 180 + q * 4] = rbv;
    }
    for (int i = t; i < 64 * 6; i += 256) {
        int row = i / 6, q = i % 6;
        ushort4 z; z.x = 0; z.y = 0; z.z = 0; z.w = 0;
        *(ushort4*)&As[row * 392 + 360 + q * 4] = z;
    }
    __syncthreads();
    int wave = t >> 6, lane = t & 63, lr = lane & 15, lk = lane >> 4;
    s16x8 a[12];
    #pragma unroll
    for (int ks = 0; ks < 12; ++ks)
        a[ks] = *(const s16x8*)&As[(wave * 16 + lr) * 392 + ks * 32 + lk * 8];

    f32x4 val[12];
    float s0 = 0.f, s1 = 0.f, s2 = 0.f, s3 = 0.f;
    float q0 = 0.f, q1 = 0.f, q2 = 0.f, q3 = 0.f;
    #pragma unroll
    for (int ct = 0; ct < 12; ++ct) {
        f32x4 acc = {0.f, 0.f, 0.f, 0.f};
        #pragma unroll
        for (int ks = 0; ks < 12; ++ks) {
            s16x8 b = *(const s16x8*)&Wb[((size_t)(ct * 12 + ks) * 64 + lane) * 8];
            acc = __builtin_amdgcn_mfma_f32_16x16x32_bf16(a[ks], b, acc, 0, 0, 0);
        }
        int c = ct * 16 + lr;
        if (c < CD) {
            float bb = bias[c];
            #pragma unroll
            for (int j = 0; j < 4; ++j) {
                int rowm = (int)rb64 + wave * 16 + lk * 4 + j;
                int win = rowm >> 6, pos = rowm & 63;
                int b = win >> 8, whh = (win >> 4) & 15, www = win & 15;
                int hh = (((whh << 3) + (pos >> 3)) + 4) & 127;
                int w2 = (((www << 3) + (pos & 7)) + 4) & 127;
                size_t idx = (((size_t)(b * CD + c)) << 14) + (hh << 7) + w2;
                float v = src[idx] + acc[j] + bb;
                xout[idx] = v;
                val[ct][j] = v;
                if (j == 0) { s0 += v; q0 += v * v; }
                else if (j == 1) { s1 += v; q1 += v * v; }
                else if (j == 2) { s2 += v; q2 += v * v; }
                else { s3 += v; q3 += v * v; }
            }
        } else {
            val[ct] = (f32x4){0.f, 0.f, 0.f, 0.f};
        }
    }
    // reduce row sums over the 16-lane lr group
    #pragma unroll
    for (int m = 1; m < 16; m <<= 1) {
        s0 += __shfl_xor(s0, m); q0 += __shfl_xor(q0, m);
        s1 += __shfl_xor(s1, m); q1 += __shfl_xor(q1, m);
        s2 += __shfl_xor(s2, m); q2 += __shfl_xor(q2, m);
        s3 += __shfl_xor(s3, m); q3 += __shfl_xor(q3, m);
    }
    float mean[4], rstd[4];
    mean[0] = s0 * (1.f / CD); rstd[0] = rsqrtf(q0 * (1.f / CD) - mean[0] * mean[0] + 1e-5f);
    mean[1] = s1 * (1.f / CD); rstd[1] = rsqrtf(q1 * (1.f / CD) - mean[1] * mean[1] + 1e-5f);
    mean[2] = s2 * (1.f / CD); rstd[2] = rsqrtf(q2 * (1.f / CD) - mean[2] * mean[2] + 1e-5f);
    mean[3] = s3 * (1.f / CD); rstd[3] = rsqrtf(q3 * (1.f / CD) - mean[3] * mean[3] + 1e-5f);
    // write normalized xln (bf16, WINDOWED row order, stride CP; pad cols = 0)
    #pragma unroll
    for (int ct = 0; ct < 12; ++ct) {
        int c = ct * 16 + lr;
        float g = 0.f, be = 0.f;
        if (c < CD) { g = gamma[c]; be = beta2[c]; }
        #pragma unroll
        for (int j = 0; j < 4; ++j) {
            size_t rowm = rb64 + wave * 16 + lk * 4 + j;
            u16 o = 0;
            if (c < CD) o = f2b((val[ct][j] - mean[j]) * rstd[j] * g + be);
            xln[rowm * CP + c] = o;
        }
    }
}

// ---------------- MFMA MLP v4: wave-N-split, B-reuse=4, LDS X + Hid (43 KB)
// xln rows are WINDOWED; epilogue maps windowed row -> unshifted NCHW position.
__global__ __launch_bounds__(256, 3) void mlp3(
    const u16* __restrict__ xln_base, const u16* __restrict__ w1_base,
    const float* __restrict__ b1_e, const float* __restrict__ b1_b,
    const u16* __restrict__ w2_base, const float* __restrict__ b2_e,
    const float* __restrict__ b2_b, float* __restrict__ xout_base) {
    __shared__ __align__(16) u16 Xs[64 * 200];    // 25600 B
    __shared__ __align__(16) u16 Hid[64 * 136];   // 17408 B
    int bid = blockIdx.x, t = threadIdx.x;
    int flag = bid >> 10;
    int rb = bid & 1023;
    const u16* xln = xln_base + (size_t)flag * S192;
    const u16* W1p = w1_base + (size_t)flag * (768 * 192);
    const u16* W2p = w2_base + (size_t)flag * (192 * 768);
    const float* b1 = flag ? b1_b : b1_e;
    const float* b2v = flag ? b2_b : b2_e;
    float* xout = xout_base + (size_t)flag * XSZ;
    int wave = t >> 6, lane = t & 63, lr = lane & 15, lk = lane >> 4;

    for (int i = t; i < 64 * 24; i += 256) {
        int row = i / 24, seg = i % 24;
        *(s16x8*)&Xs[row * 200 + seg * 8] =
            *(const s16x8*)&xln[((size_t)rb * 64 + row) * CP + seg * 8];
    }
    __syncthreads();

    f32x4 acc2[3][4];
    #pragma unroll
    for (int c = 0; c < 3; ++c)
        #pragma unroll
        for (int m = 0; m < 4; ++m) acc2[c][m] = (f32x4){0.f, 0.f, 0.f, 0.f};

    for (int ch = 0; ch < 6; ++ch) {
        // ---- GEMM1: this wave computes hid cols [ch*128 + wave*32, +32) for ALL 64 rows
        int ctg0 = ch * 8 + wave * 2, ctg1 = ctg0 + 1;
        f32x4 h0[4], h1[4];
        #pragma unroll
        for (int m = 0; m < 4; ++m) { h0[m] = (f32x4){0,0,0,0}; h1[m] = (f32x4){0,0,0,0}; }
        #pragma unroll
        for (int ks = 0; ks < 6; ++ks) {
            s16x8 b0 = *(const s16x8*)&W1p[((size_t)(ctg0 * 6 + ks) * 64 + lane) * 8];
            s16x8 b1v = *(const s16x8*)&W1p[((size_t)(ctg1 * 6 + ks) * 64 + lane) * 8];
            #pragma unroll
            for (int m = 0; m < 4; ++m) {
                s16x8 av = *(const s16x8*)&Xs[(m * 16 + lr) * 200 + ks * 32 + lk * 8];
                h0[m] = __builtin_amdgcn_mfma_f32_16x16x32_bf16(av, b0, h0[m], 0, 0, 0);
                h1[m] = __builtin_amdgcn_mfma_f32_16x16x32_bf16(av, b1v, h1[m], 0, 0, 0);
            }
        }
        #pragma unroll 2
        for (int cti = 0; cti < 2; ++cti) {
            int hcol = (ctg0 + cti) * 16 + lr;
            float bb = (hcol < 720) ? b1[hcol] : 0.f;
            int lcol = wave * 32 + cti * 16 + lr;
            #pragma unroll
            for (int m = 0; m < 4; ++m) {
                f32x4 hv = cti ? h1[m] : h0[m];
                #pragma unroll
                for (int j = 0; j < 4; ++j) {
                    float v = gelu_f(hv[j] + bb);
                    Hid[(m * 16 + lk * 4 + j) * 136 + lcol] = f2b(v);
                }
            }
        }
        __syncthreads();
        // ---- GEMM2: this wave computes out cols [wave*48, +48) over this chunk's 128 K
        #pragma unroll
        for (int ks = 0; ks < 4; ++ks) {
            int gks = ch * 4 + ks;
            s16x8 av[4];
            #pragma unroll
            for (int m = 0; m < 4; ++m)
                av[m] = *(const s16x8*)&Hid[(m * 16 + lr) * 136 + ks * 32 + lk * 8];
            #pragma unroll
            for (int ct3 = 0; ct3 < 3; ++ct3) {
                int ctg = wave * 3 + ct3;
                s16x8 b = *(const s16x8*)&W2p[((size_t)(ctg * 24 + gks) * 64 + lane) * 8];
                #pragma unroll
                for (int m = 0; m < 4; ++m)
                    acc2[ct3][m] = __builtin_amdgcn_mfma_f32_16x16x32_bf16(av[m], b, acc2[ct3][m], 0, 0, 0);
            }
        }
        __syncthreads();
    }
    // ---- epilogue: bias + accumulate into xout (NCHW), windowed row -> spatial
    #pragma unroll
    for (int ct3 = 0; ct3 < 3; ++ct3) {
        int cc = (wave * 3 + ct3) * 16 + lr;
        if (cc < CD) {
            float bb = b2v[cc];
            #pragma unroll
            for (int m = 0; m < 4; ++m) {
                #pragma unroll
                for (int j = 0; j < 4; ++j) {
                    int mm = rb * 64 + m * 16 + lk * 4 + j;   // windowed row
                    int win = mm >> 6, pos = mm & 63;
                    int b = win >> 8, whh = (win >> 4) & 15, www = win & 15;
                    int hh = (((whh << 3) + (pos >> 3)) + 4) & 127;
                    int w2 = (((www << 3) + (pos & 7)) + 4) & 127;
                    size_t idx = (((size_t)(b * CD + cc)) << 14) + (hh << 7) + w2;
                    xout[idx] += acc2[ct3][m][j] + bb;
                }
            }
        }
    }
}

extern "C" void kernel_launch(void* const* d_in, const int* in_sizes, int n_in,
                              void* d_out, int out_size, void* d_ws, size_t ws_size,
                              hipStream_t stream) {
    const float* e_f = (const float*)d_in[0];
    const float* b_f = (const float*)d_in[1];

    u16* ew   = (u16*)d_ws;
    u16* bw   = ew + S192;
    u16* sige = bw + S192;
    u16* sigb = sige + S192;
    u16* oute = sigb + S192;
    u16* outb = oute + S180;
    u16* wg_e = outb + S180;                 // contiguous prep region
    u16* wp_e = wg_e + 2 * 36864;
    u16* w1_e = wp_e + 2 * 73728;
    u16* w2_e = w1_e + 2 * 147456;
    u16* wq_e = w2_e + 2 * 147456;           // 2 * 576*192
    float* bq_e = (float*)(wq_e + 2 * 576 * 192);   // 2 * 576
    u16* lne = sige;   // xln (from proj_ln2) overwrites sig region

    float* xe = (float*)d_out;

    PrepArgs pa;
    pa.s0 = (const float*)d_in[10];
    pa.s1 = (const float*)d_in[12];
    pa.s2 = (const float*)d_in[15];
    pa.s3 = (const float*)d_in[17];
    pa.s4 = (const float*)d_in[23];
    pa.s5 = (const float*)d_in[27];
    pa.s6 = (const float*)d_in[25];
    pa.s7 = (const float*)d_in[29];
    pa.dst = wg_e;
    prep_all<<<3168, 256, 0, stream>>>(pa);
    prep_wqkv2<<<(2 * 576 * 192 + 255) / 256, 256, 0, stream>>>(
        (const float*)d_in[6], (const float*)d_in[7],
        (const float*)d_in[8], (const float*)d_in[9], wq_e, bq_e);

    ln_win2<<<2 * NWIN, 256, 0, stream>>>(e_f, b_f,
        (const float*)d_in[2], (const float*)d_in[3],
        (const float*)d_in[4], (const float*)d_in[5], ew);

    gate2<<<2 * MROWS / 64, 256, 0, stream>>>(ew, wg_e,
        (const float*)d_in[11], (const float*)d_in[13], sige);

    attn2<<<2 * NWIN, 256, 0, stream>>>(ew, wq_e, bq_e,
        (const float*)d_in[14], oute);

    proj_ln2<<<2 * MROWS / 64, 256, 0, stream>>>(oute, outb, sige, wp_e,
        (const float*)d_in[16], (const float*)d_in[18], e_f, b_f,
        (const float*)d_in[19], (const float*)d_in[20],
        (const float*)d_in[21], (const float*)d_in[22], xe, lne);

    mlp3<<<2 * MROWS / 64, 256, 0, stream>>>(lne, w1_e,
        (const float*)d_in[24], (const float*)d_in[28], w2_e,
        (const float*)d_in[26], (const float*)d_in[30], xe);
}

// Round 9
// 719.771 us; speedup vs baseline: 12.0605x; 1.1558x over previous
//
#include <hip/hip_runtime.h>
#include <hip/hip_bf16.h>

typedef unsigned short u16;
typedef unsigned int u32;
typedef __attribute__((ext_vector_type(8))) short s16x8;
typedef __attribute__((ext_vector_type(4))) float f32x4;

constexpr int CD    = 180;
constexpr int CP    = 192;              // K-padded channel count
constexpr int BATCH = 4;
constexpr int RES   = 128;
constexpr int LSZ   = RES * RES;        // 16384
constexpr int NHEAD = 6;
constexpr int DH    = 30;
constexpr int NTOK  = 64;
constexpr int NWIN  = 1024;
constexpr int MROWS = NWIN * NTOK;      // 65536
constexpr size_t S192 = (size_t)MROWS * CP;
constexpr size_t S180 = (size_t)MROWS * CD;
constexpr size_t XSZ  = (size_t)BATCH * CD * LSZ;

__device__ __forceinline__ float b2f(u16 u) { return __uint_as_float(((u32)u) << 16); }
__device__ __forceinline__ u16 f2b(float f) {
    __hip_bfloat16 h = __float2bfloat16(f);
    return *reinterpret_cast<u16*>(&h);
}
// fast GELU (tanh form); |err vs exact erf-GELU| <~1e-3
__device__ __forceinline__ float gelu_f(float x) {
    float y = 0.7978845608028654f * (x + 0.044715f * x * x * x);
    float t = __expf(-2.f * fabsf(y));
    float th = (1.f - t) / (1.f + t);
    th = copysignf(th, y);
    return 0.5f * x * (1.f + th);
}

// ---------------- merged weight prep: 8 fragment-major jobs in one launch
struct PrepArgs {
    const float *s0, *s1, *s2, *s3, *s4, *s5, *s6, *s7;
    u16* dst;   // base of contiguous dst region (wg_e)
};
__device__ __forceinline__ void do_frag(const float* __restrict__ src,
        u16* __restrict__ dst, int N, int K, int nks, int li) {
    int e = li & 7, lr = (li >> 3) & 15, lk = (li >> 7) & 3, rest = li >> 9;
    int ks = rest % nks, ct = rest / nks;
    int n = ct * 16 + lr, k = ks * 32 + lk * 8 + e;
    float v = (n < N && k < K) ? src[n * K + k] : 0.f;
    dst[li] = f2b(v);
}
// proj weights: K=384 split layout. frag col k<192 -> src col k (if <180);
// k in [192,384) -> src col 180+(k-192) (if k-192<180). src is [180][360].
__device__ __forceinline__ void do_frag_proj(const float* __restrict__ src,
        u16* __restrict__ dst, int li) {
    int e = li & 7, lr = (li >> 3) & 15, lk = (li >> 7) & 3, rest = li >> 9;
    int ks = rest % 12, ct = rest / 12;
    int n = ct * 16 + lr, k = ks * 32 + lk * 8 + e;
    int khalf = k & 191;
    int ksrc = (k < 192) ? khalf : 180 + khalf;
    float v = (n < 180 && khalf < 180) ? src[n * 360 + ksrc] : 0.f;
    dst[li] = f2b(v);
}
__global__ __launch_bounds__(256) void prep_all(PrepArgs pa) {
    int bid = blockIdx.x, t = threadIdx.x;
    if (bid < 144)       do_frag(pa.s0, pa.dst,          180, 180,  6, (bid       ) * 256 + t);
    else if (bid < 288)  do_frag(pa.s1, pa.dst + 36864,  180, 180,  6, (bid - 144 ) * 256 + t);
    else if (bid < 576)  do_frag_proj(pa.s2, pa.dst + 73728,           (bid - 288 ) * 256 + t);
    else if (bid < 864)  do_frag_proj(pa.s3, pa.dst + 147456,          (bid - 576 ) * 256 + t);
    else if (bid < 1440) do_frag(pa.s4, pa.dst + 221184, 720, 180,  6, (bid - 864 ) * 256 + t);
    else if (bid < 2016) do_frag(pa.s5, pa.dst + 368640, 720, 180,  6, (bid - 1440) * 256 + t);
    else if (bid < 2592) do_frag(pa.s6, pa.dst + 516096, 180, 720, 24, (bid - 2016) * 256 + t);
    else                 do_frag(pa.s7, pa.dst + 663552, 180, 720, 24, (bid - 2592) * 256 + t);
}

// ---------------- merged qkv weight prep (e and b)
__global__ __launch_bounds__(256) void prep_wqkv2(
        const float* __restrict__ we, const float* __restrict__ be,
        const float* __restrict__ wb, const float* __restrict__ bb,
        u16* __restrict__ wp_base, float* __restrict__ bp_base) {
    int gi = blockIdx.x * 256 + threadIdx.x;
    int flag = gi >= 576 * 192;
    int i = flag ? gi - 576 * 192 : gi;
    if (i >= 576 * 192) return;
    const float* w = flag ? wb : we;
    const float* bsrc = flag ? bb : be;
    u16* wp = wp_base + (size_t)flag * (576 * 192);
    float* bp = bp_base + flag * 576;
    int e = i & 7, lr = (i >> 3) & 15, lk = (i >> 7) & 3, rest = i >> 9;
    int ks = rest % 6, rest2 = rest / 6;
    int ct = rest2 % 6, head = rest2 / 6;
    int rr = ct * 16 + lr;
    int sec = rr >> 5, dd = rr & 31;
    int srow = sec * 180 + head * 30 + dd;
    int k = ks * 32 + lk * 8 + e;
    float scale = (sec == 0) ? 0.18257418583505536f : 1.f;
    float v = (dd < 30 && k < 180) ? w[srow * 180 + k] * scale : 0.f;
    wp[i] = f2b(v);
    if (ks == 0 && lk == 0 && e == 0)
        bp[head * 96 + rr] = (dd < 30) ? bsrc[srow] * scale : 0.f;
}

// ---------------- merged LN1 + roll + window partition (e and b)
__global__ __launch_bounds__(256) void ln_win2(
    const float* __restrict__ e_f, const float* __restrict__ b_f,
    const float* __restrict__ g_e, const float* __restrict__ be_e,
    const float* __restrict__ g_b, const float* __restrict__ be_b,
    u16* __restrict__ dst_base) {
    __shared__ float tile[NTOK][CD + 1];
    int bid = blockIdx.x;
    int flag = bid >> 10;
    int widx = bid & 1023;
    const float* src = flag ? b_f : e_f;
    const float* gamma = flag ? g_b : g_e;
    const float* beta = flag ? be_b : be_e;
    u16* dst = dst_base + (size_t)flag * S192;
    int b = widx >> 8, wrem = widx & 255;
    int wh = wrem >> 4, ww = wrem & 15;
    int t = threadIdx.x;
    for (int i = t; i < NTOK * CD; i += 256) {
        int c = i >> 6, pos = i & 63;
        int sh = ((wh << 3) + (pos >> 3) + 4) & 127;
        int sw = ((ww << 3) + (pos & 7) + 4) & 127;
        tile[pos][c] = src[(((size_t)b * CD + c) << 14) + (sh << 7) + sw];
    }
    __syncthreads();
    int pos = t >> 2, sub = t & 3;
    float s = 0.f, ss = 0.f;
    for (int k = 0; k < 45; ++k) {
        float v = tile[pos][sub * 45 + k];
        s += v; ss += v * v;
    }
    s += __shfl_xor(s, 1); ss += __shfl_xor(ss, 1);
    s += __shfl_xor(s, 2); ss += __shfl_xor(ss, 2);
    float mean = s * (1.f / CD);
    float rstd = rsqrtf(ss * (1.f / CD) - mean * mean + 1e-5f);
    size_t obase = ((size_t)widx * NTOK + pos) * CP;
    for (int k = 0; k < 45; ++k) {
        int c = sub * 45 + k;
        dst[obase + c] = f2b((tile[pos][c] - mean) * rstd * gamma[c] + beta[c]);
    }
    if (sub == 3) {
        for (int k = 0; k < 12; ++k) dst[obase + CD + k] = 0;
    }
}

// ---------------- merged MFMA gate (e and b), no LDS: direct A-fragments
__global__ __launch_bounds__(256) void gate2(
    const u16* __restrict__ A_base, const u16* __restrict__ W_base,
    const float* __restrict__ bias_e, const float* __restrict__ bias_b,
    u16* __restrict__ sig_base) {
    int bid = blockIdx.x, t = threadIdx.x;
    int flag = bid >> 10;
    int rb = bid & 1023;
    const u16* A = A_base + (size_t)flag * S192;
    const u16* Wb = W_base + flag * 36864;
    const float* bias = flag ? bias_b : bias_e;
    u16* sig = sig_base + (size_t)flag * S192;
    int wave = t >> 6, lane = t & 63, lr = lane & 15, lk = lane >> 4;
    const u16* arow = A + ((size_t)rb * 64 + wave * 16 + lr) * CP;
    s16x8 a[6];
    #pragma unroll
    for (int ks = 0; ks < 6; ++ks)
        a[ks] = *(const s16x8*)&arow[ks * 32 + lk * 8];
    for (int ct = 0; ct < 12; ++ct) {
        f32x4 acc = {0.f, 0.f, 0.f, 0.f};
        #pragma unroll
        for (int ks = 0; ks < 6; ++ks) {
            s16x8 b = *(const s16x8*)&Wb[((size_t)(ct * 6 + ks) * 64 + lane) * 8];
            acc = __builtin_amdgcn_mfma_f32_16x16x32_bf16(a[ks], b, acc, 0, 0, 0);
        }
        int c = ct * 16 + lr;
        if (c < CD) {
            float bb = bias[c];
            #pragma unroll
            for (int j = 0; j < 4; ++j) {
                int rowm = rb * 64 + wave * 16 + lk * 4 + j;
                float v = acc[j] + bb;
                v = 1.f / (1.f + __expf(-v));
                sig[(size_t)rowm * CP + c] = f2b(v);
            }
        }
    }
}

// ---------------- merged MFMA attention (e and b)
__global__ __launch_bounds__(256) void attn2(
    const u16* __restrict__ ew_base, const u16* __restrict__ wq_base,
    const float* __restrict__ bq_base, const float* __restrict__ rpb,
    u16* __restrict__ out_base) {
    __shared__ __align__(16) char smem[28448];
    u16*   ews  = (u16*)smem;                 // 64*200*2 = 25600 B (staging, dies)
    u16*   Qs   = (u16*)smem;                 // 64*36*2  =  4608
    u16*   Ks   = (u16*)(smem + 4608);
    u16*   Vt   = (u16*)(smem + 9216);        // 32*72*2  =  4608
    u16*   Pb   = (u16*)(smem + 13824);       // 64*72*2  =  9216
    float* rpbs = (float*)(smem + 23040);     // 1350*4   =  5400

    int bid = blockIdx.x;
    int flag = bid >> 10;
    int widx = bid & 1023;
    const u16* ew = ew_base + (size_t)flag * S192;
    const u16* Wq = wq_base + (size_t)flag * (576 * 192);
    const float* Bq = bq_base + flag * 576;
    u16* outp = out_base + (size_t)flag * S180;

    int wrem = widx & 255;
    int wh = wrem >> 4, ww = wrem & 15;
    bool edge = (wh == 15) || (ww == 15);
    int t = threadIdx.x;
    size_t wbase = (size_t)widx * NTOK * CD;
    size_t wb192 = (size_t)widx * NTOK * CP;

    for (int i = t; i < 64 * 24; i += 256) {
        int row = i / 24, seg = i % 24;
        *(s16x8*)&ews[row * 200 + seg * 8] = *(const s16x8*)&ew[wb192 + (size_t)row * CP + seg * 8];
    }
    __syncthreads();

    int wave = t >> 6, lane = t & 63, lr = lane & 15, lk = lane >> 4;
    s16x8 a[6];
    #pragma unroll
    for (int ks = 0; ks < 6; ++ks)
        a[ks] = *(const s16x8*)&ews[(wave * 16 + lr) * 200 + ks * 32 + lk * 8];
    __syncthreads();   // all waves done reading ews; region reusable

    for (int i = t; i < 1350; i += 256) rpbs[i] = rpb[i];  // visible after next barrier

    for (int h = 0; h < NHEAD; ++h) {
        #pragma unroll
        for (int ct = 0; ct < 6; ++ct) {
            f32x4 acc = {0.f, 0.f, 0.f, 0.f};
            #pragma unroll
            for (int ks = 0; ks < 6; ++ks) {
                s16x8 b = *(const s16x8*)&Wq[(((size_t)(h * 6 + ct) * 6 + ks) * 64 + lane) * 8];
                acc = __builtin_amdgcn_mfma_f32_16x16x32_bf16(a[ks], b, acc, 0, 0, 0);
            }
            int sec = ct >> 1;
            int dd = ((ct & 1) << 4) + lr;
            float bb = Bq[h * 96 + ct * 16 + lr];
            #pragma unroll
            for (int j = 0; j < 4; ++j) {
                int tok = wave * 16 + lk * 4 + j;
                float v = acc[j] + bb;
                if (sec == 0)      Qs[tok * 36 + dd] = f2b(v);
                else if (sec == 1) Ks[tok * 36 + dd] = f2b(v);
                else               Vt[dd * 72 + tok] = f2b(v);
            }
        }
        __syncthreads();
        f32x4 sv[4];
        {
            s16x8 qa = *(const s16x8*)&Qs[(wave * 16 + lr) * 36 + lk * 8];
            #pragma unroll
            for (int ct = 0; ct < 4; ++ct) {
                s16x8 kb = *(const s16x8*)&Ks[(ct * 16 + lr) * 36 + lk * 8];
                f32x4 z = {0.f, 0.f, 0.f, 0.f};
                sv[ct] = __builtin_amdgcn_mfma_f32_16x16x32_bf16(qa, kb, z, 0, 0, 0);
            }
            #pragma unroll
            for (int ct = 0; ct < 4; ++ct) {
                int sj = ct * 16 + lr;
                int jh = sj >> 3, jw = sj & 7;
                #pragma unroll
                for (int j = 0; j < 4; ++j) {
                    int si = wave * 16 + lk * 4 + j;
                    int ih = si >> 3, iw = si & 7;
                    float v = sv[ct][j] + rpbs[((ih - jh + 7) * 15 + (iw - jw + 7)) * 6 + h];
                    if (edge) {
                        int hri = (wh << 3) + ih, wri = (ww << 3) + iw;
                        int hrj = (wh << 3) + jh, wrj = (ww << 3) + jw;
                        int ri = (hri < 120 ? 0 : (hri < 124 ? 1 : 2)) * 3 + (wri < 120 ? 0 : (wri < 124 ? 1 : 2));
                        int rj = (hrj < 120 ? 0 : (hrj < 124 ? 1 : 2)) * 3 + (wrj < 120 ? 0 : (wrj < 124 ? 1 : 2));
                        if (ri != rj) v -= 100.f;
                    }
                    sv[ct][j] = v;
                }
            }
        }
        __syncthreads();
        #pragma unroll
        for (int j = 0; j < 4; ++j) {
            float mx = fmaxf(fmaxf(sv[0][j], sv[1][j]), fmaxf(sv[2][j], sv[3][j]));
            mx = fmaxf(mx, __shfl_xor(mx, 1));
            mx = fmaxf(mx, __shfl_xor(mx, 2));
            mx = fmaxf(mx, __shfl_xor(mx, 4));
            mx = fmaxf(mx, __shfl_xor(mx, 8));
            float e0 = __expf(sv[0][j] - mx);
            float e1 = __expf(sv[1][j] - mx);
            float e2 = __expf(sv[2][j] - mx);
            float e3 = __expf(sv[3][j] - mx);
            float sm = e0 + e1 + e2 + e3;
            sm += __shfl_xor(sm, 1);
            sm += __shfl_xor(sm, 2);
            sm += __shfl_xor(sm, 4);
            sm += __shfl_xor(sm, 8);
            float inv = 1.f / sm;
            int row = wave * 16 + lk * 4 + j;
            Pb[row * 72 +      lr] = f2b(e0 * inv);
            Pb[row * 72 + 16 + lr] = f2b(e1 * inv);
            Pb[row * 72 + 32 + lr] = f2b(e2 * inv);
            Pb[row * 72 + 48 + lr] = f2b(e3 * inv);
        }
        __syncthreads();
        {
            s16x8 pa0 = *(const s16x8*)&Pb[(wave * 16 + lr) * 72 + lk * 8];
            s16x8 pa1 = *(const s16x8*)&Pb[(wave * 16 + lr) * 72 + 32 + lk * 8];
            #pragma unroll
            for (int ct = 0; ct < 2; ++ct) {
                f32x4 acc = {0.f, 0.f, 0.f, 0.f};
                s16x8 vb0 = *(const s16x8*)&Vt[(ct * 16 + lr) * 72 + lk * 8];
                s16x8 vb1 = *(const s16x8*)&Vt[(ct * 16 + lr) * 72 + 32 + lk * 8];
                acc = __builtin_amdgcn_mfma_f32_16x16x32_bf16(pa0, vb0, acc, 0, 0, 0);
                acc = __builtin_amdgcn_mfma_f32_16x16x32_bf16(pa1, vb1, acc, 0, 0, 0);
                int dd = ct * 16 + lr;
                if (dd < DH) {
                    #pragma unroll
                    for (int j = 0; j < 4; ++j) {
                        int tok = wave * 16 + lk * 4 + j;
                        outp[wbase + (size_t)tok * CD + h * DH + dd] = f2b(acc[j]);
                    }
                }
            }
        }
        __syncthreads();
    }
}

// ---------------- proj + addback + fused LN2, zero-LDS, float4 NCHW I/O
__global__ __launch_bounds__(256) void proj_ln2(
    const u16* __restrict__ oute, const u16* __restrict__ outb,
    const u16* __restrict__ sig_base, const u16* __restrict__ wp_base,
    const float* __restrict__ bias_e, const float* __restrict__ bias_b,
    const float* __restrict__ e_f, const float* __restrict__ b_f,
    const float* __restrict__ g2e, const float* __restrict__ be2e,
    const float* __restrict__ g2b, const float* __restrict__ be2b,
    float* __restrict__ xout_base, u16* __restrict__ xln_base) {
    int bid = blockIdx.x, t = threadIdx.x;
    int flag = bid >> 10;
    int rb = bid & 1023;
    const u16* sig = sig_base + (size_t)flag * S192;
    const u16* Wb = wp_base + flag * (192 * 384);
    const float* bias = flag ? bias_b : bias_e;
    const float* src = flag ? b_f : e_f;
    const float* gamma = flag ? g2b : g2e;
    const float* beta2 = flag ? be2b : be2e;
    float* xout = xout_base + (size_t)flag * XSZ;
    u16* xln = xln_base + (size_t)flag * S192;
    size_t rb64 = (size_t)rb * 64;
    int wave = t >> 6, lane = t & 63, lr = lane & 15, lk = lane >> 4;
    int row = wave * 16 + lr;

    // ---- direct gated A-fragments (K=384 split layout, seam-free)
    const u16* oe_row = oute + (rb64 + row) * (size_t)CD;
    const u16* ob_row = outb + (rb64 + row) * (size_t)CD;
    const u16* sg_row = sig + (rb64 + row) * (size_t)CP;
    s16x8 a[12];
    #pragma unroll
    for (int ks = 0; ks < 12; ++ks) {
        int koff = (ks >= 6 ? ks - 6 : ks) * 32 + lk * 8;   // 0..184
        const u16* sp = (ks < 6) ? oe_row : ob_row;
        s16x8 v = *(const s16x8*)&sp[koff];
        s16x8 g = *(const s16x8*)&sg_row[koff];
        s16x8 r;
        #pragma unroll
        for (int e = 0; e < 8; ++e) {
            float p = b2f((u16)v[e]) * b2f((u16)g[e]);
            if ((ks == 5 || ks == 11) && (koff + e >= 180)) p = 0.f;
            r[e] = (short)f2b(p);
        }
        a[ks] = r;
    }

    // ---- spatial address (same hh for j=0..3; w contiguous, wrap-safe)
    int rowm0 = (int)rb64 + wave * 16 + lk * 4;
    int win = rowm0 >> 6, pos0 = rowm0 & 63;
    int bb_ = win >> 8, whh = (win >> 4) & 15, www = win & 15;
    int hh = (((whh << 3) + (pos0 >> 3)) + 4) & 127;
    int w20 = (((www << 3) + (pos0 & 7)) + 4) & 127;
    size_t sbase = (((size_t)bb_ * CD) << 14) + (hh << 7) + w20;

    f32x4 val[12];
    float s0 = 0.f, s1 = 0.f, s2 = 0.f, s3 = 0.f;
    float q0 = 0.f, q1 = 0.f, q2 = 0.f, q3 = 0.f;
    #pragma unroll
    for (int ct = 0; ct < 12; ++ct) {
        f32x4 acc = {0.f, 0.f, 0.f, 0.f};
        #pragma unroll
        for (int ks = 0; ks < 12; ++ks) {
            s16x8 b = *(const s16x8*)&Wb[((size_t)(ct * 12 + ks) * 64 + lane) * 8];
            acc = __builtin_amdgcn_mfma_f32_16x16x32_bf16(a[ks], b, acc, 0, 0, 0);
        }
        int c = ct * 16 + lr;
        if (c < CD) {
            float bv = bias[c];
            size_t idx0 = sbase + ((size_t)c << 14);
            float4 s4 = *(const float4*)&src[idx0];
            f32x4 x;
            x[0] = s4.x + acc[0] + bv;
            x[1] = s4.y + acc[1] + bv;
            x[2] = s4.z + acc[2] + bv;
            x[3] = s4.w + acc[3] + bv;
            *(float4*)&xout[idx0] = make_float4(x[0], x[1], x[2], x[3]);
            val[ct] = x;
            s0 += x[0]; q0 += x[0] * x[0];
            s1 += x[1]; q1 += x[1] * x[1];
            s2 += x[2]; q2 += x[2] * x[2];
            s3 += x[3]; q3 += x[3] * x[3];
        } else {
            val[ct] = (f32x4){0.f, 0.f, 0.f, 0.f};
        }
    }
    // reduce row sums over the 16-lane lr group
    #pragma unroll
    for (int m = 1; m < 16; m <<= 1) {
        s0 += __shfl_xor(s0, m); q0 += __shfl_xor(q0, m);
        s1 += __shfl_xor(s1, m); q1 += __shfl_xor(q1, m);
        s2 += __shfl_xor(s2, m); q2 += __shfl_xor(q2, m);
        s3 += __shfl_xor(s3, m); q3 += __shfl_xor(q3, m);
    }
    float mean[4], rstd[4];
    mean[0] = s0 * (1.f / CD); rstd[0] = rsqrtf(q0 * (1.f / CD) - mean[0] * mean[0] + 1e-5f);
    mean[1] = s1 * (1.f / CD); rstd[1] = rsqrtf(q1 * (1.f / CD) - mean[1] * mean[1] + 1e-5f);
    mean[2] = s2 * (1.f / CD); rstd[2] = rsqrtf(q2 * (1.f / CD) - mean[2] * mean[2] + 1e-5f);
    mean[3] = s3 * (1.f / CD); rstd[3] = rsqrtf(q3 * (1.f / CD) - mean[3] * mean[3] + 1e-5f);
    // write normalized xln (bf16, WINDOWED row order, stride CP; pad cols = 0)
    #pragma unroll
    for (int ct = 0; ct < 12; ++ct) {
        int c = ct * 16 + lr;
        float g = 0.f, be = 0.f;
        if (c < CD) { g = gamma[c]; be = beta2[c]; }
        #pragma unroll
        for (int j = 0; j < 4; ++j) {
            size_t rowm = rb64 + wave * 16 + lk * 4 + j;
            u16 o = 0;
            if (c < CD) o = f2b((val[ct][j] - mean[j]) * rstd[j] * g + be);
            xln[rowm * CP + c] = o;
        }
    }
}

// ---------------- MFMA MLP v4: wave-N-split; float4 NCHW RMW epilogue
__global__ __launch_bounds__(256, 3) void mlp3(
    const u16* __restrict__ xln_base, const u16* __restrict__ w1_base,
    const float* __restrict__ b1_e, const float* __restrict__ b1_b,
    const u16* __restrict__ w2_base, const float* __restrict__ b2_e,
    const float* __restrict__ b2_b, float* __restrict__ xout_base) {
    __shared__ __align__(16) u16 Xs[64 * 200];    // 25600 B
    __shared__ __align__(16) u16 Hid[64 * 136];   // 17408 B
    int bid = blockIdx.x, t = threadIdx.x;
    int flag = bid >> 10;
    int rb = bid & 1023;
    const u16* xln = xln_base + (size_t)flag * S192;
    const u16* W1p = w1_base + (size_t)flag * (768 * 192);
    const u16* W2p = w2_base + (size_t)flag * (192 * 768);
    const float* b1 = flag ? b1_b : b1_e;
    const float* b2v = flag ? b2_b : b2_e;
    float* xout = xout_base + (size_t)flag * XSZ;
    int wave = t >> 6, lane = t & 63, lr = lane & 15, lk = lane >> 4;

    for (int i = t; i < 64 * 24; i += 256) {
        int row = i / 24, seg = i % 24;
        *(s16x8*)&Xs[row * 200 + seg * 8] =
            *(const s16x8*)&xln[((size_t)rb * 64 + row) * CP + seg * 8];
    }
    __syncthreads();

    f32x4 acc2[3][4];
    #pragma unroll
    for (int c = 0; c < 3; ++c)
        #pragma unroll
        for (int m = 0; m < 4; ++m) acc2[c][m] = (f32x4){0.f, 0.f, 0.f, 0.f};

    for (int ch = 0; ch < 6; ++ch) {
        // ---- GEMM1: this wave computes hid cols [ch*128 + wave*32, +32) for ALL 64 rows
        int ctg0 = ch * 8 + wave * 2, ctg1 = ctg0 + 1;
        f32x4 h0[4], h1[4];
        #pragma unroll
        for (int m = 0; m < 4; ++m) { h0[m] = (f32x4){0,0,0,0}; h1[m] = (f32x4){0,0,0,0}; }
        #pragma unroll
        for (int ks = 0; ks < 6; ++ks) {
            s16x8 b0 = *(const s16x8*)&W1p[((size_t)(ctg0 * 6 + ks) * 64 + lane) * 8];
            s16x8 b1v = *(const s16x8*)&W1p[((size_t)(ctg1 * 6 + ks) * 64 + lane) * 8];
            #pragma unroll
            for (int m = 0; m < 4; ++m) {
                s16x8 av = *(const s16x8*)&Xs[(m * 16 + lr) * 200 + ks * 32 + lk * 8];
                h0[m] = __builtin_amdgcn_mfma_f32_16x16x32_bf16(av, b0, h0[m], 0, 0, 0);
                h1[m] = __builtin_amdgcn_mfma_f32_16x16x32_bf16(av, b1v, h1[m], 0, 0, 0);
            }
        }
        #pragma unroll 2
        for (int cti = 0; cti < 2; ++cti) {
            int hcol = (ctg0 + cti) * 16 + lr;
            float bb = (hcol < 720) ? b1[hcol] : 0.f;
            int lcol = wave * 32 + cti * 16 + lr;
            #pragma unroll
            for (int m = 0; m < 4; ++m) {
                f32x4 hv = cti ? h1[m] : h0[m];
                #pragma unroll
                for (int j = 0; j < 4; ++j) {
                    float v = gelu_f(hv[j] + bb);
                    Hid[(m * 16 + lk * 4 + j) * 136 + lcol] = f2b(v);
                }
            }
        }
        __syncthreads();
        // ---- GEMM2: this wave computes out cols [wave*48, +48) over this chunk's 128 K
        #pragma unroll
        for (int ks = 0; ks < 4; ++ks) {
            int gks = ch * 4 + ks;
            s16x8 av[4];
            #pragma unroll
            for (int m = 0; m < 4; ++m)
                av[m] = *(const s16x8*)&Hid[(m * 16 + lr) * 136 + ks * 32 + lk * 8];
            #pragma unroll
            for (int ct3 = 0; ct3 < 3; ++ct3) {
                int ctg = wave * 3 + ct3;
                s16x8 b = *(const s16x8*)&W2p[((size_t)(ctg * 24 + gks) * 64 + lane) * 8];
                #pragma unroll
                for (int m = 0; m < 4; ++m)
                    acc2[ct3][m] = __builtin_amdgcn_mfma_f32_16x16x32_bf16(av[m], b, acc2[ct3][m], 0, 0, 0);
            }
        }
        __syncthreads();
    }
    // ---- epilogue: float4 RMW into xout (NCHW); windowed row -> spatial
    #pragma unroll
    for (int m = 0; m < 4; ++m) {
        int mm0 = rb * 64 + m * 16 + lk * 4;        // windowed row of j=0
        int win = mm0 >> 6, pos0 = mm0 & 63;
        int b = win >> 8, whh = (win >> 4) & 15, www = win & 15;
        int hh = (((whh << 3) + (pos0 >> 3)) + 4) & 127;
        int w20 = (((www << 3) + (pos0 & 7)) + 4) & 127;
        size_t sbase = (((size_t)b * CD) << 14) + (hh << 7) + w20;
        #pragma unroll
        for (int ct3 = 0; ct3 < 3; ++ct3) {
            int cc = (wave * 3 + ct3) * 16 + lr;
            if (cc < CD) {
                float bb = b2v[cc];
                size_t idx0 = sbase + ((size_t)cc << 14);
                float4 o4 = *(const float4*)&xout[idx0];
                o4.x += acc2[ct3][m][0] + bb;
                o4.y += acc2[ct3][m][1] + bb;
                o4.z += acc2[ct3][m][2] + bb;
                o4.w += acc2[ct3][m][3] + bb;
                *(float4*)&xout[idx0] = o4;
            }
        }
    }
}

extern "C" void kernel_launch(void* const* d_in, const int* in_sizes, int n_in,
                              void* d_out, int out_size, void* d_ws, size_t ws_size,
                              hipStream_t stream) {
    const float* e_f = (const float*)d_in[0];
    const float* b_f = (const float*)d_in[1];

    u16* ew   = (u16*)d_ws;
    u16* bw   = ew + S192;
    u16* sige = bw + S192;
    u16* sigb = sige + S192;
    u16* oute = sigb + S192;
    u16* outb = oute + S180;
    u16* wg_e = outb + S180;                 // contiguous prep region
    u16* wp_e = wg_e + 2 * 36864;
    u16* w1_e = wp_e + 2 * 73728;
    u16* w2_e = w1_e + 2 * 147456;
    u16* wq_e = w2_e + 2 * 147456;           // 2 * 576*192
    float* bq_e = (float*)(wq_e + 2 * 576 * 192);   // 2 * 576
    u16* lne = sige;   // xln (from proj_ln2) overwrites sig region

    float* xe = (float*)d_out;

    PrepArgs pa;
    pa.s0 = (const float*)d_in[10];
    pa.s1 = (const float*)d_in[12];
    pa.s2 = (const float*)d_in[15];
    pa.s3 = (const float*)d_in[17];
    pa.s4 = (const float*)d_in[23];
    pa.s5 = (const float*)d_in[27];
    pa.s6 = (const float*)d_in[25];
    pa.s7 = (const float*)d_in[29];
    pa.dst = wg_e;
    prep_all<<<3168, 256, 0, stream>>>(pa);
    prep_wqkv2<<<(2 * 576 * 192 + 255) / 256, 256, 0, stream>>>(
        (const float*)d_in[6], (const float*)d_in[7],
        (const float*)d_in[8], (const float*)d_in[9], wq_e, bq_e);

    ln_win2<<<2 * NWIN, 256, 0, stream>>>(e_f, b_f,
        (const float*)d_in[2], (const float*)d_in[3],
        (const float*)d_in[4], (const float*)d_in[5], ew);

    gate2<<<2 * MROWS / 64, 256, 0, stream>>>(ew, wg_e,
        (const float*)d_in[11], (const float*)d_in[13], sige);

    attn2<<<2 * NWIN, 256, 0, stream>>>(ew, wq_e, bq_e,
        (const float*)d_in[14], oute);

    proj_ln2<<<2 * MROWS / 64, 256, 0, stream>>>(oute, outb, sige, wp_e,
        (const float*)d_in[16], (const float*)d_in[18], e_f, b_f,
        (const float*)d_in[19], (const float*)d_in[20],
        (const float*)d_in[21], (const float*)d_in[22], xe, lne);

    mlp3<<<2 * MROWS / 64, 256, 0, stream>>>(lne, w1_e,
        (const float*)d_in[24], (const float*)d_in[28], w2_e,
        (const float*)d_in[26], (const float*)d_in[30], xe);
}